// Round 1
// baseline (1525.844 us; speedup 1.0000x reference)
//
#include <hip/hip_runtime.h>
#include <math.h>

constexpr int Nn = 50000;
constexpr int Ee = 800000;

// ---------------- CSR build ----------------
__global__ void k_count(const int* __restrict__ dst, int* __restrict__ cnt) {
  int e = blockIdx.x * 256 + threadIdx.x;
  if (e < Ee) atomicAdd(&cnt[dst[e]], 1);
}

__global__ __launch_bounds__(1024) void k_scan(const int* __restrict__ cnt, int* __restrict__ offs) {
  __shared__ int sh[1024];
  int t = threadIdx.x;
  const int CH = (Nn + 1023) / 1024;
  int s0 = t * CH, s1 = min(s0 + CH, Nn);
  int lsum = 0;
  for (int i = s0; i < s1; i++) lsum += cnt[i];
  sh[t] = lsum;
  __syncthreads();
  for (int off = 1; off < 1024; off <<= 1) {
    int v = (t >= off) ? sh[t - off] : 0;
    __syncthreads();
    sh[t] += v;
    __syncthreads();
  }
  int base = sh[t] - lsum;
  for (int i = s0; i < s1; i++) { offs[i] = base; base += cnt[i]; }
  if (t == 1023) offs[Nn] = sh[1023];
}

__global__ void k_scatter(const int* __restrict__ src, const int* __restrict__ dst,
                          const int* __restrict__ offs, int* __restrict__ cur,
                          int* __restrict__ csr) {
  int e = blockIdx.x * 256 + threadIdx.x;
  if (e < Ee) {
    int d = dst[e];
    int p = offs[d] + atomicAdd(&cur[d], 1);
    csr[p] = src[e];
  }
}

// ---------------- column stats (64-wide, ddof=1) ----------------
__global__ __launch_bounds__(256) void k_stats(const float* __restrict__ X, double* __restrict__ acc) {
  int col = threadIdx.x & 63, rs_ = threadIdx.x >> 6;
  int row0 = blockIdx.x * 1024;
  int rend = min(row0 + 1024, Nn);
  double s = 0.0, ss = 0.0;
  for (int r = row0 + rs_; r < rend; r += 4) {
    float v = X[(size_t)r * 64 + col];
    s += v; ss += (double)v * v;
  }
  __shared__ double sh[512];
  sh[threadIdx.x] = s; sh[256 + threadIdx.x] = ss;
  __syncthreads();
  if (rs_ == 0) {
    s = sh[col] + sh[col + 64] + sh[col + 128] + sh[col + 192];
    ss = sh[256 + col] + sh[256 + col + 64] + sh[256 + col + 128] + sh[256 + col + 192];
    atomicAdd(&acc[col], s);
    atomicAdd(&acc[64 + col], ss);
  }
}

__global__ void k_stats_final(const double* __restrict__ acc, float* __restrict__ mean,
                              float* __restrict__ rstd) {
  int c = threadIdx.x;
  if (c < 64) {
    double s = acc[c], ss = acc[64 + c];
    double m = s / (double)Nn;
    double var = (ss - s * s / (double)Nn) / (double)(Nn - 1);
    double sd = sqrt(var > 0.0 ? var : 0.0);
    if (sd < 1e-8) sd = 1e-8;
    mean[c] = (float)m;
    rstd[c] = (float)(1.0 / sd);
  }
}

// ---------------- local Dirichlet energy (pull over in-edges) ----------------
__global__ __launch_bounds__(256) void k_energy(const float* __restrict__ X,
                                                const int* __restrict__ cnt,
                                                const int* __restrict__ offs,
                                                const int* __restrict__ csr,
                                                float* __restrict__ R) {
  int wid = threadIdx.x >> 6, lane = threadIdx.x & 63;
  int node = blockIdx.x * 4 + wid;
  if (node >= Nn) return;
  int deg = cnt[node];
  float degf = (float)deg;
  float inv_i = rsqrtf(fmaxf(degf, 1e-12f));
  float xi = X[(size_t)node * 64 + lane] * inv_i;
  float num = 0.f, den = degf * xi * xi;
  int j0 = offs[node], j1 = offs[node + 1];
  for (int j = j0; j < j1; j++) {
    int s = csr[j];
    float inv_s = rsqrtf(fmaxf((float)cnt[s], 1e-12f));
    float xs = X[(size_t)s * 64 + lane] * inv_s;
    float d = xi - xs;
    num += d * d;
    den += xs * xs;
  }
  R[(size_t)node * 64 + lane] = num / (den + 1e-8f);
}

// ---------------- gate MLP + Z (in-place R -> Z) ----------------
__global__ __launch_bounds__(256) void k_gate(const float* __restrict__ feat,
                                              const float* __restrict__ fm, const float* __restrict__ fr,
                                              const float* __restrict__ rm, const float* __restrict__ rr,
                                              const float* __restrict__ w1, const float* __restrict__ b1,
                                              const float* __restrict__ w2, const float* __restrict__ b2,
                                              float* __restrict__ RZ) {
  __shared__ float sw1[1024], sw2[1024], sb1[16], sb2[64], sfm[64], sfr[64], srm[64], srr[64];
  for (int i = threadIdx.x; i < 1024; i += 256) { sw1[i] = w1[i]; sw2[i] = w2[i]; }
  if (threadIdx.x < 16) sb1[threadIdx.x] = b1[threadIdx.x];
  if (threadIdx.x < 64) {
    sb2[threadIdx.x] = b2[threadIdx.x];
    sfm[threadIdx.x] = fm[threadIdx.x]; sfr[threadIdx.x] = fr[threadIdx.x];
    srm[threadIdx.x] = rm[threadIdx.x]; srr[threadIdx.x] = rr[threadIdx.x];
  }
  __syncthreads();
  int node = blockIdx.x * 256 + threadIdx.x;
  if (node >= Nn) return;
  float xn[64];
  const float4* fx = (const float4*)(feat + (size_t)node * 64);
  for (int q = 0; q < 16; q++) {
    float4 v = fx[q];
    xn[q * 4 + 0] = (v.x - sfm[q * 4 + 0]) * sfr[q * 4 + 0];
    xn[q * 4 + 1] = (v.y - sfm[q * 4 + 1]) * sfr[q * 4 + 1];
    xn[q * 4 + 2] = (v.z - sfm[q * 4 + 2]) * sfr[q * 4 + 2];
    xn[q * 4 + 3] = (v.w - sfm[q * 4 + 3]) * sfr[q * 4 + 3];
  }
  float hid[16];
  #pragma unroll
  for (int h = 0; h < 16; h++) {
    float a = sb1[h];
    #pragma unroll
    for (int k = 0; k < 64; k++) a += xn[k] * sw1[k * 16 + h];
    hid[h] = fmaxf(a, 0.f);
  }
  float4* row = (float4*)(RZ + (size_t)node * 64);
  for (int q = 0; q < 16; q++) {
    float4 rv = row[q];
    float Rv[4] = {rv.x, rv.y, rv.z, rv.w};
    float zo[4];
    #pragma unroll
    for (int j = 0; j < 4; j++) {
      int o = q * 4 + j;
      float a = sb2[o];
      #pragma unroll
      for (int h = 0; h < 16; h++) a += hid[h] * sw2[h * 64 + o];
      float g = 1.f / (1.f + expf(-a));
      float Rn = (Rv[j] - srm[o]) * srr[o];
      float Rf = (2.f - Rv[j] - srm[o]) * srr[o];
      zo[j] = g * Rn + (1.f - g) * Rf;
    }
    row[q] = make_float4(zo[0], zo[1], zo[2], zo[3]);
  }
}

// ---------------- attn MLP + h0 = en*attn (in-place Z -> h0) ----------------
__global__ __launch_bounds__(256) void k_attn(const float* __restrict__ zm, const float* __restrict__ zr,
                                              const float* __restrict__ w1, const float* __restrict__ b1,
                                              const float* __restrict__ w2, const float* __restrict__ b2,
                                              float* __restrict__ ZH) {
  __shared__ float sw1[1024], sw2[1024], sb1[16], sb2[64], szm[64], szr[64];
  for (int i = threadIdx.x; i < 1024; i += 256) { sw1[i] = w1[i]; sw2[i] = w2[i]; }
  if (threadIdx.x < 16) sb1[threadIdx.x] = b1[threadIdx.x];
  if (threadIdx.x < 64) {
    sb2[threadIdx.x] = b2[threadIdx.x];
    szm[threadIdx.x] = zm[threadIdx.x]; szr[threadIdx.x] = zr[threadIdx.x];
  }
  __syncthreads();
  int node = blockIdx.x * 256 + threadIdx.x;
  if (node >= Nn) return;
  float en[64];
  float4* row = (float4*)(ZH + (size_t)node * 64);
  for (int q = 0; q < 16; q++) {
    float4 v = row[q];
    en[q * 4 + 0] = (v.x - szm[q * 4 + 0]) * szr[q * 4 + 0];
    en[q * 4 + 1] = (v.y - szm[q * 4 + 1]) * szr[q * 4 + 1];
    en[q * 4 + 2] = (v.z - szm[q * 4 + 2]) * szr[q * 4 + 2];
    en[q * 4 + 3] = (v.w - szm[q * 4 + 3]) * szr[q * 4 + 3];
  }
  float hid[16];
  #pragma unroll
  for (int h = 0; h < 16; h++) {
    float a = sb1[h];
    #pragma unroll
    for (int k = 0; k < 64; k++) a += en[k] * sw1[k * 16 + h];
    hid[h] = fmaxf(a, 0.f);
  }
  for (int q = 0; q < 16; q++) {
    float ho[4];
    #pragma unroll
    for (int j = 0; j < 4; j++) {
      int o = q * 4 + j;
      float a = sb2[o];
      #pragma unroll
      for (int h = 0; h < 16; h++) a += hid[h] * sw2[h * 64 + o];
      float att = 1.f / (1.f + expf(-a));
      ho[j] = en[o] * att;
    }
    row[q] = make_float4(ho[0], ho[1], ho[2], ho[3]);
  }
}

// ---------------- neighbor-mean pulls ----------------
__global__ __launch_bounds__(256) void k_pull64(const float* __restrict__ X,
                                                const int* __restrict__ cnt,
                                                const int* __restrict__ offs,
                                                const int* __restrict__ csr,
                                                float* __restrict__ out) {
  int wid = threadIdx.x >> 6, lane = threadIdx.x & 63;
  int node = blockIdx.x * 4 + wid;
  if (node >= Nn) return;
  float sum = 0.f;
  int j0 = offs[node], j1 = offs[node + 1];
  for (int j = j0; j < j1; j++) sum += X[(size_t)csr[j] * 64 + lane];
  float inv = 1.f / fmaxf((float)cnt[node], 1.f);
  out[(size_t)node * 64 + lane] = sum * inv;
}

__global__ __launch_bounds__(256) void k_pull256(const float* __restrict__ X,
                                                 const int* __restrict__ cnt,
                                                 const int* __restrict__ offs,
                                                 const int* __restrict__ csr,
                                                 float* __restrict__ out) {
  int wid = threadIdx.x >> 6, lane = threadIdx.x & 63;
  int node = blockIdx.x * 4 + wid;
  if (node >= Nn) return;
  const float4* X4 = (const float4*)X;
  float4 s = make_float4(0.f, 0.f, 0.f, 0.f);
  int j0 = offs[node], j1 = offs[node + 1];
  for (int j = j0; j < j1; j++) {
    float4 v = X4[(size_t)csr[j] * 64 + lane];
    s.x += v.x; s.y += v.y; s.z += v.z; s.w += v.w;
  }
  float inv = 1.f / fmaxf((float)cnt[node], 1.f);
  s.x *= inv; s.y *= inv; s.z *= inv; s.w *= inv;
  ((float4*)out)[(size_t)node * 64 + lane] = s;
}

// ---------------- dual-input fp32 GEMM: C = act(A1@B1 + A2@B2 + bias) ----------------
template <bool RELU>
__global__ __launch_bounds__(256) void k_gemm_dual(const float* __restrict__ A1, const float* __restrict__ B1,
                                                   const float* __restrict__ A2, const float* __restrict__ B2,
                                                   const float* __restrict__ bias, float* __restrict__ Cmat,
                                                   int K, int Nout) {
  constexpr int BK = 16;
  __shared__ float As[BK][65];
  __shared__ float Bs[BK][65];
  int row0 = blockIdx.x * 64, col0 = blockIdx.y * 64;
  int tid = threadIdx.x;
  int tx = tid & 15, ty = tid >> 4;
  float acc[4][4] = {};
  for (int pass = 0; pass < 2; ++pass) {
    const float* A = pass ? A2 : A1;
    const float* B = pass ? B2 : B1;
    for (int k0 = 0; k0 < K; k0 += BK) {
      #pragma unroll
      for (int i = 0; i < 4; i++) {
        int idx = tid + i * 256;
        int m = idx >> 4, k = idx & 15;
        int gr = row0 + m;
        As[k][m] = (gr < Nn) ? A[(size_t)gr * K + k0 + k] : 0.f;
      }
      #pragma unroll
      for (int i = 0; i < 4; i++) {
        int idx = tid + i * 256;
        int n = idx & 63, k = idx >> 6;
        Bs[k][n] = B[(size_t)(k0 + k) * Nout + col0 + n];
      }
      __syncthreads();
      #pragma unroll
      for (int k = 0; k < BK; k++) {
        float a[4], b[4];
        #pragma unroll
        for (int i = 0; i < 4; i++) a[i] = As[k][ty * 4 + i];
        #pragma unroll
        for (int j = 0; j < 4; j++) b[j] = Bs[k][tx * 4 + j];
        #pragma unroll
        for (int i = 0; i < 4; i++)
          #pragma unroll
          for (int j = 0; j < 4; j++) acc[i][j] += a[i] * b[j];
      }
      __syncthreads();
    }
  }
  #pragma unroll
  for (int i = 0; i < 4; i++) {
    int r = row0 + ty * 4 + i;
    if (r >= Nn) continue;
    #pragma unroll
    for (int j = 0; j < 4; j++) {
      int c = col0 + tx * 4 + j;
      float v = acc[i][j] + bias[c];
      if (RELU) v = fmaxf(v, 0.f);
      Cmat[(size_t)r * Nout + c] = v;
    }
  }
}

// ---------------- classifier: [N,128] @ [128,8] + b ----------------
__global__ __launch_bounds__(256) void k_cls(const float* __restrict__ X, const float* __restrict__ W,
                                             const float* __restrict__ B, float* __restrict__ out) {
  __shared__ float sw[1024];
  __shared__ float sb[8];
  for (int i = threadIdx.x; i < 1024; i += 256) sw[i] = W[i];
  if (threadIdx.x < 8) sb[threadIdx.x] = B[threadIdx.x];
  __syncthreads();
  int node = blockIdx.x * 256 + threadIdx.x;
  if (node >= Nn) return;
  float acc[8];
  #pragma unroll
  for (int o = 0; o < 8; o++) acc[o] = sb[o];
  const float4* xr = (const float4*)(X + (size_t)node * 128);
  for (int k4 = 0; k4 < 32; k4++) {
    float4 v = xr[k4];
    float vv[4] = {v.x, v.y, v.z, v.w};
    #pragma unroll
    for (int j = 0; j < 4; j++) {
      int k = k4 * 4 + j;
      #pragma unroll
      for (int o = 0; o < 8; o++) acc[o] += vv[j] * sw[k * 8 + o];
    }
  }
  float4* orow = (float4*)(out + (size_t)node * 8);
  orow[0] = make_float4(acc[0], acc[1], acc[2], acc[3]);
  orow[1] = make_float4(acc[4], acc[5], acc[6], acc[7]);
}

extern "C" void kernel_launch(void* const* d_in, const int* in_sizes, int n_in,
                              void* d_out, int out_size, void* d_ws, size_t ws_size,
                              hipStream_t stream) {
  (void)in_sizes; (void)n_in; (void)out_size; (void)ws_size;
  const float* feat = (const float*)d_in[0];
  const int* eidx = (const int*)d_in[1];
  const int* esrc = eidx;
  const int* edst = eidx + Ee;
  const float* gw1 = (const float*)d_in[2];  const float* gb1 = (const float*)d_in[3];
  const float* gw2 = (const float*)d_in[4];  const float* gb2 = (const float*)d_in[5];
  const float* aw1 = (const float*)d_in[6];  const float* ab1 = (const float*)d_in[7];
  const float* aw2 = (const float*)d_in[8];  const float* ab2 = (const float*)d_in[9];
  const float* c1ws = (const float*)d_in[10]; const float* c1wn = (const float*)d_in[11]; const float* c1b = (const float*)d_in[12];
  const float* c2ws = (const float*)d_in[13]; const float* c2wn = (const float*)d_in[14]; const float* c2b = (const float*)d_in[15];
  const float* c3ws = (const float*)d_in[16]; const float* c3wn = (const float*)d_in[17]; const float* c3b = (const float*)d_in[18];
  const float* clw = (const float*)d_in[19];  const float* clb = (const float*)d_in[20];
  float* out = (float*)d_out;

  char* ws = (char*)d_ws;
  size_t off = 0;
  auto alloc = [&](size_t b) -> char* {
    char* p = ws + off;
    off = (off + b + 255) & ~(size_t)255;
    return p;
  };
  int* cnt = (int*)alloc(Nn * 4);
  int* cur = (int*)alloc(Nn * 4);
  double* accF = (double*)alloc(128 * 8);
  double* accR = (double*)alloc(128 * 8);
  double* accZ = (double*)alloc(128 * 8);
  size_t zbytes = off;  // everything above must be zeroed
  int* offs = (int*)alloc((size_t)(Nn + 1) * 4);
  int* csr = (int*)alloc((size_t)Ee * 4);
  float* fm = (float*)alloc(64 * 4); float* fr = (float*)alloc(64 * 4);
  float* rm = (float*)alloc(64 * 4); float* rr = (float*)alloc(64 * 4);
  float* zm = (float*)alloc(64 * 4); float* zr = (float*)alloc(64 * 4);
  float* X1 = (float*)alloc((size_t)Nn * 64 * 4);
  float* X2 = (float*)alloc((size_t)Nn * 64 * 4);
  float* X3 = (float*)alloc((size_t)Nn * 256 * 4);
  float* X4 = (float*)alloc((size_t)Nn * 256 * 4);
  float* X5 = (float*)alloc((size_t)Nn * 256 * 4);

  hipMemsetAsync(d_ws, 0, zbytes, stream);

  int eb = (Ee + 255) / 256;
  hipLaunchKernelGGL(k_count, dim3(eb), dim3(256), 0, stream, edst, cnt);
  hipLaunchKernelGGL(k_scan, dim3(1), dim3(1024), 0, stream, cnt, offs);
  hipLaunchKernelGGL(k_scatter, dim3(eb), dim3(256), 0, stream, esrc, edst, offs, cur, csr);

  hipLaunchKernelGGL(k_stats, dim3(49), dim3(256), 0, stream, feat, accF);
  hipLaunchKernelGGL(k_stats_final, dim3(1), dim3(64), 0, stream, accF, fm, fr);

  hipLaunchKernelGGL(k_energy, dim3((Nn + 3) / 4), dim3(256), 0, stream, feat, cnt, offs, csr, X1);
  hipLaunchKernelGGL(k_stats, dim3(49), dim3(256), 0, stream, X1, accR);
  hipLaunchKernelGGL(k_stats_final, dim3(1), dim3(64), 0, stream, accR, rm, rr);

  hipLaunchKernelGGL(k_gate, dim3((Nn + 255) / 256), dim3(256), 0, stream,
                     feat, fm, fr, rm, rr, gw1, gb1, gw2, gb2, X1);
  hipLaunchKernelGGL(k_stats, dim3(49), dim3(256), 0, stream, X1, accZ);
  hipLaunchKernelGGL(k_stats_final, dim3(1), dim3(64), 0, stream, accZ, zm, zr);

  hipLaunchKernelGGL(k_attn, dim3((Nn + 255) / 256), dim3(256), 0, stream,
                     zm, zr, aw1, ab1, aw2, ab2, X1);

  hipLaunchKernelGGL(k_pull64, dim3((Nn + 3) / 4), dim3(256), 0, stream, X1, cnt, offs, csr, X2);
  hipLaunchKernelGGL((k_gemm_dual<true>), dim3(782, 4), dim3(256), 0, stream,
                     X1, c1ws, X2, c1wn, c1b, X3, 64, 256);
  hipLaunchKernelGGL(k_pull256, dim3((Nn + 3) / 4), dim3(256), 0, stream, X3, cnt, offs, csr, X4);
  hipLaunchKernelGGL((k_gemm_dual<true>), dim3(782, 4), dim3(256), 0, stream,
                     X3, c2ws, X4, c2wn, c2b, X5, 256, 256);
  hipLaunchKernelGGL(k_pull256, dim3((Nn + 3) / 4), dim3(256), 0, stream, X5, cnt, offs, csr, X3);
  hipLaunchKernelGGL((k_gemm_dual<true>), dim3(782, 2), dim3(256), 0, stream,
                     X5, c3ws, X3, c3wn, c3b, X4, 256, 128);
  hipLaunchKernelGGL(k_cls, dim3((Nn + 255) / 256), dim3(256), 0, stream, X4, clw, clb, out);
}

// Round 2
// 1157.811 us; speedup vs baseline: 1.3179x; 1.3179x over previous
//
#include <hip/hip_runtime.h>
#include <math.h>

constexpr int Nn = 50000;
constexpr int Ee = 800000;

typedef __attribute__((ext_vector_type(8))) short short8;
typedef __attribute__((ext_vector_type(4))) float f32x4;

__device__ inline unsigned short f2bf_rtn(float f) {
  union { float f; unsigned u; } v; v.f = f;
  unsigned r = v.u + 0x7FFFu + ((v.u >> 16) & 1u);
  return (unsigned short)(r >> 16);
}
__device__ inline float bf2f(unsigned short h) {
  union { unsigned u; float f; } v; v.u = ((unsigned)h) << 16;
  return v.f;
}

// ---------------- CSR build ----------------
__global__ void k_count(const int* __restrict__ dst, int* __restrict__ cnt) {
  int e = blockIdx.x * 256 + threadIdx.x;
  if (e < Ee) atomicAdd(&cnt[dst[e]], 1);
}

__global__ __launch_bounds__(1024) void k_scan(const int* __restrict__ cnt, int* __restrict__ offs) {
  __shared__ int sh[1024];
  int t = threadIdx.x;
  const int CH = (Nn + 1023) / 1024;
  int s0 = t * CH, s1 = min(s0 + CH, Nn);
  int lsum = 0;
  for (int i = s0; i < s1; i++) lsum += cnt[i];
  sh[t] = lsum;
  __syncthreads();
  for (int off = 1; off < 1024; off <<= 1) {
    int v = (t >= off) ? sh[t - off] : 0;
    __syncthreads();
    sh[t] += v;
    __syncthreads();
  }
  int base = sh[t] - lsum;
  for (int i = s0; i < s1; i++) { offs[i] = base; base += cnt[i]; }
  if (t == 1023) offs[Nn] = sh[1023];
}

__global__ void k_scatter(const int* __restrict__ src, const int* __restrict__ dst,
                          const int* __restrict__ offs, int* __restrict__ cur,
                          int* __restrict__ csr) {
  int e = blockIdx.x * 256 + threadIdx.x;
  if (e < Ee) {
    int d = dst[e];
    int p = offs[d] + atomicAdd(&cur[d], 1);
    csr[p] = src[e];
  }
}

// ---------------- column stats (64-wide, ddof=1) ----------------
__global__ __launch_bounds__(256) void k_stats(const float* __restrict__ X, double* __restrict__ acc) {
  int col = threadIdx.x & 63, rs_ = threadIdx.x >> 6;
  int row0 = blockIdx.x * 1024;
  int rend = min(row0 + 1024, Nn);
  double s = 0.0, ss = 0.0;
  for (int r = row0 + rs_; r < rend; r += 4) {
    float v = X[(size_t)r * 64 + col];
    s += v; ss += (double)v * v;
  }
  __shared__ double sh[512];
  sh[threadIdx.x] = s; sh[256 + threadIdx.x] = ss;
  __syncthreads();
  if (rs_ == 0) {
    s = sh[col] + sh[col + 64] + sh[col + 128] + sh[col + 192];
    ss = sh[256 + col] + sh[256 + col + 64] + sh[256 + col + 128] + sh[256 + col + 192];
    atomicAdd(&acc[col], s);
    atomicAdd(&acc[64 + col], ss);
  }
}

__global__ void k_stats_final(const double* __restrict__ acc, float* __restrict__ mean,
                              float* __restrict__ rstd) {
  int c = threadIdx.x;
  if (c < 64) {
    double s = acc[c], ss = acc[64 + c];
    double m = s / (double)Nn;
    double var = (ss - s * s / (double)Nn) / (double)(Nn - 1);
    double sd = sqrt(var > 0.0 ? var : 0.0);
    if (sd < 1e-8) sd = 1e-8;
    mean[c] = (float)m;
    rstd[c] = (float)(1.0 / sd);
  }
}

// ---------------- local Dirichlet energy (pull over in-edges) ----------------
__global__ __launch_bounds__(256) void k_energy(const float* __restrict__ X,
                                                const int* __restrict__ cnt,
                                                const int* __restrict__ offs,
                                                const int* __restrict__ csr,
                                                float* __restrict__ R) {
  int wid = threadIdx.x >> 6, lane = threadIdx.x & 63;
  int node = blockIdx.x * 4 + wid;
  if (node >= Nn) return;
  int deg = cnt[node];
  float degf = (float)deg;
  float inv_i = rsqrtf(fmaxf(degf, 1e-12f));
  float xi = X[(size_t)node * 64 + lane] * inv_i;
  float num = 0.f, den = degf * xi * xi;
  int j0 = offs[node], j1 = offs[node + 1];
  for (int j = j0; j < j1; j++) {
    int s = csr[j];
    float inv_s = rsqrtf(fmaxf((float)cnt[s], 1e-12f));
    float xs = X[(size_t)s * 64 + lane] * inv_s;
    float d = xi - xs;
    num += d * d;
    den += xs * xs;
  }
  R[(size_t)node * 64 + lane] = num / (den + 1e-8f);
}

// ---------------- gate MLP + Z (in-place R -> Z, fp32) ----------------
__global__ __launch_bounds__(256) void k_gate(const float* __restrict__ feat,
                                              const float* __restrict__ fm, const float* __restrict__ fr,
                                              const float* __restrict__ rm, const float* __restrict__ rr,
                                              const float* __restrict__ w1, const float* __restrict__ b1,
                                              const float* __restrict__ w2, const float* __restrict__ b2,
                                              float* __restrict__ RZ) {
  __shared__ float sw1[1024], sw2[1024], sb1[16], sb2[64], sfm[64], sfr[64], srm[64], srr[64];
  for (int i = threadIdx.x; i < 1024; i += 256) { sw1[i] = w1[i]; sw2[i] = w2[i]; }
  if (threadIdx.x < 16) sb1[threadIdx.x] = b1[threadIdx.x];
  if (threadIdx.x < 64) {
    sb2[threadIdx.x] = b2[threadIdx.x];
    sfm[threadIdx.x] = fm[threadIdx.x]; sfr[threadIdx.x] = fr[threadIdx.x];
    srm[threadIdx.x] = rm[threadIdx.x]; srr[threadIdx.x] = rr[threadIdx.x];
  }
  __syncthreads();
  int node = blockIdx.x * 256 + threadIdx.x;
  if (node >= Nn) return;
  float xn[64];
  const float4* fx = (const float4*)(feat + (size_t)node * 64);
  for (int q = 0; q < 16; q++) {
    float4 v = fx[q];
    xn[q * 4 + 0] = (v.x - sfm[q * 4 + 0]) * sfr[q * 4 + 0];
    xn[q * 4 + 1] = (v.y - sfm[q * 4 + 1]) * sfr[q * 4 + 1];
    xn[q * 4 + 2] = (v.z - sfm[q * 4 + 2]) * sfr[q * 4 + 2];
    xn[q * 4 + 3] = (v.w - sfm[q * 4 + 3]) * sfr[q * 4 + 3];
  }
  float hid[16];
  #pragma unroll
  for (int h = 0; h < 16; h++) {
    float a = sb1[h];
    #pragma unroll
    for (int k = 0; k < 64; k++) a += xn[k] * sw1[k * 16 + h];
    hid[h] = fmaxf(a, 0.f);
  }
  float4* row = (float4*)(RZ + (size_t)node * 64);
  for (int q = 0; q < 16; q++) {
    float4 rv = row[q];
    float Rv[4] = {rv.x, rv.y, rv.z, rv.w};
    float zo[4];
    #pragma unroll
    for (int j = 0; j < 4; j++) {
      int o = q * 4 + j;
      float a = sb2[o];
      #pragma unroll
      for (int h = 0; h < 16; h++) a += hid[h] * sw2[h * 64 + o];
      float g = 1.f / (1.f + expf(-a));
      float Rn = (Rv[j] - srm[o]) * srr[o];
      float Rf = (2.f - Rv[j] - srm[o]) * srr[o];
      zo[j] = g * Rn + (1.f - g) * Rf;
    }
    row[q] = make_float4(zo[0], zo[1], zo[2], zo[3]);
  }
}

// ---------------- attn MLP + h0 = en*attn (Z fp32 -> H0 hi/lo bf16) ----------------
__global__ __launch_bounds__(256) void k_attn(const float* __restrict__ zm, const float* __restrict__ zr,
                                              const float* __restrict__ w1, const float* __restrict__ b1,
                                              const float* __restrict__ w2, const float* __restrict__ b2,
                                              const float* __restrict__ Zf,
                                              unsigned short* __restrict__ Hh,
                                              unsigned short* __restrict__ Hl) {
  __shared__ float sw1[1024], sw2[1024], sb1[16], sb2[64], szm[64], szr[64];
  for (int i = threadIdx.x; i < 1024; i += 256) { sw1[i] = w1[i]; sw2[i] = w2[i]; }
  if (threadIdx.x < 16) sb1[threadIdx.x] = b1[threadIdx.x];
  if (threadIdx.x < 64) {
    sb2[threadIdx.x] = b2[threadIdx.x];
    szm[threadIdx.x] = zm[threadIdx.x]; szr[threadIdx.x] = zr[threadIdx.x];
  }
  __syncthreads();
  int node = blockIdx.x * 256 + threadIdx.x;
  if (node >= Nn) return;
  float en[64];
  const float4* row = (const float4*)(Zf + (size_t)node * 64);
  for (int q = 0; q < 16; q++) {
    float4 v = row[q];
    en[q * 4 + 0] = (v.x - szm[q * 4 + 0]) * szr[q * 4 + 0];
    en[q * 4 + 1] = (v.y - szm[q * 4 + 1]) * szr[q * 4 + 1];
    en[q * 4 + 2] = (v.z - szm[q * 4 + 2]) * szr[q * 4 + 2];
    en[q * 4 + 3] = (v.w - szm[q * 4 + 3]) * szr[q * 4 + 3];
  }
  float hid[16];
  #pragma unroll
  for (int h = 0; h < 16; h++) {
    float a = sb1[h];
    #pragma unroll
    for (int k = 0; k < 64; k++) a += en[k] * sw1[k * 16 + h];
    hid[h] = fmaxf(a, 0.f);
  }
  for (int q = 0; q < 16; q++) {
    ushort4 oh, ol;
    unsigned short hq[4], lq[4];
    #pragma unroll
    for (int j = 0; j < 4; j++) {
      int o = q * 4 + j;
      float a = sb2[o];
      #pragma unroll
      for (int h = 0; h < 16; h++) a += hid[h] * sw2[h * 64 + o];
      float att = 1.f / (1.f + expf(-a));
      float v = en[o] * att;
      hq[j] = f2bf_rtn(v);
      lq[j] = f2bf_rtn(v - bf2f(hq[j]));
    }
    oh.x = hq[0]; oh.y = hq[1]; oh.z = hq[2]; oh.w = hq[3];
    ol.x = lq[0]; ol.y = lq[1]; ol.z = lq[2]; ol.w = lq[3];
    *(ushort4*)(Hh + (size_t)node * 64 + q * 4) = oh;
    *(ushort4*)(Hl + (size_t)node * 64 + q * 4) = ol;
  }
}

// ---------------- neighbor-mean pulls (hi/lo bf16 in, hi/lo bf16 out) ----------------
__global__ __launch_bounds__(256) void k_pull64hl(const unsigned short* __restrict__ Xh,
                                                  const unsigned short* __restrict__ Xl,
                                                  const int* __restrict__ cnt,
                                                  const int* __restrict__ offs,
                                                  const int* __restrict__ csr,
                                                  unsigned short* __restrict__ Oh,
                                                  unsigned short* __restrict__ Ol) {
  int wid = threadIdx.x >> 6, lane = threadIdx.x & 63;
  int node = blockIdx.x * 4 + wid;
  if (node >= Nn) return;
  float s = 0.f;
  int j0 = offs[node], j1 = offs[node + 1];
  for (int j = j0; j < j1; j++) {
    size_t b = (size_t)csr[j] * 64 + lane;
    s += bf2f(Xh[b]) + bf2f(Xl[b]);
  }
  s *= 1.f / fmaxf((float)cnt[node], 1.f);
  unsigned short h = f2bf_rtn(s);
  Oh[(size_t)node * 64 + lane] = h;
  Ol[(size_t)node * 64 + lane] = f2bf_rtn(s - bf2f(h));
}

__global__ __launch_bounds__(256) void k_pull256hl(const unsigned short* __restrict__ Xh,
                                                   const unsigned short* __restrict__ Xl,
                                                   const int* __restrict__ cnt,
                                                   const int* __restrict__ offs,
                                                   const int* __restrict__ csr,
                                                   unsigned short* __restrict__ Oh,
                                                   unsigned short* __restrict__ Ol) {
  int wid = threadIdx.x >> 6, lane = threadIdx.x & 63;
  int node = blockIdx.x * 4 + wid;
  if (node >= Nn) return;
  float s0 = 0.f, s1 = 0.f, s2 = 0.f, s3 = 0.f;
  int j0 = offs[node], j1 = offs[node + 1];
  for (int j = j0; j < j1; j++) {
    size_t b = (size_t)csr[j] * 256 + lane * 4;
    ushort4 h4 = *(const ushort4*)(Xh + b);
    ushort4 l4 = *(const ushort4*)(Xl + b);
    s0 += bf2f(h4.x) + bf2f(l4.x);
    s1 += bf2f(h4.y) + bf2f(l4.y);
    s2 += bf2f(h4.z) + bf2f(l4.z);
    s3 += bf2f(h4.w) + bf2f(l4.w);
  }
  float inv = 1.f / fmaxf((float)cnt[node], 1.f);
  s0 *= inv; s1 *= inv; s2 *= inv; s3 *= inv;
  ushort4 oh, ol;
  oh.x = f2bf_rtn(s0); ol.x = f2bf_rtn(s0 - bf2f(oh.x));
  oh.y = f2bf_rtn(s1); ol.y = f2bf_rtn(s1 - bf2f(oh.y));
  oh.z = f2bf_rtn(s2); ol.z = f2bf_rtn(s2 - bf2f(oh.z));
  oh.w = f2bf_rtn(s3); ol.w = f2bf_rtn(s3 - bf2f(oh.w));
  *(ushort4*)(Oh + (size_t)node * 256 + lane * 4) = oh;
  *(ushort4*)(Ol + (size_t)node * 256 + lane * 4) = ol;
}

// ---------------- weight prep: W[K][N] fp32 -> Wt hi/lo [N][K] bf16 ----------------
__global__ void k_prep(const float* __restrict__ W, int K, int N,
                       unsigned short* __restrict__ Hi, unsigned short* __restrict__ Lo) {
  int idx = blockIdx.x * 256 + threadIdx.x;
  if (idx >= K * N) return;
  int k = idx / N, n = idx - k * N;
  float x = W[idx];
  unsigned short h = f2bf_rtn(x);
  Hi[(size_t)n * K + k] = h;
  Lo[(size_t)n * K + k] = f2bf_rtn(x - bf2f(h));
}

// ---------------- split-bf16 MFMA GEMM: C = relu(A1@B1 + A2@B2 + bias) ----------------
// A given as hi/lo bf16 [M][K]; B given as hi/lo bf16 [N][K] (pre-transposed).
// 3-MFMA emulation: Ahi*Bhi + Ahi*Blo + Alo*Bhi  (error ~2^-17 per product).
template <bool OUTF32>
__global__ __launch_bounds__(256) void k_gemm(
    const unsigned short* __restrict__ A1h, const unsigned short* __restrict__ A1l,
    const unsigned short* __restrict__ B1h, const unsigned short* __restrict__ B1l,
    const unsigned short* __restrict__ A2h, const unsigned short* __restrict__ A2l,
    const unsigned short* __restrict__ B2h, const unsigned short* __restrict__ B2l,
    const float* __restrict__ bias,
    unsigned short* __restrict__ Ch, unsigned short* __restrict__ Cl,
    float* __restrict__ Cf, int K, int Nout) {
  __shared__ __align__(16) unsigned short Ah[128 * 32];
  __shared__ __align__(16) unsigned short Al[128 * 32];
  __shared__ __align__(16) unsigned short Bh[128 * 32];
  __shared__ __align__(16) unsigned short Bl[128 * 32];
  const int tid = threadIdx.x;
  const int lane = tid & 63;
  const int wid = tid >> 6;
  const int l15 = lane & 15, l4 = lane >> 4;
  const int wm = (wid >> 1) * 64, wn = (wid & 1) * 64;
  const int row0 = blockIdx.x * 128, col0 = blockIdx.y * 128;
  const int sr = tid >> 2;          // staging row (0..63), +64 second chunk
  const int sc = (tid & 3) * 8;     // staging k offset (elements)
  f32x4 acc[4][4];
  #pragma unroll
  for (int s = 0; s < 4; ++s)
    #pragma unroll
    for (int t = 0; t < 4; ++t) acc[s][t] = (f32x4)0.0f;

  for (int pass = 0; pass < 2; ++pass) {
    const unsigned short* Agh = pass ? A2h : A1h;
    const unsigned short* Agl = pass ? A2l : A1l;
    const unsigned short* Bgh = pass ? B2h : B1h;
    const unsigned short* Bgl = pass ? B2l : B1l;
    for (int k0 = 0; k0 < K; k0 += 32) {
      __syncthreads();
      #pragma unroll
      for (int i = 0; i < 2; ++i) {
        int r = sr + i * 64;
        int gr = row0 + r;
        short8 vh = {0, 0, 0, 0, 0, 0, 0, 0}, vl = {0, 0, 0, 0, 0, 0, 0, 0};
        if (gr < Nn) {
          vh = *(const short8*)(Agh + (size_t)gr * K + k0 + sc);
          vl = *(const short8*)(Agl + (size_t)gr * K + k0 + sc);
        }
        *(short8*)&Ah[r * 32 + sc] = vh;
        *(short8*)&Al[r * 32 + sc] = vl;
        int br = col0 + r;
        *(short8*)&Bh[r * 32 + sc] = *(const short8*)(Bgh + (size_t)br * K + k0 + sc);
        *(short8*)&Bl[r * 32 + sc] = *(const short8*)(Bgl + (size_t)br * K + k0 + sc);
      }
      __syncthreads();
      short8 bhf[4], blf[4];
      #pragma unroll
      for (int t = 0; t < 4; ++t) {
        bhf[t] = *(const short8*)&Bh[(wn + t * 16 + l15) * 32 + l4 * 8];
        blf[t] = *(const short8*)&Bl[(wn + t * 16 + l15) * 32 + l4 * 8];
      }
      #pragma unroll
      for (int s = 0; s < 4; ++s) {
        short8 ah = *(const short8*)&Ah[(wm + s * 16 + l15) * 32 + l4 * 8];
        short8 al = *(const short8*)&Al[(wm + s * 16 + l15) * 32 + l4 * 8];
        #pragma unroll
        for (int t = 0; t < 4; ++t) {
          acc[s][t] = __builtin_amdgcn_mfma_f32_16x16x32_bf16(ah, bhf[t], acc[s][t], 0, 0, 0);
          acc[s][t] = __builtin_amdgcn_mfma_f32_16x16x32_bf16(ah, blf[t], acc[s][t], 0, 0, 0);
          acc[s][t] = __builtin_amdgcn_mfma_f32_16x16x32_bf16(al, bhf[t], acc[s][t], 0, 0, 0);
        }
      }
    }
  }
  #pragma unroll
  for (int s = 0; s < 4; ++s) {
    #pragma unroll
    for (int t = 0; t < 4; ++t) {
      int col = col0 + wn + t * 16 + l15;
      float bv = bias[col];
      #pragma unroll
      for (int j = 0; j < 4; ++j) {
        int row = row0 + wm + s * 16 + l4 * 4 + j;
        if (row < Nn) {
          float v = fmaxf(acc[s][t][j] + bv, 0.f);
          if (OUTF32) {
            Cf[(size_t)row * Nout + col] = v;
          } else {
            unsigned short h = f2bf_rtn(v);
            Ch[(size_t)row * Nout + col] = h;
            Cl[(size_t)row * Nout + col] = f2bf_rtn(v - bf2f(h));
          }
        }
      }
    }
  }
}

// ---------------- classifier: [N,128] @ [128,8] + b ----------------
__global__ __launch_bounds__(256) void k_cls(const float* __restrict__ X, const float* __restrict__ W,
                                             const float* __restrict__ B, float* __restrict__ out) {
  __shared__ float sw[1024];
  __shared__ float sb[8];
  for (int i = threadIdx.x; i < 1024; i += 256) sw[i] = W[i];
  if (threadIdx.x < 8) sb[threadIdx.x] = B[threadIdx.x];
  __syncthreads();
  int node = blockIdx.x * 256 + threadIdx.x;
  if (node >= Nn) return;
  float acc[8];
  #pragma unroll
  for (int o = 0; o < 8; o++) acc[o] = sb[o];
  const float4* xr = (const float4*)(X + (size_t)node * 128);
  for (int k4 = 0; k4 < 32; k4++) {
    float4 v = xr[k4];
    float vv[4] = {v.x, v.y, v.z, v.w};
    #pragma unroll
    for (int j = 0; j < 4; j++) {
      int k = k4 * 4 + j;
      #pragma unroll
      for (int o = 0; o < 8; o++) acc[o] += vv[j] * sw[k * 8 + o];
    }
  }
  float4* orow = (float4*)(out + (size_t)node * 8);
  orow[0] = make_float4(acc[0], acc[1], acc[2], acc[3]);
  orow[1] = make_float4(acc[4], acc[5], acc[6], acc[7]);
}

extern "C" void kernel_launch(void* const* d_in, const int* in_sizes, int n_in,
                              void* d_out, int out_size, void* d_ws, size_t ws_size,
                              hipStream_t stream) {
  (void)in_sizes; (void)n_in; (void)out_size; (void)ws_size;
  const float* feat = (const float*)d_in[0];
  const int* eidx = (const int*)d_in[1];
  const int* esrc = eidx;
  const int* edst = eidx + Ee;
  const float* gw1 = (const float*)d_in[2];  const float* gb1 = (const float*)d_in[3];
  const float* gw2 = (const float*)d_in[4];  const float* gb2 = (const float*)d_in[5];
  const float* aw1 = (const float*)d_in[6];  const float* ab1 = (const float*)d_in[7];
  const float* aw2 = (const float*)d_in[8];  const float* ab2 = (const float*)d_in[9];
  const float* c1ws = (const float*)d_in[10]; const float* c1wn = (const float*)d_in[11]; const float* c1b = (const float*)d_in[12];
  const float* c2ws = (const float*)d_in[13]; const float* c2wn = (const float*)d_in[14]; const float* c2b = (const float*)d_in[15];
  const float* c3ws = (const float*)d_in[16]; const float* c3wn = (const float*)d_in[17]; const float* c3b = (const float*)d_in[18];
  const float* clw = (const float*)d_in[19];  const float* clb = (const float*)d_in[20];
  float* out = (float*)d_out;

  char* ws = (char*)d_ws;
  size_t off = 0;
  auto alloc = [&](size_t b) -> char* {
    char* p = ws + off;
    off = (off + b + 255) & ~(size_t)255;
    return p;
  };
  int* cnt = (int*)alloc(Nn * 4);
  int* cur = (int*)alloc(Nn * 4);
  double* accF = (double*)alloc(128 * 8);
  double* accR = (double*)alloc(128 * 8);
  double* accZ = (double*)alloc(128 * 8);
  size_t zbytes = off;  // region above must be zeroed
  int* offs = (int*)alloc((size_t)(Nn + 1) * 4);
  int* csr = (int*)alloc((size_t)Ee * 4);
  float* fm = (float*)alloc(64 * 4); float* fr = (float*)alloc(64 * 4);
  float* rm = (float*)alloc(64 * 4); float* rr = (float*)alloc(64 * 4);
  float* zm = (float*)alloc(64 * 4); float* zr = (float*)alloc(64 * 4);
  // weight splits (transposed [N][K])
  unsigned short* B1sh = (unsigned short*)alloc(64 * 256 * 2);
  unsigned short* B1sl = (unsigned short*)alloc(64 * 256 * 2);
  unsigned short* B1nh = (unsigned short*)alloc(64 * 256 * 2);
  unsigned short* B1nl = (unsigned short*)alloc(64 * 256 * 2);
  unsigned short* B2sh = (unsigned short*)alloc(256 * 256 * 2);
  unsigned short* B2sl = (unsigned short*)alloc(256 * 256 * 2);
  unsigned short* B2nh = (unsigned short*)alloc(256 * 256 * 2);
  unsigned short* B2nl = (unsigned short*)alloc(256 * 256 * 2);
  unsigned short* B3sh = (unsigned short*)alloc(256 * 128 * 2);
  unsigned short* B3sl = (unsigned short*)alloc(256 * 128 * 2);
  unsigned short* B3nh = (unsigned short*)alloc(256 * 128 * 2);
  unsigned short* B3nl = (unsigned short*)alloc(256 * 128 * 2);
  // activations: contiguous 25.6MB region {Zf(12.8) | H0h(6.4) | H0l(6.4)}
  float* Zf = (float*)alloc((size_t)Nn * 64 * 4);           // also hosts AG0 later
  unsigned short* H0h = (unsigned short*)alloc((size_t)Nn * 64 * 2);
  unsigned short* H0l = (unsigned short*)alloc((size_t)Nn * 64 * 2);
  unsigned short* AG0h = (unsigned short*)Zf;               // alias (Zf dead after k_attn)
  unsigned short* AG0l = (unsigned short*)Zf + (size_t)Nn * 64;
  unsigned short* H1h = (unsigned short*)alloc((size_t)Nn * 256 * 2);
  unsigned short* H1l = (unsigned short*)alloc((size_t)Nn * 256 * 2);
  unsigned short* AG1h = (unsigned short*)alloc((size_t)Nn * 256 * 2);
  unsigned short* AG1l = (unsigned short*)alloc((size_t)Nn * 256 * 2);
  unsigned short* H2h = (unsigned short*)Zf;                // alias 25.6MB (Zf+H0 dead after GEMM1)
  unsigned short* H2l = (unsigned short*)alloc((size_t)Nn * 256 * 2);
  unsigned short* AG2h = H1h;                               // alias (H1 dead after GEMM2)
  unsigned short* AG2l = H1l;
  float* H3f = (float*)AG1h;                                // alias 25.6MB (AG1 dead after GEMM2)

  hipMemsetAsync(d_ws, 0, zbytes, stream);

  // weight prep
  hipLaunchKernelGGL(k_prep, dim3(64), dim3(256), 0, stream, c1ws, 64, 256, B1sh, B1sl);
  hipLaunchKernelGGL(k_prep, dim3(64), dim3(256), 0, stream, c1wn, 64, 256, B1nh, B1nl);
  hipLaunchKernelGGL(k_prep, dim3(256), dim3(256), 0, stream, c2ws, 256, 256, B2sh, B2sl);
  hipLaunchKernelGGL(k_prep, dim3(256), dim3(256), 0, stream, c2wn, 256, 256, B2nh, B2nl);
  hipLaunchKernelGGL(k_prep, dim3(128), dim3(256), 0, stream, c3ws, 256, 128, B3sh, B3sl);
  hipLaunchKernelGGL(k_prep, dim3(128), dim3(256), 0, stream, c3wn, 256, 128, B3nh, B3nl);

  int eb = (Ee + 255) / 256;
  hipLaunchKernelGGL(k_count, dim3(eb), dim3(256), 0, stream, edst, cnt);
  hipLaunchKernelGGL(k_scan, dim3(1), dim3(1024), 0, stream, cnt, offs);
  hipLaunchKernelGGL(k_scatter, dim3(eb), dim3(256), 0, stream, esrc, edst, offs, cur, csr);

  hipLaunchKernelGGL(k_stats, dim3(49), dim3(256), 0, stream, feat, accF);
  hipLaunchKernelGGL(k_stats_final, dim3(1), dim3(64), 0, stream, accF, fm, fr);

  hipLaunchKernelGGL(k_energy, dim3((Nn + 3) / 4), dim3(256), 0, stream, feat, cnt, offs, csr, Zf);
  hipLaunchKernelGGL(k_stats, dim3(49), dim3(256), 0, stream, Zf, accR);
  hipLaunchKernelGGL(k_stats_final, dim3(1), dim3(64), 0, stream, accR, rm, rr);

  hipLaunchKernelGGL(k_gate, dim3((Nn + 255) / 256), dim3(256), 0, stream,
                     feat, fm, fr, rm, rr, gw1, gb1, gw2, gb2, Zf);
  hipLaunchKernelGGL(k_stats, dim3(49), dim3(256), 0, stream, Zf, accZ);
  hipLaunchKernelGGL(k_stats_final, dim3(1), dim3(64), 0, stream, accZ, zm, zr);

  hipLaunchKernelGGL(k_attn, dim3((Nn + 255) / 256), dim3(256), 0, stream,
                     zm, zr, aw1, ab1, aw2, ab2, Zf, H0h, H0l);

  hipLaunchKernelGGL(k_pull64hl, dim3((Nn + 3) / 4), dim3(256), 0, stream,
                     H0h, H0l, cnt, offs, csr, AG0h, AG0l);
  hipLaunchKernelGGL((k_gemm<false>), dim3(391, 2), dim3(256), 0, stream,
                     H0h, H0l, B1sh, B1sl, AG0h, AG0l, B1nh, B1nl, c1b,
                     H1h, H1l, (float*)nullptr, 64, 256);
  hipLaunchKernelGGL(k_pull256hl, dim3((Nn + 3) / 4), dim3(256), 0, stream,
                     H1h, H1l, cnt, offs, csr, AG1h, AG1l);
  hipLaunchKernelGGL((k_gemm<false>), dim3(391, 2), dim3(256), 0, stream,
                     H1h, H1l, B2sh, B2sl, AG1h, AG1l, B2nh, B2nl, c2b,
                     H2h, H2l, (float*)nullptr, 256, 256);
  hipLaunchKernelGGL(k_pull256hl, dim3((Nn + 3) / 4), dim3(256), 0, stream,
                     H2h, H2l, cnt, offs, csr, AG2h, AG2l);
  hipLaunchKernelGGL((k_gemm<true>), dim3(391, 1), dim3(256), 0, stream,
                     H2h, H2l, B3sh, B3sl, AG2h, AG2l, B3nh, B3nl, c3b,
                     (unsigned short*)nullptr, (unsigned short*)nullptr, H3f, 256, 128);
  hipLaunchKernelGGL(k_cls, dim3((Nn + 255) / 256), dim3(256), 0, stream, H3f, clw, clb, out);
}

// Round 3
// 1126.021 us; speedup vs baseline: 1.3551x; 1.0282x over previous
//
#include <hip/hip_runtime.h>
#include <math.h>

constexpr int Nn = 50000;
constexpr int Ee = 800000;

typedef __attribute__((ext_vector_type(8))) short short8;
typedef __attribute__((ext_vector_type(4))) float f32x4;

__device__ inline unsigned short f2bf_rtn(float f) {
  union { float f; unsigned u; } v; v.f = f;
  unsigned r = v.u + 0x7FFFu + ((v.u >> 16) & 1u);
  return (unsigned short)(r >> 16);
}
__device__ inline float bf2f(unsigned short h) {
  union { unsigned u; float f; } v; v.u = ((unsigned)h) << 16;
  return v.f;
}

// ---------------- CSR build ----------------
__global__ void k_count(const int* __restrict__ dst, int* __restrict__ cnt) {
  int e = blockIdx.x * 256 + threadIdx.x;
  if (e < Ee) atomicAdd(&cnt[dst[e]], 1);
}

__global__ __launch_bounds__(1024) void k_scan(const int* __restrict__ cnt, int* __restrict__ offs) {
  __shared__ int sh[1024];
  int t = threadIdx.x;
  const int CH = (Nn + 1023) / 1024;
  int s0 = t * CH, s1 = min(s0 + CH, Nn);
  int lsum = 0;
  for (int i = s0; i < s1; i++) lsum += cnt[i];
  sh[t] = lsum;
  __syncthreads();
  for (int off = 1; off < 1024; off <<= 1) {
    int v = (t >= off) ? sh[t - off] : 0;
    __syncthreads();
    sh[t] += v;
    __syncthreads();
  }
  int base = sh[t] - lsum;
  for (int i = s0; i < s1; i++) { offs[i] = base; base += cnt[i]; }
  if (t == 1023) offs[Nn] = sh[1023];
}

__global__ void k_scatter(const int* __restrict__ src, const int* __restrict__ dst,
                          const int* __restrict__ offs, int* __restrict__ cur,
                          int* __restrict__ csr) {
  int e = blockIdx.x * 256 + threadIdx.x;
  if (e < Ee) {
    int d = dst[e];
    int p = offs[d] + atomicAdd(&cur[d], 1);
    csr[p] = src[e];
  }
}

// ---------------- column stats (64-wide, ddof=1) ----------------
__global__ __launch_bounds__(256) void k_stats(const float* __restrict__ X, double* __restrict__ acc) {
  int col = threadIdx.x & 63, rs_ = threadIdx.x >> 6;
  int row0 = blockIdx.x * 1024;
  int rend = min(row0 + 1024, Nn);
  double s = 0.0, ss = 0.0;
  for (int r = row0 + rs_; r < rend; r += 4) {
    float v = X[(size_t)r * 64 + col];
    s += v; ss += (double)v * v;
  }
  __shared__ double sh[512];
  sh[threadIdx.x] = s; sh[256 + threadIdx.x] = ss;
  __syncthreads();
  if (rs_ == 0) {
    s = sh[col] + sh[col + 64] + sh[col + 128] + sh[col + 192];
    ss = sh[256 + col] + sh[256 + col + 64] + sh[256 + col + 128] + sh[256 + col + 192];
    atomicAdd(&acc[col], s);
    atomicAdd(&acc[64 + col], ss);
  }
}

__global__ void k_stats_final(const double* __restrict__ acc, float* __restrict__ mean,
                              float* __restrict__ rstd) {
  int c = threadIdx.x;
  if (c < 64) {
    double s = acc[c], ss = acc[64 + c];
    double m = s / (double)Nn;
    double var = (ss - s * s / (double)Nn) / (double)(Nn - 1);
    double sd = sqrt(var > 0.0 ? var : 0.0);
    if (sd < 1e-8) sd = 1e-8;
    mean[c] = (float)m;
    rstd[c] = (float)(1.0 / sd);
  }
}

// ---------------- local Dirichlet energy (pull over in-edges) ----------------
__global__ __launch_bounds__(256) void k_energy(const float* __restrict__ X,
                                                const int* __restrict__ cnt,
                                                const int* __restrict__ offs,
                                                const int* __restrict__ csr,
                                                float* __restrict__ R) {
  int wid = threadIdx.x >> 6, lane = threadIdx.x & 63;
  int node = blockIdx.x * 4 + wid;
  if (node >= Nn) return;
  int deg = cnt[node];
  float degf = (float)deg;
  float inv_i = rsqrtf(fmaxf(degf, 1e-12f));
  float xi = X[(size_t)node * 64 + lane] * inv_i;
  float num = 0.f, den = degf * xi * xi;
  int j0 = offs[node], j1 = offs[node + 1];
  for (int j = j0; j < j1; j++) {
    int s = csr[j];
    float inv_s = rsqrtf(fmaxf((float)cnt[s], 1e-12f));
    float xs = X[(size_t)s * 64 + lane] * inv_s;
    float d = xi - xs;
    num += d * d;
    den += xs * xs;
  }
  R[(size_t)node * 64 + lane] = num / (den + 1e-8f);
}

// ---------------- gate MLP + Z (in-place R -> Z, fp32) ----------------
__global__ __launch_bounds__(256) void k_gate(const float* __restrict__ feat,
                                              const float* __restrict__ fm, const float* __restrict__ fr,
                                              const float* __restrict__ rm, const float* __restrict__ rr,
                                              const float* __restrict__ w1, const float* __restrict__ b1,
                                              const float* __restrict__ w2, const float* __restrict__ b2,
                                              float* __restrict__ RZ) {
  __shared__ float sw1[1024], sw2[1024], sb1[16], sb2[64], sfm[64], sfr[64], srm[64], srr[64];
  for (int i = threadIdx.x; i < 1024; i += 256) { sw1[i] = w1[i]; sw2[i] = w2[i]; }
  if (threadIdx.x < 16) sb1[threadIdx.x] = b1[threadIdx.x];
  if (threadIdx.x < 64) {
    sb2[threadIdx.x] = b2[threadIdx.x];
    sfm[threadIdx.x] = fm[threadIdx.x]; sfr[threadIdx.x] = fr[threadIdx.x];
    srm[threadIdx.x] = rm[threadIdx.x]; srr[threadIdx.x] = rr[threadIdx.x];
  }
  __syncthreads();
  int node = blockIdx.x * 256 + threadIdx.x;
  if (node >= Nn) return;
  float xn[64];
  const float4* fx = (const float4*)(feat + (size_t)node * 64);
  for (int q = 0; q < 16; q++) {
    float4 v = fx[q];
    xn[q * 4 + 0] = (v.x - sfm[q * 4 + 0]) * sfr[q * 4 + 0];
    xn[q * 4 + 1] = (v.y - sfm[q * 4 + 1]) * sfr[q * 4 + 1];
    xn[q * 4 + 2] = (v.z - sfm[q * 4 + 2]) * sfr[q * 4 + 2];
    xn[q * 4 + 3] = (v.w - sfm[q * 4 + 3]) * sfr[q * 4 + 3];
  }
  float hid[16];
  #pragma unroll
  for (int h = 0; h < 16; h++) {
    float a = sb1[h];
    #pragma unroll
    for (int k = 0; k < 64; k++) a += xn[k] * sw1[k * 16 + h];
    hid[h] = fmaxf(a, 0.f);
  }
  float4* row = (float4*)(RZ + (size_t)node * 64);
  for (int q = 0; q < 16; q++) {
    float4 rv = row[q];
    float Rv[4] = {rv.x, rv.y, rv.z, rv.w};
    float zo[4];
    #pragma unroll
    for (int j = 0; j < 4; j++) {
      int o = q * 4 + j;
      float a = sb2[o];
      #pragma unroll
      for (int h = 0; h < 16; h++) a += hid[h] * sw2[h * 64 + o];
      float g = 1.f / (1.f + expf(-a));
      float Rn = (Rv[j] - srm[o]) * srr[o];
      float Rf = (2.f - Rv[j] - srm[o]) * srr[o];
      zo[j] = g * Rn + (1.f - g) * Rf;
    }
    row[q] = make_float4(zo[0], zo[1], zo[2], zo[3]);
  }
}

// ---------------- attn MLP + h0 = en*attn (Z fp32 -> H0 hi/lo bf16) ----------------
__global__ __launch_bounds__(256) void k_attn(const float* __restrict__ zm, const float* __restrict__ zr,
                                              const float* __restrict__ w1, const float* __restrict__ b1,
                                              const float* __restrict__ w2, const float* __restrict__ b2,
                                              const float* __restrict__ Zf,
                                              unsigned short* __restrict__ Hh,
                                              unsigned short* __restrict__ Hl) {
  __shared__ float sw1[1024], sw2[1024], sb1[16], sb2[64], szm[64], szr[64];
  for (int i = threadIdx.x; i < 1024; i += 256) { sw1[i] = w1[i]; sw2[i] = w2[i]; }
  if (threadIdx.x < 16) sb1[threadIdx.x] = b1[threadIdx.x];
  if (threadIdx.x < 64) {
    sb2[threadIdx.x] = b2[threadIdx.x];
    szm[threadIdx.x] = zm[threadIdx.x]; szr[threadIdx.x] = zr[threadIdx.x];
  }
  __syncthreads();
  int node = blockIdx.x * 256 + threadIdx.x;
  if (node >= Nn) return;
  float en[64];
  const float4* row = (const float4*)(Zf + (size_t)node * 64);
  for (int q = 0; q < 16; q++) {
    float4 v = row[q];
    en[q * 4 + 0] = (v.x - szm[q * 4 + 0]) * szr[q * 4 + 0];
    en[q * 4 + 1] = (v.y - szm[q * 4 + 1]) * szr[q * 4 + 1];
    en[q * 4 + 2] = (v.z - szm[q * 4 + 2]) * szr[q * 4 + 2];
    en[q * 4 + 3] = (v.w - szm[q * 4 + 3]) * szr[q * 4 + 3];
  }
  float hid[16];
  #pragma unroll
  for (int h = 0; h < 16; h++) {
    float a = sb1[h];
    #pragma unroll
    for (int k = 0; k < 64; k++) a += en[k] * sw1[k * 16 + h];
    hid[h] = fmaxf(a, 0.f);
  }
  for (int q = 0; q < 16; q++) {
    ushort4 oh, ol;
    unsigned short hq[4], lq[4];
    #pragma unroll
    for (int j = 0; j < 4; j++) {
      int o = q * 4 + j;
      float a = sb2[o];
      #pragma unroll
      for (int h = 0; h < 16; h++) a += hid[h] * sw2[h * 64 + o];
      float att = 1.f / (1.f + expf(-a));
      float v = en[o] * att;
      hq[j] = f2bf_rtn(v);
      lq[j] = f2bf_rtn(v - bf2f(hq[j]));
    }
    oh.x = hq[0]; oh.y = hq[1]; oh.z = hq[2]; oh.w = hq[3];
    ol.x = lq[0]; ol.y = lq[1]; ol.z = lq[2]; ol.w = lq[3];
    *(ushort4*)(Hh + (size_t)node * 64 + q * 4) = oh;
    *(ushort4*)(Hl + (size_t)node * 64 + q * 4) = ol;
  }
}

// ---------------- neighbor-mean pulls (hi/lo bf16 in, hi/lo bf16 out) ----------------
__global__ __launch_bounds__(256) void k_pull64hl(const unsigned short* __restrict__ Xh,
                                                  const unsigned short* __restrict__ Xl,
                                                  const int* __restrict__ cnt,
                                                  const int* __restrict__ offs,
                                                  const int* __restrict__ csr,
                                                  unsigned short* __restrict__ Oh,
                                                  unsigned short* __restrict__ Ol) {
  int wid = threadIdx.x >> 6, lane = threadIdx.x & 63;
  int node = blockIdx.x * 4 + wid;
  if (node >= Nn) return;
  float s = 0.f;
  int j0 = offs[node], j1 = offs[node + 1];
  for (int j = j0; j < j1; j++) {
    size_t b = (size_t)csr[j] * 64 + lane;
    s += bf2f(Xh[b]) + bf2f(Xl[b]);
  }
  s *= 1.f / fmaxf((float)cnt[node], 1.f);
  unsigned short h = f2bf_rtn(s);
  Oh[(size_t)node * 64 + lane] = h;
  Ol[(size_t)node * 64 + lane] = f2bf_rtn(s - bf2f(h));
}

__global__ __launch_bounds__(256) void k_pull256hl(const unsigned short* __restrict__ Xh,
                                                   const unsigned short* __restrict__ Xl,
                                                   const int* __restrict__ cnt,
                                                   const int* __restrict__ offs,
                                                   const int* __restrict__ csr,
                                                   unsigned short* __restrict__ Oh,
                                                   unsigned short* __restrict__ Ol) {
  int wid = threadIdx.x >> 6, lane = threadIdx.x & 63;
  int node = blockIdx.x * 4 + wid;
  if (node >= Nn) return;
  float s0 = 0.f, s1 = 0.f, s2 = 0.f, s3 = 0.f;
  int j0 = offs[node], j1 = offs[node + 1];
  for (int j = j0; j < j1; j++) {
    size_t b = (size_t)csr[j] * 256 + lane * 4;
    ushort4 h4 = *(const ushort4*)(Xh + b);
    ushort4 l4 = *(const ushort4*)(Xl + b);
    s0 += bf2f(h4.x) + bf2f(l4.x);
    s1 += bf2f(h4.y) + bf2f(l4.y);
    s2 += bf2f(h4.z) + bf2f(l4.z);
    s3 += bf2f(h4.w) + bf2f(l4.w);
  }
  float inv = 1.f / fmaxf((float)cnt[node], 1.f);
  s0 *= inv; s1 *= inv; s2 *= inv; s3 *= inv;
  ushort4 oh, ol;
  oh.x = f2bf_rtn(s0); ol.x = f2bf_rtn(s0 - bf2f(oh.x));
  oh.y = f2bf_rtn(s1); ol.y = f2bf_rtn(s1 - bf2f(oh.y));
  oh.z = f2bf_rtn(s2); ol.z = f2bf_rtn(s2 - bf2f(oh.z));
  oh.w = f2bf_rtn(s3); ol.w = f2bf_rtn(s3 - bf2f(oh.w));
  *(ushort4*)(Oh + (size_t)node * 256 + lane * 4) = oh;
  *(ushort4*)(Ol + (size_t)node * 256 + lane * 4) = ol;
}

// ---------------- fp32 pull over cols [128,256) of a [N][256] fp32 matrix ----------------
__global__ __launch_bounds__(256) void k_pullf(const float* __restrict__ P,
                                               const int* __restrict__ cnt,
                                               const int* __restrict__ offs,
                                               const int* __restrict__ csr,
                                               float* __restrict__ AG) {
  int wid = threadIdx.x >> 6, lane = threadIdx.x & 63;
  int node = blockIdx.x * 4 + wid;
  if (node >= Nn) return;
  float s0 = 0.f, s1 = 0.f;
  int j0 = offs[node], j1 = offs[node + 1];
  for (int j = j0; j < j1; j++) {
    const float2 v = *(const float2*)(P + (size_t)csr[j] * 256 + 128 + lane * 2);
    s0 += v.x; s1 += v.y;
  }
  float inv = 1.f / fmaxf((float)cnt[node], 1.f);
  *(float2*)(AG + (size_t)node * 128 + lane * 2) = make_float2(s0 * inv, s1 * inv);
}

// ---------------- weight prep: W[K][N] fp32 -> Wt hi/lo [N][K] bf16 ----------------
__global__ void k_prep(const float* __restrict__ W, int K, int N,
                       unsigned short* __restrict__ Hi, unsigned short* __restrict__ Lo) {
  int idx = blockIdx.x * 256 + threadIdx.x;
  if (idx >= K * N) return;
  int k = idx / N, n = idx - k * N;
  float x = W[idx];
  unsigned short h = f2bf_rtn(x);
  Hi[(size_t)n * K + k] = h;
  Lo[(size_t)n * K + k] = f2bf_rtn(x - bf2f(h));
}

__global__ void k_bias_pad(const float* __restrict__ b, float* __restrict__ out) {
  int i = threadIdx.x;
  out[i] = (i < 128) ? b[i] : 0.f;
}

// ---------------- split-bf16 MFMA GEMM with global_load_lds staging ----------------
// A: hi/lo bf16 [M][K]; B: hi/lo bf16 [N][K] (pre-transposed). 3-MFMA fp32 emulation.
template <int PASSES, bool RELU, bool OUTF32>
__global__ __launch_bounds__(256) void k_gemm(
    const unsigned short* __restrict__ A1h, const unsigned short* __restrict__ A1l,
    const unsigned short* __restrict__ B1h, const unsigned short* __restrict__ B1l,
    const unsigned short* __restrict__ A2h, const unsigned short* __restrict__ A2l,
    const unsigned short* __restrict__ B2h, const unsigned short* __restrict__ B2l,
    const float* __restrict__ bias,
    unsigned short* __restrict__ Ch, unsigned short* __restrict__ Cl,
    float* __restrict__ Cf, int K, int Nout) {
  __shared__ __align__(16) unsigned short Ah[128 * 32];
  __shared__ __align__(16) unsigned short Al[128 * 32];
  __shared__ __align__(16) unsigned short Bh[128 * 32];
  __shared__ __align__(16) unsigned short Bl[128 * 32];
  const int tid = threadIdx.x;
  const int lane = tid & 63;
  const int wid = tid >> 6;
  const int l15 = lane & 15, l4 = lane >> 4;
  const int wm = (wid >> 1) * 64, wn = (wid & 1) * 64;
  const int row0 = blockIdx.x * 128, col0 = blockIdx.y * 128;
  // staging: wave `wid` owns one plane; 8 chunks x (16 rows x 32 elems) = 1KB each.
  unsigned short* ldsp = (wid == 0) ? Ah : (wid == 1) ? Al : (wid == 2) ? Bh : Bl;
  const int sbase = (wid < 2) ? row0 : col0;
  const int srow = lane >> 2;        // row within chunk (0..15)
  const int skel = (lane & 3) * 8;   // element offset within K-tile (0,8,16,24)

  f32x4 acc[4][4];
  #pragma unroll
  for (int s = 0; s < 4; ++s)
    #pragma unroll
    for (int t = 0; t < 4; ++t) acc[s][t] = (f32x4)0.0f;

  for (int pass = 0; pass < PASSES; ++pass) {
    const unsigned short* gplane =
        (pass == 0) ? ((wid == 0) ? A1h : (wid == 1) ? A1l : (wid == 2) ? B1h : B1l)
                    : ((wid == 0) ? A2h : (wid == 1) ? A2l : (wid == 2) ? B2h : B2l);
    for (int k0 = 0; k0 < K; k0 += 32) {
      __syncthreads();
      #pragma unroll
      for (int c = 0; c < 8; ++c) {
        int r = c * 16 + srow;
        const unsigned short* gp = gplane + (size_t)(sbase + r) * K + k0 + skel;
        __builtin_amdgcn_global_load_lds(
            (const __attribute__((address_space(1))) void*)gp,
            (__attribute__((address_space(3))) void*)(ldsp + c * 512),
            16, 0, 0);
      }
      __syncthreads();
      short8 bhf[4], blf[4];
      #pragma unroll
      for (int t = 0; t < 4; ++t) {
        bhf[t] = *(const short8*)&Bh[(wn + t * 16 + l15) * 32 + l4 * 8];
        blf[t] = *(const short8*)&Bl[(wn + t * 16 + l15) * 32 + l4 * 8];
      }
      #pragma unroll
      for (int s = 0; s < 4; ++s) {
        short8 ah = *(const short8*)&Ah[(wm + s * 16 + l15) * 32 + l4 * 8];
        short8 al = *(const short8*)&Al[(wm + s * 16 + l15) * 32 + l4 * 8];
        #pragma unroll
        for (int t = 0; t < 4; ++t) {
          acc[s][t] = __builtin_amdgcn_mfma_f32_16x16x32_bf16(ah, bhf[t], acc[s][t], 0, 0, 0);
          acc[s][t] = __builtin_amdgcn_mfma_f32_16x16x32_bf16(ah, blf[t], acc[s][t], 0, 0, 0);
          acc[s][t] = __builtin_amdgcn_mfma_f32_16x16x32_bf16(al, bhf[t], acc[s][t], 0, 0, 0);
        }
      }
    }
  }
  #pragma unroll
  for (int s = 0; s < 4; ++s) {
    #pragma unroll
    for (int t = 0; t < 4; ++t) {
      int col = col0 + wn + t * 16 + l15;
      float bv = bias[col];
      #pragma unroll
      for (int j = 0; j < 4; ++j) {
        int row = row0 + wm + s * 16 + l4 * 4 + j;
        if (row < Nn) {
          float v = acc[s][t][j] + bv;
          if (RELU) v = fmaxf(v, 0.f);
          if (OUTF32) {
            Cf[(size_t)row * Nout + col] = v;
          } else {
            unsigned short h = f2bf_rtn(v);
            Ch[(size_t)row * Nout + col] = h;
            Cl[(size_t)row * Nout + col] = f2bf_rtn(v - bf2f(h));
          }
        }
      }
    }
  }
}

// ---------------- fused final: h3 = relu(S3 + AG3); out = h3 @ clw + clb ----------------
__global__ __launch_bounds__(256) void k_cls2(const float* __restrict__ S3P3,
                                              const float* __restrict__ AG3,
                                              const float* __restrict__ W,
                                              const float* __restrict__ B,
                                              float* __restrict__ out) {
  __shared__ float sw[1024];
  __shared__ float sb[8];
  for (int i = threadIdx.x; i < 1024; i += 256) sw[i] = W[i];
  if (threadIdx.x < 8) sb[threadIdx.x] = B[threadIdx.x];
  __syncthreads();
  int node = blockIdx.x * 256 + threadIdx.x;
  if (node >= Nn) return;
  float acc[8];
  #pragma unroll
  for (int o = 0; o < 8; o++) acc[o] = sb[o];
  const float4* s4 = (const float4*)(S3P3 + (size_t)node * 256);
  const float4* a4 = (const float4*)(AG3 + (size_t)node * 128);
  for (int k4 = 0; k4 < 32; k4++) {
    float4 sv = s4[k4];
    float4 av = a4[k4];
    float vv[4] = {fmaxf(sv.x + av.x, 0.f), fmaxf(sv.y + av.y, 0.f),
                   fmaxf(sv.z + av.z, 0.f), fmaxf(sv.w + av.w, 0.f)};
    #pragma unroll
    for (int j = 0; j < 4; j++) {
      int k = k4 * 4 + j;
      #pragma unroll
      for (int o = 0; o < 8; o++) acc[o] += vv[j] * sw[k * 8 + o];
    }
  }
  float4* orow = (float4*)(out + (size_t)node * 8);
  orow[0] = make_float4(acc[0], acc[1], acc[2], acc[3]);
  orow[1] = make_float4(acc[4], acc[5], acc[6], acc[7]);
}

extern "C" void kernel_launch(void* const* d_in, const int* in_sizes, int n_in,
                              void* d_out, int out_size, void* d_ws, size_t ws_size,
                              hipStream_t stream) {
  (void)in_sizes; (void)n_in; (void)out_size; (void)ws_size;
  const float* feat = (const float*)d_in[0];
  const int* eidx = (const int*)d_in[1];
  const int* esrc = eidx;
  const int* edst = eidx + Ee;
  const float* gw1 = (const float*)d_in[2];  const float* gb1 = (const float*)d_in[3];
  const float* gw2 = (const float*)d_in[4];  const float* gb2 = (const float*)d_in[5];
  const float* aw1 = (const float*)d_in[6];  const float* ab1 = (const float*)d_in[7];
  const float* aw2 = (const float*)d_in[8];  const float* ab2 = (const float*)d_in[9];
  const float* c1ws = (const float*)d_in[10]; const float* c1wn = (const float*)d_in[11]; const float* c1b = (const float*)d_in[12];
  const float* c2ws = (const float*)d_in[13]; const float* c2wn = (const float*)d_in[14]; const float* c2b = (const float*)d_in[15];
  const float* c3ws = (const float*)d_in[16]; const float* c3wn = (const float*)d_in[17]; const float* c3b = (const float*)d_in[18];
  const float* clw = (const float*)d_in[19];  const float* clb = (const float*)d_in[20];
  float* out = (float*)d_out;

  char* ws = (char*)d_ws;
  size_t off = 0;
  auto alloc = [&](size_t b) -> char* {
    char* p = ws + off;
    off = (off + b + 255) & ~(size_t)255;
    return p;
  };
  int* cnt = (int*)alloc(Nn * 4);
  int* cur = (int*)alloc(Nn * 4);
  double* accF = (double*)alloc(128 * 8);
  double* accR = (double*)alloc(128 * 8);
  double* accZ = (double*)alloc(128 * 8);
  size_t zbytes = off;  // region above must be zeroed
  int* offs = (int*)alloc((size_t)(Nn + 1) * 4);
  int* csr = (int*)alloc((size_t)Ee * 4);
  float* fm = (float*)alloc(64 * 4); float* fr = (float*)alloc(64 * 4);
  float* rm = (float*)alloc(64 * 4); float* rr = (float*)alloc(64 * 4);
  float* zm = (float*)alloc(64 * 4); float* zr = (float*)alloc(64 * 4);
  // weight splits (transposed [N][K])
  unsigned short* B1sh = (unsigned short*)alloc(64 * 256 * 2);
  unsigned short* B1sl = (unsigned short*)alloc(64 * 256 * 2);
  unsigned short* B1nh = (unsigned short*)alloc(64 * 256 * 2);
  unsigned short* B1nl = (unsigned short*)alloc(64 * 256 * 2);
  unsigned short* B2sh = (unsigned short*)alloc(256 * 256 * 2);
  unsigned short* B2sl = (unsigned short*)alloc(256 * 256 * 2);
  unsigned short* B2nh = (unsigned short*)alloc(256 * 256 * 2);
  unsigned short* B2nl = (unsigned short*)alloc(256 * 256 * 2);
  // layer3 combined [ws|wn] transposed: [256][256]
  unsigned short* B3h = (unsigned short*)alloc(256 * 256 * 2);
  unsigned short* B3l = (unsigned short*)alloc(256 * 256 * 2);
  float* b3p = (float*)alloc(256 * 4);
  // activations: contiguous region {Zf(12.8) | H0h(6.4) | H0l(6.4)} = 25.6MB
  float* Zf = (float*)alloc((size_t)Nn * 64 * 4);
  unsigned short* H0h = (unsigned short*)alloc((size_t)Nn * 64 * 2);
  unsigned short* H0l = (unsigned short*)alloc((size_t)Nn * 64 * 2);
  unsigned short* AG0h = (unsigned short*)Zf;               // alias (Zf dead after k_attn)
  unsigned short* AG0l = (unsigned short*)Zf + (size_t)Nn * 64;
  unsigned short* H1h = (unsigned short*)alloc((size_t)Nn * 256 * 2);
  unsigned short* H1l = (unsigned short*)alloc((size_t)Nn * 256 * 2);
  unsigned short* AG1h = (unsigned short*)alloc((size_t)Nn * 256 * 2);
  unsigned short* AG1l = (unsigned short*)alloc((size_t)Nn * 256 * 2);
  unsigned short* H2h = (unsigned short*)Zf;                // alias 25.6MB (Zf+H0 dead after GEMM1)
  unsigned short* H2l = (unsigned short*)alloc((size_t)Nn * 256 * 2);
  alloc(65536);                                             // guard pad for OOB A-row staging reads
  float* S3P3 = (float*)AG1h;                               // alias 51.2MB (AG1 dead after GEMM2)
  float* AG3 = (float*)H1h;                                 // alias 25.6MB (H1 dead after GEMM2)

  hipMemsetAsync(d_ws, 0, zbytes, stream);

  // weight prep
  hipLaunchKernelGGL(k_prep, dim3(64), dim3(256), 0, stream, c1ws, 64, 256, B1sh, B1sl);
  hipLaunchKernelGGL(k_prep, dim3(64), dim3(256), 0, stream, c1wn, 64, 256, B1nh, B1nl);
  hipLaunchKernelGGL(k_prep, dim3(256), dim3(256), 0, stream, c2ws, 256, 256, B2sh, B2sl);
  hipLaunchKernelGGL(k_prep, dim3(256), dim3(256), 0, stream, c2wn, 256, 256, B2nh, B2nl);
  hipLaunchKernelGGL(k_prep, dim3(128), dim3(256), 0, stream, c3ws, 256, 128, B3h, B3l);
  hipLaunchKernelGGL(k_prep, dim3(128), dim3(256), 0, stream, c3wn, 256, 128,
                     B3h + 128 * 256, B3l + 128 * 256);
  hipLaunchKernelGGL(k_bias_pad, dim3(1), dim3(256), 0, stream, c3b, b3p);

  int eb = (Ee + 255) / 256;
  hipLaunchKernelGGL(k_count, dim3(eb), dim3(256), 0, stream, edst, cnt);
  hipLaunchKernelGGL(k_scan, dim3(1), dim3(1024), 0, stream, cnt, offs);
  hipLaunchKernelGGL(k_scatter, dim3(eb), dim3(256), 0, stream, esrc, edst, offs, cur, csr);

  hipLaunchKernelGGL(k_stats, dim3(49), dim3(256), 0, stream, feat, accF);
  hipLaunchKernelGGL(k_stats_final, dim3(1), dim3(64), 0, stream, accF, fm, fr);

  hipLaunchKernelGGL(k_energy, dim3((Nn + 3) / 4), dim3(256), 0, stream, feat, cnt, offs, csr, Zf);
  hipLaunchKernelGGL(k_stats, dim3(49), dim3(256), 0, stream, Zf, accR);
  hipLaunchKernelGGL(k_stats_final, dim3(1), dim3(64), 0, stream, accR, rm, rr);

  hipLaunchKernelGGL(k_gate, dim3((Nn + 255) / 256), dim3(256), 0, stream,
                     feat, fm, fr, rm, rr, gw1, gb1, gw2, gb2, Zf);
  hipLaunchKernelGGL(k_stats, dim3(49), dim3(256), 0, stream, Zf, accZ);
  hipLaunchKernelGGL(k_stats_final, dim3(1), dim3(64), 0, stream, accZ, zm, zr);

  hipLaunchKernelGGL(k_attn, dim3((Nn + 255) / 256), dim3(256), 0, stream,
                     zm, zr, aw1, ab1, aw2, ab2, Zf, H0h, H0l);

  hipLaunchKernelGGL(k_pull64hl, dim3((Nn + 3) / 4), dim3(256), 0, stream,
                     H0h, H0l, cnt, offs, csr, AG0h, AG0l);
  hipLaunchKernelGGL((k_gemm<2, true, false>), dim3(391, 2), dim3(256), 0, stream,
                     H0h, H0l, B1sh, B1sl, AG0h, AG0l, B1nh, B1nl, c1b,
                     H1h, H1l, (float*)nullptr, 64, 256);
  hipLaunchKernelGGL(k_pull256hl, dim3((Nn + 3) / 4), dim3(256), 0, stream,
                     H1h, H1l, cnt, offs, csr, AG1h, AG1l);
  hipLaunchKernelGGL((k_gemm<2, true, false>), dim3(391, 2), dim3(256), 0, stream,
                     H1h, H1l, B2sh, B2sl, AG1h, AG1l, B2nh, B2nl, c2b,
                     H2h, H2l, (float*)nullptr, 256, 256);
  hipLaunchKernelGGL((k_gemm<1, false, true>), dim3(391, 2), dim3(256), 0, stream,
                     H2h, H2l, B3h, B3l,
                     (unsigned short*)nullptr, (unsigned short*)nullptr,
                     (unsigned short*)nullptr, (unsigned short*)nullptr, b3p,
                     (unsigned short*)nullptr, (unsigned short*)nullptr, S3P3, 256, 256);
  hipLaunchKernelGGL(k_pullf, dim3((Nn + 3) / 4), dim3(256), 0, stream,
                     S3P3, cnt, offs, csr, AG3);
  hipLaunchKernelGGL(k_cls2, dim3((Nn + 255) / 256), dim3(256), 0, stream,
                     S3P3, AG3, clw, clb, out);
}

// Round 4
// 886.536 us; speedup vs baseline: 1.7211x; 1.2701x over previous
//
#include <hip/hip_runtime.h>
#include <math.h>

constexpr int Nn = 50000;
constexpr int Ee = 800000;

typedef __attribute__((ext_vector_type(8))) short short8;
typedef __attribute__((ext_vector_type(4))) float f32x4;

__device__ inline unsigned short f2bf_rtn(float f) {
  union { float f; unsigned u; } v; v.f = f;
  unsigned r = v.u + 0x7FFFu + ((v.u >> 16) & 1u);
  return (unsigned short)(r >> 16);
}
__device__ inline float bf2f(unsigned short h) {
  union { unsigned u; float f; } v; v.u = ((unsigned)h) << 16;
  return v.f;
}

// ---------------- CSR build ----------------
__global__ void k_count(const int* __restrict__ dst, int* __restrict__ cnt) {
  int e = blockIdx.x * 256 + threadIdx.x;
  if (e < Ee) atomicAdd(&cnt[dst[e]], 1);
}

__global__ __launch_bounds__(1024) void k_scan(const int* __restrict__ cnt, int* __restrict__ offs) {
  __shared__ int sh[1024];
  int t = threadIdx.x;
  const int CH = (Nn + 1023) / 1024;
  int s0 = t * CH, s1 = min(s0 + CH, Nn);
  int lsum = 0;
  for (int i = s0; i < s1; i++) lsum += cnt[i];
  sh[t] = lsum;
  __syncthreads();
  for (int off = 1; off < 1024; off <<= 1) {
    int v = (t >= off) ? sh[t - off] : 0;
    __syncthreads();
    sh[t] += v;
    __syncthreads();
  }
  int base = sh[t] - lsum;
  for (int i = s0; i < s1; i++) { offs[i] = base; base += cnt[i]; }
  if (t == 1023) offs[Nn] = sh[1023];
}

__global__ void k_scatter(const int* __restrict__ src, const int* __restrict__ dst,
                          const int* __restrict__ offs, int* __restrict__ cur,
                          int* __restrict__ csr) {
  int e = blockIdx.x * 256 + threadIdx.x;
  if (e < Ee) {
    int d = dst[e];
    int p = offs[d] + atomicAdd(&cur[d], 1);
    csr[p] = src[e];
  }
}

// per-node 1/sqrt(deg) for energy
__global__ void k_dinv(const int* __restrict__ cnt, float* __restrict__ dinv) {
  int i = blockIdx.x * 256 + threadIdx.x;
  if (i < Nn) dinv[i] = rsqrtf(fmaxf((float)cnt[i], 1e-12f));
}

// ---------------- column stats (64-wide, ddof=1) ----------------
__global__ __launch_bounds__(256) void k_stats(const float* __restrict__ X, double* __restrict__ acc) {
  int col = threadIdx.x & 63, rs_ = threadIdx.x >> 6;
  int row0 = blockIdx.x * 256;
  int rend = min(row0 + 256, Nn);
  double s = 0.0, ss = 0.0;
  for (int r = row0 + rs_; r < rend; r += 4) {
    float v = X[(size_t)r * 64 + col];
    s += v; ss += (double)v * v;
  }
  __shared__ double sh[512];
  sh[threadIdx.x] = s; sh[256 + threadIdx.x] = ss;
  __syncthreads();
  if (rs_ == 0) {
    s = sh[col] + sh[col + 64] + sh[col + 128] + sh[col + 192];
    ss = sh[256 + col] + sh[256 + col + 64] + sh[256 + col + 128] + sh[256 + col + 192];
    atomicAdd(&acc[col], s);
    atomicAdd(&acc[64 + col], ss);
  }
}

__global__ void k_stats_final(const double* __restrict__ acc, float* __restrict__ mean,
                              float* __restrict__ rstd) {
  int c = threadIdx.x;
  if (c < 64) {
    double s = acc[c], ss = acc[64 + c];
    double m = s / (double)Nn;
    double var = (ss - s * s / (double)Nn) / (double)(Nn - 1);
    double sd = sqrt(var > 0.0 ? var : 0.0);
    if (sd < 1e-8) sd = 1e-8;
    mean[c] = (float)m;
    rstd[c] = (float)(1.0 / sd);
  }
}

// ---------------- local Dirichlet energy (pull over in-edges) ----------------
__global__ __launch_bounds__(256) void k_energy(const float* __restrict__ X,
                                                const int* __restrict__ cnt,
                                                const float* __restrict__ dinv,
                                                const int* __restrict__ offs,
                                                const int* __restrict__ csr,
                                                float* __restrict__ R) {
  int wid = threadIdx.x >> 6, lane = threadIdx.x & 63;
  int node = blockIdx.x * 4 + wid;
  if (node >= Nn) return;
  float degf = (float)cnt[node];
  float xi = X[(size_t)node * 64 + lane] * dinv[node];
  float num = 0.f, den = degf * xi * xi;
  int j0 = offs[node], j1 = offs[node + 1];
  for (int j = j0; j < j1; j++) {
    int s = csr[j];
    float xs = X[(size_t)s * 64 + lane] * dinv[s];
    float d = xi - xs;
    num += d * d;
    den += xs * xs;
  }
  R[(size_t)node * 64 + lane] = num / (den + 1e-8f);
}

// ---------------- gate MLP + Z (in-place R -> Z, fp32) ----------------
__global__ __launch_bounds__(256) void k_gate(const float* __restrict__ feat,
                                              const float* __restrict__ fm, const float* __restrict__ fr,
                                              const float* __restrict__ rm, const float* __restrict__ rr,
                                              const float* __restrict__ w1, const float* __restrict__ b1,
                                              const float* __restrict__ w2, const float* __restrict__ b2,
                                              float* __restrict__ RZ) {
  __shared__ float sw1[1024], sw2[1024], sb1[16], sb2[64], sfm[64], sfr[64], srm[64], srr[64];
  for (int i = threadIdx.x; i < 1024; i += 256) { sw1[i] = w1[i]; sw2[i] = w2[i]; }
  if (threadIdx.x < 16) sb1[threadIdx.x] = b1[threadIdx.x];
  if (threadIdx.x < 64) {
    sb2[threadIdx.x] = b2[threadIdx.x];
    sfm[threadIdx.x] = fm[threadIdx.x]; sfr[threadIdx.x] = fr[threadIdx.x];
    srm[threadIdx.x] = rm[threadIdx.x]; srr[threadIdx.x] = rr[threadIdx.x];
  }
  __syncthreads();
  int node = blockIdx.x * 256 + threadIdx.x;
  if (node >= Nn) return;
  float xn[64];
  const float4* fx = (const float4*)(feat + (size_t)node * 64);
  for (int q = 0; q < 16; q++) {
    float4 v = fx[q];
    xn[q * 4 + 0] = (v.x - sfm[q * 4 + 0]) * sfr[q * 4 + 0];
    xn[q * 4 + 1] = (v.y - sfm[q * 4 + 1]) * sfr[q * 4 + 1];
    xn[q * 4 + 2] = (v.z - sfm[q * 4 + 2]) * sfr[q * 4 + 2];
    xn[q * 4 + 3] = (v.w - sfm[q * 4 + 3]) * sfr[q * 4 + 3];
  }
  float hid[16];
  #pragma unroll
  for (int h = 0; h < 16; h++) {
    float a = sb1[h];
    #pragma unroll
    for (int k = 0; k < 64; k++) a += xn[k] * sw1[k * 16 + h];
    hid[h] = fmaxf(a, 0.f);
  }
  float4* row = (float4*)(RZ + (size_t)node * 64);
  for (int q = 0; q < 16; q++) {
    float4 rv = row[q];
    float Rv[4] = {rv.x, rv.y, rv.z, rv.w};
    float zo[4];
    #pragma unroll
    for (int j = 0; j < 4; j++) {
      int o = q * 4 + j;
      float a = sb2[o];
      #pragma unroll
      for (int h = 0; h < 16; h++) a += hid[h] * sw2[h * 64 + o];
      float g = 1.f / (1.f + expf(-a));
      float Rn = (Rv[j] - srm[o]) * srr[o];
      float Rf = (2.f - Rv[j] - srm[o]) * srr[o];
      zo[j] = g * Rn + (1.f - g) * Rf;
    }
    row[q] = make_float4(zo[0], zo[1], zo[2], zo[3]);
  }
}

// ---------------- attn MLP + h0 = en*attn (Z fp32 -> H0 bf16) ----------------
__global__ __launch_bounds__(256) void k_attn(const float* __restrict__ zm, const float* __restrict__ zr,
                                              const float* __restrict__ w1, const float* __restrict__ b1,
                                              const float* __restrict__ w2, const float* __restrict__ b2,
                                              const float* __restrict__ Zf,
                                              unsigned short* __restrict__ Hh) {
  __shared__ float sw1[1024], sw2[1024], sb1[16], sb2[64], szm[64], szr[64];
  for (int i = threadIdx.x; i < 1024; i += 256) { sw1[i] = w1[i]; sw2[i] = w2[i]; }
  if (threadIdx.x < 16) sb1[threadIdx.x] = b1[threadIdx.x];
  if (threadIdx.x < 64) {
    sb2[threadIdx.x] = b2[threadIdx.x];
    szm[threadIdx.x] = zm[threadIdx.x]; szr[threadIdx.x] = zr[threadIdx.x];
  }
  __syncthreads();
  int node = blockIdx.x * 256 + threadIdx.x;
  if (node >= Nn) return;
  float en[64];
  const float4* row = (const float4*)(Zf + (size_t)node * 64);
  for (int q = 0; q < 16; q++) {
    float4 v = row[q];
    en[q * 4 + 0] = (v.x - szm[q * 4 + 0]) * szr[q * 4 + 0];
    en[q * 4 + 1] = (v.y - szm[q * 4 + 1]) * szr[q * 4 + 1];
    en[q * 4 + 2] = (v.z - szm[q * 4 + 2]) * szr[q * 4 + 2];
    en[q * 4 + 3] = (v.w - szm[q * 4 + 3]) * szr[q * 4 + 3];
  }
  float hid[16];
  #pragma unroll
  for (int h = 0; h < 16; h++) {
    float a = sb1[h];
    #pragma unroll
    for (int k = 0; k < 64; k++) a += en[k] * sw1[k * 16 + h];
    hid[h] = fmaxf(a, 0.f);
  }
  for (int q = 0; q < 16; q++) {
    ushort4 oh;
    unsigned short hq[4];
    #pragma unroll
    for (int j = 0; j < 4; j++) {
      int o = q * 4 + j;
      float a = sb2[o];
      #pragma unroll
      for (int h = 0; h < 16; h++) a += hid[h] * sw2[h * 64 + o];
      float att = 1.f / (1.f + expf(-a));
      hq[j] = f2bf_rtn(en[o] * att);
    }
    oh.x = hq[0]; oh.y = hq[1]; oh.z = hq[2]; oh.w = hq[3];
    *(ushort4*)(Hh + (size_t)node * 64 + q * 4) = oh;
  }
}

// ---------------- neighbor-mean pulls (bf16 in, bf16 out) ----------------
__global__ __launch_bounds__(256) void k_pull64b(const unsigned short* __restrict__ Xh,
                                                 const int* __restrict__ cnt,
                                                 const int* __restrict__ offs,
                                                 const int* __restrict__ csr,
                                                 unsigned short* __restrict__ Oh) {
  int wid = threadIdx.x >> 6, lane = threadIdx.x & 63;
  int node = blockIdx.x * 4 + wid;
  if (node >= Nn) return;
  float s = 0.f;
  int j0 = offs[node], j1 = offs[node + 1];
  for (int j = j0; j < j1; j++) s += bf2f(Xh[(size_t)csr[j] * 64 + lane]);
  s *= 1.f / fmaxf((float)cnt[node], 1.f);
  Oh[(size_t)node * 64 + lane] = f2bf_rtn(s);
}

__global__ __launch_bounds__(256) void k_pull256b(const unsigned short* __restrict__ Xh,
                                                  const int* __restrict__ cnt,
                                                  const int* __restrict__ offs,
                                                  const int* __restrict__ csr,
                                                  unsigned short* __restrict__ Oh) {
  int wid = threadIdx.x >> 6, lane = threadIdx.x & 63;
  int node = blockIdx.x * 4 + wid;
  if (node >= Nn) return;
  float s0 = 0.f, s1 = 0.f, s2 = 0.f, s3 = 0.f;
  int j0 = offs[node], j1 = offs[node + 1];
  for (int j = j0; j < j1; j++) {
    ushort4 h4 = *(const ushort4*)(Xh + (size_t)csr[j] * 256 + lane * 4);
    s0 += bf2f(h4.x); s1 += bf2f(h4.y); s2 += bf2f(h4.z); s3 += bf2f(h4.w);
  }
  float inv = 1.f / fmaxf((float)cnt[node], 1.f);
  ushort4 oh;
  oh.x = f2bf_rtn(s0 * inv); oh.y = f2bf_rtn(s1 * inv);
  oh.z = f2bf_rtn(s2 * inv); oh.w = f2bf_rtn(s3 * inv);
  *(ushort4*)(Oh + (size_t)node * 256 + lane * 4) = oh;
}

// P3 gather: bf16 [N][128] in, fp32 [N][128] out
__global__ __launch_bounds__(256) void k_pullh(const unsigned short* __restrict__ P,
                                               const int* __restrict__ cnt,
                                               const int* __restrict__ offs,
                                               const int* __restrict__ csr,
                                               float* __restrict__ AG) {
  int wid = threadIdx.x >> 6, lane = threadIdx.x & 63;
  int node = blockIdx.x * 4 + wid;
  if (node >= Nn) return;
  float s0 = 0.f, s1 = 0.f;
  int j0 = offs[node], j1 = offs[node + 1];
  for (int j = j0; j < j1; j++) {
    ushort2 v = *(const ushort2*)(P + (size_t)csr[j] * 128 + lane * 2);
    s0 += bf2f(v.x); s1 += bf2f(v.y);
  }
  float inv = 1.f / fmaxf((float)cnt[node], 1.f);
  *(float2*)(AG + (size_t)node * 128 + lane * 2) = make_float2(s0 * inv, s1 * inv);
}

// ---------------- weight prep: W[K][N] fp32 -> Wt hi/lo [N][K] bf16 ----------------
__global__ void k_prep(const float* __restrict__ W, int K, int N,
                       unsigned short* __restrict__ Hi, unsigned short* __restrict__ Lo) {
  int idx = blockIdx.x * 256 + threadIdx.x;
  if (idx >= K * N) return;
  int k = idx / N, n = idx - k * N;
  float x = W[idx];
  unsigned short h = f2bf_rtn(x);
  Hi[(size_t)n * K + k] = h;
  Lo[(size_t)n * K + k] = f2bf_rtn(x - bf2f(h));
}

__global__ void k_bias_pad(const float* __restrict__ b, float* __restrict__ out) {
  int i = threadIdx.x;
  out[i] = (i < 128) ? b[i] : 0.f;
}

// ---------------- bf16-A x split-bf16-B MFMA GEMM, BM=64 BN=256 BK=32 ----------------
// C = act(A1@B1 + A2@B2 + bias); B pre-transposed [256][K] hi/lo.
// XOR-swizzled LDS (pre-swizzled global src; conflict-free ds_read_b128).
template <int PASSES, bool RELU, bool SPLITOUT>
__global__ __launch_bounds__(256) void k_gemm(
    const unsigned short* __restrict__ A1,
    const unsigned short* __restrict__ B1h, const unsigned short* __restrict__ B1l,
    const unsigned short* __restrict__ A2,
    const unsigned short* __restrict__ B2h, const unsigned short* __restrict__ B2l,
    const float* __restrict__ bias,
    unsigned short* __restrict__ Cb, float* __restrict__ S3, unsigned short* __restrict__ P3,
    int K) {
  __shared__ __align__(16) unsigned short Ash[64 * 32];
  __shared__ __align__(16) unsigned short Bsh[256 * 32];
  __shared__ __align__(16) unsigned short Bsl[256 * 32];
  const int tid = threadIdx.x;
  const int lane = tid & 63;
  const int wid = tid >> 6;
  const int l15 = lane & 15, l4 = lane >> 4;
  const int wm = (wid >> 1) * 32;        // wave row offset (0/32)
  const int wn2 = (wid & 1) * 128;       // wave col offset (0/128)
  const int row0 = blockIdx.x * 64;
  const int srow = lane >> 2;                                  // 0..15
  const int sg = ((lane & 3) ^ ((lane >> 3) & 3)) * 8;         // pre-swizzled k-group
  const int gsw = (l4 ^ ((l15 >> 1) & 3)) * 8;                 // swizzled read k-group

  f32x4 acc[2][8];
  #pragma unroll
  for (int s = 0; s < 2; ++s)
    #pragma unroll
    for (int t = 0; t < 8; ++t) acc[s][t] = (f32x4)0.0f;

  for (int pass = 0; pass < PASSES; ++pass) {
    const unsigned short* gA = pass ? A2 : A1;
    const unsigned short* gBh = pass ? B2h : B1h;
    const unsigned short* gBl = pass ? B2l : B1l;
    for (int k0 = 0; k0 < K; k0 += 32) {
      __syncthreads();
      #pragma unroll
      for (int cc = 0; cc < 9; ++cc) {
        int c = wid * 9 + cc;
        unsigned short* lb;
        const unsigned short* gb;
        int grow;
        if (c < 4)       { lb = Ash + c * 512;        gb = gA;  grow = row0 + c * 16 + srow; }
        else if (c < 20) { int q = c - 4;  lb = Bsh + q * 512; gb = gBh; grow = q * 16 + srow; }
        else             { int q = c - 20; lb = Bsl + q * 512; gb = gBl; grow = q * 16 + srow; }
        __builtin_amdgcn_global_load_lds(
            (const __attribute__((address_space(1))) void*)(gb + (size_t)grow * K + k0 + sg),
            (__attribute__((address_space(3))) void*)lb, 16, 0, 0);
      }
      __syncthreads();
      short8 af[2];
      #pragma unroll
      for (int s = 0; s < 2; ++s)
        af[s] = *(const short8*)&Ash[(wm + s * 16 + l15) * 32 + gsw];
      #pragma unroll
      for (int t = 0; t < 8; ++t) {
        short8 b = *(const short8*)&Bsh[(wn2 + t * 16 + l15) * 32 + gsw];
        acc[0][t] = __builtin_amdgcn_mfma_f32_16x16x32_bf16(af[0], b, acc[0][t], 0, 0, 0);
        acc[1][t] = __builtin_amdgcn_mfma_f32_16x16x32_bf16(af[1], b, acc[1][t], 0, 0, 0);
      }
      #pragma unroll
      for (int t = 0; t < 8; ++t) {
        short8 b = *(const short8*)&Bsl[(wn2 + t * 16 + l15) * 32 + gsw];
        acc[0][t] = __builtin_amdgcn_mfma_f32_16x16x32_bf16(af[0], b, acc[0][t], 0, 0, 0);
        acc[1][t] = __builtin_amdgcn_mfma_f32_16x16x32_bf16(af[1], b, acc[1][t], 0, 0, 0);
      }
    }
  }
  #pragma unroll
  for (int t = 0; t < 8; ++t) {
    int col = wn2 + t * 16 + l15;
    float bv = bias[col];
    #pragma unroll
    for (int s = 0; s < 2; ++s) {
      #pragma unroll
      for (int j = 0; j < 4; ++j) {
        int row = row0 + wm + s * 16 + l4 * 4 + j;
        if (row < Nn) {
          float v = acc[s][t][j] + bv;
          if (RELU) v = fmaxf(v, 0.f);
          if (SPLITOUT) {
            if (col < 128) S3[(size_t)row * 128 + col] = v;
            else P3[(size_t)row * 128 + col - 128] = f2bf_rtn(v);
          } else {
            Cb[(size_t)row * 256 + col] = f2bf_rtn(v);
          }
        }
      }
    }
  }
}

// ---------------- fused final: h3 = relu(S3 + AG3); out = h3 @ clw + clb ----------------
__global__ __launch_bounds__(256) void k_cls2(const float* __restrict__ S3,
                                              const float* __restrict__ AG3,
                                              const float* __restrict__ W,
                                              const float* __restrict__ B,
                                              float* __restrict__ out) {
  __shared__ float sw[1024];
  __shared__ float sb[8];
  for (int i = threadIdx.x; i < 1024; i += 256) sw[i] = W[i];
  if (threadIdx.x < 8) sb[threadIdx.x] = B[threadIdx.x];
  __syncthreads();
  int node = blockIdx.x * 256 + threadIdx.x;
  if (node >= Nn) return;
  float acc[8];
  #pragma unroll
  for (int o = 0; o < 8; o++) acc[o] = sb[o];
  const float4* s4 = (const float4*)(S3 + (size_t)node * 128);
  const float4* a4 = (const float4*)(AG3 + (size_t)node * 128);
  for (int k4 = 0; k4 < 32; k4++) {
    float4 sv = s4[k4];
    float4 av = a4[k4];
    float vv[4] = {fmaxf(sv.x + av.x, 0.f), fmaxf(sv.y + av.y, 0.f),
                   fmaxf(sv.z + av.z, 0.f), fmaxf(sv.w + av.w, 0.f)};
    #pragma unroll
    for (int j = 0; j < 4; j++) {
      int k = k4 * 4 + j;
      #pragma unroll
      for (int o = 0; o < 8; o++) acc[o] += vv[j] * sw[k * 8 + o];
    }
  }
  float4* orow = (float4*)(out + (size_t)node * 8);
  orow[0] = make_float4(acc[0], acc[1], acc[2], acc[3]);
  orow[1] = make_float4(acc[4], acc[5], acc[6], acc[7]);
}

extern "C" void kernel_launch(void* const* d_in, const int* in_sizes, int n_in,
                              void* d_out, int out_size, void* d_ws, size_t ws_size,
                              hipStream_t stream) {
  (void)in_sizes; (void)n_in; (void)out_size; (void)ws_size;
  const float* feat = (const float*)d_in[0];
  const int* eidx = (const int*)d_in[1];
  const int* esrc = eidx;
  const int* edst = eidx + Ee;
  const float* gw1 = (const float*)d_in[2];  const float* gb1 = (const float*)d_in[3];
  const float* gw2 = (const float*)d_in[4];  const float* gb2 = (const float*)d_in[5];
  const float* aw1 = (const float*)d_in[6];  const float* ab1 = (const float*)d_in[7];
  const float* aw2 = (const float*)d_in[8];  const float* ab2 = (const float*)d_in[9];
  const float* c1ws = (const float*)d_in[10]; const float* c1wn = (const float*)d_in[11]; const float* c1b = (const float*)d_in[12];
  const float* c2ws = (const float*)d_in[13]; const float* c2wn = (const float*)d_in[14]; const float* c2b = (const float*)d_in[15];
  const float* c3ws = (const float*)d_in[16]; const float* c3wn = (const float*)d_in[17]; const float* c3b = (const float*)d_in[18];
  const float* clw = (const float*)d_in[19];  const float* clb = (const float*)d_in[20];
  float* out = (float*)d_out;

  char* ws = (char*)d_ws;
  size_t off = 0;
  auto alloc = [&](size_t b) -> char* {
    char* p = ws + off;
    off = (off + b + 255) & ~(size_t)255;
    return p;
  };
  int* cnt = (int*)alloc(Nn * 4);
  int* cur = (int*)alloc(Nn * 4);
  double* accF = (double*)alloc(128 * 8);
  double* accR = (double*)alloc(128 * 8);
  double* accZ = (double*)alloc(128 * 8);
  size_t zbytes = off;  // region above must be zeroed
  int* offs = (int*)alloc((size_t)(Nn + 1) * 4);
  int* csr = (int*)alloc((size_t)Ee * 4);
  float* dinv = (float*)alloc(Nn * 4);
  float* fm = (float*)alloc(64 * 4); float* fr = (float*)alloc(64 * 4);
  float* rm = (float*)alloc(64 * 4); float* rr = (float*)alloc(64 * 4);
  float* zm = (float*)alloc(64 * 4); float* zr = (float*)alloc(64 * 4);
  // weight splits (transposed [256][K])
  unsigned short* B1sh = (unsigned short*)alloc(256 * 64 * 2);
  unsigned short* B1sl = (unsigned short*)alloc(256 * 64 * 2);
  unsigned short* B1nh = (unsigned short*)alloc(256 * 64 * 2);
  unsigned short* B1nl = (unsigned short*)alloc(256 * 64 * 2);
  unsigned short* B2sh = (unsigned short*)alloc(256 * 256 * 2);
  unsigned short* B2sl = (unsigned short*)alloc(256 * 256 * 2);
  unsigned short* B2nh = (unsigned short*)alloc(256 * 256 * 2);
  unsigned short* B2nl = (unsigned short*)alloc(256 * 256 * 2);
  unsigned short* B3h = (unsigned short*)alloc(256 * 256 * 2);
  unsigned short* B3l = (unsigned short*)alloc(256 * 256 * 2);
  float* b3p = (float*)alloc(256 * 4);
  // activations
  float* Zf = (float*)alloc((size_t)Nn * 64 * 4);            // 12.8 MB
  unsigned short* H0h = (unsigned short*)alloc((size_t)Nn * 64 * 2);   // 6.4
  unsigned short* AG0 = (unsigned short*)alloc((size_t)Nn * 64 * 2);   // 6.4
  unsigned short* H1h = (unsigned short*)alloc((size_t)Nn * 256 * 2);  // 25.6
  unsigned short* AG1 = (unsigned short*)alloc((size_t)Nn * 256 * 2);  // 25.6
  unsigned short* H2h = (unsigned short*)alloc((size_t)Nn * 256 * 2);  // 25.6
  alloc(65536);  // guard for OOB A-row staging (rows 50000..50047)
  float* S3f = (float*)Zf;            // 25.6 MB alias over {Zf,H0h,AG0} (dead after GEMM1)
  float* AG3 = (float*)H1h;           // 25.6 MB alias (H1 dead after GEMM2)
  unsigned short* P3h = AG1;          // 12.8 MB alias (AG1 dead after GEMM2)

  hipMemsetAsync(d_ws, 0, zbytes, stream);

  // weight prep
  hipLaunchKernelGGL(k_prep, dim3(64), dim3(256), 0, stream, c1ws, 64, 256, B1sh, B1sl);
  hipLaunchKernelGGL(k_prep, dim3(64), dim3(256), 0, stream, c1wn, 64, 256, B1nh, B1nl);
  hipLaunchKernelGGL(k_prep, dim3(256), dim3(256), 0, stream, c2ws, 256, 256, B2sh, B2sl);
  hipLaunchKernelGGL(k_prep, dim3(256), dim3(256), 0, stream, c2wn, 256, 256, B2nh, B2nl);
  hipLaunchKernelGGL(k_prep, dim3(128), dim3(256), 0, stream, c3ws, 256, 128, B3h, B3l);
  hipLaunchKernelGGL(k_prep, dim3(128), dim3(256), 0, stream, c3wn, 256, 128,
                     B3h + 128 * 256, B3l + 128 * 256);
  hipLaunchKernelGGL(k_bias_pad, dim3(1), dim3(256), 0, stream, c3b, b3p);

  int eb = (Ee + 255) / 256;
  hipLaunchKernelGGL(k_count, dim3(eb), dim3(256), 0, stream, edst, cnt);
  hipLaunchKernelGGL(k_scan, dim3(1), dim3(1024), 0, stream, cnt, offs);
  hipLaunchKernelGGL(k_scatter, dim3(eb), dim3(256), 0, stream, esrc, edst, offs, cur, csr);
  hipLaunchKernelGGL(k_dinv, dim3((Nn + 255) / 256), dim3(256), 0, stream, cnt, dinv);

  hipLaunchKernelGGL(k_stats, dim3(196), dim3(256), 0, stream, feat, accF);
  hipLaunchKernelGGL(k_stats_final, dim3(1), dim3(64), 0, stream, accF, fm, fr);

  hipLaunchKernelGGL(k_energy, dim3((Nn + 3) / 4), dim3(256), 0, stream,
                     feat, cnt, dinv, offs, csr, Zf);
  hipLaunchKernelGGL(k_stats, dim3(196), dim3(256), 0, stream, Zf, accR);
  hipLaunchKernelGGL(k_stats_final, dim3(1), dim3(64), 0, stream, accR, rm, rr);

  hipLaunchKernelGGL(k_gate, dim3((Nn + 255) / 256), dim3(256), 0, stream,
                     feat, fm, fr, rm, rr, gw1, gb1, gw2, gb2, Zf);
  hipLaunchKernelGGL(k_stats, dim3(196), dim3(256), 0, stream, Zf, accZ);
  hipLaunchKernelGGL(k_stats_final, dim3(1), dim3(64), 0, stream, accZ, zm, zr);

  hipLaunchKernelGGL(k_attn, dim3((Nn + 255) / 256), dim3(256), 0, stream,
                     zm, zr, aw1, ab1, aw2, ab2, Zf, H0h);

  hipLaunchKernelGGL(k_pull64b, dim3((Nn + 3) / 4), dim3(256), 0, stream,
                     H0h, cnt, offs, csr, AG0);
  hipLaunchKernelGGL((k_gemm<2, true, false>), dim3(782), dim3(256), 0, stream,
                     H0h, B1sh, B1sl, AG0, B1nh, B1nl, c1b,
                     H1h, (float*)nullptr, (unsigned short*)nullptr, 64);
  hipLaunchKernelGGL(k_pull256b, dim3((Nn + 3) / 4), dim3(256), 0, stream,
                     H1h, cnt, offs, csr, AG1);
  hipLaunchKernelGGL((k_gemm<2, true, false>), dim3(782), dim3(256), 0, stream,
                     H1h, B2sh, B2sl, AG1, B2nh, B2nl, c2b,
                     H2h, (float*)nullptr, (unsigned short*)nullptr, 256);
  hipLaunchKernelGGL((k_gemm<1, false, true>), dim3(782), dim3(256), 0, stream,
                     H2h, B3h, B3l,
                     (unsigned short*)nullptr, (unsigned short*)nullptr, (unsigned short*)nullptr,
                     b3p, (unsigned short*)nullptr, S3f, P3h, 256);
  hipLaunchKernelGGL(k_pullh, dim3((Nn + 3) / 4), dim3(256), 0, stream,
                     P3h, cnt, offs, csr, AG3);
  hipLaunchKernelGGL(k_cls2, dim3((Nn + 255) / 256), dim3(256), 0, stream,
                     S3f, AG3, clw, clb, out);
}

// Round 5
// 751.148 us; speedup vs baseline: 2.0313x; 1.1802x over previous
//
#include <hip/hip_runtime.h>
#include <math.h>

constexpr int Nn = 50000;
constexpr int Ee = 800000;

typedef __attribute__((ext_vector_type(8))) short short8;
typedef __attribute__((ext_vector_type(4))) float f32x4;

__device__ inline unsigned short f2bf_rtn(float f) {
  union { float f; unsigned u; } v; v.f = f;
  unsigned r = v.u + 0x7FFFu + ((v.u >> 16) & 1u);
  return (unsigned short)(r >> 16);
}
__device__ inline float bf2f(unsigned short h) {
  union { unsigned u; float f; } v; v.u = ((unsigned)h) << 16;
  return v.f;
}

// ---------------- CSR build ----------------
__global__ void k_count(const int* __restrict__ dst, int* __restrict__ cnt) {
  int e = blockIdx.x * 256 + threadIdx.x;
  if (e < Ee) atomicAdd(&cnt[dst[e]], 1);
}

__global__ __launch_bounds__(1024) void k_scan(const int* __restrict__ cnt, int* __restrict__ offs,
                                               float* __restrict__ dinv) {
  __shared__ int sh[1024];
  int t = threadIdx.x;
  const int CH = (Nn + 1023) / 1024;
  int s0 = t * CH, s1 = min(s0 + CH, Nn);
  int lsum = 0;
  for (int i = s0; i < s1; i++) lsum += cnt[i];
  sh[t] = lsum;
  __syncthreads();
  for (int off = 1; off < 1024; off <<= 1) {
    int v = (t >= off) ? sh[t - off] : 0;
    __syncthreads();
    sh[t] += v;
    __syncthreads();
  }
  int base = sh[t] - lsum;
  for (int i = s0; i < s1; i++) {
    offs[i] = base; base += cnt[i];
    dinv[i] = rsqrtf(fmaxf((float)cnt[i], 1e-12f));
  }
  if (t == 1023) offs[Nn] = sh[1023];
}

__global__ void k_scatter(const int* __restrict__ src, const int* __restrict__ dst,
                          const int* __restrict__ offs, int* __restrict__ cur,
                          int* __restrict__ csr) {
  int e = blockIdx.x * 256 + threadIdx.x;
  if (e < Ee) {
    int d = dst[e];
    int p = offs[d] + atomicAdd(&cur[d], 1);
    csr[p] = src[e];
  }
}

// Xs = feat * dinv[node] (row-scaled features for energy)
__global__ void k_xs(const float* __restrict__ feat, const float* __restrict__ dinv,
                     float* __restrict__ Xs) {
  int i = blockIdx.x * 256 + threadIdx.x;
  if (i < Nn * 16) {
    float d = dinv[i >> 4];
    float4 v = ((const float4*)feat)[i];
    ((float4*)Xs)[i] = make_float4(v.x * d, v.y * d, v.z * d, v.w * d);
  }
}

// ---------------- column stats (64-wide, ddof=1) ----------------
__global__ __launch_bounds__(256) void k_stats(const float* __restrict__ X, double* __restrict__ acc) {
  int col = threadIdx.x & 63, rs_ = threadIdx.x >> 6;
  int row0 = blockIdx.x * 256;
  int rend = min(row0 + 256, Nn);
  double s = 0.0, ss = 0.0;
  for (int r = row0 + rs_; r < rend; r += 4) {
    float v = X[(size_t)r * 64 + col];
    s += v; ss += (double)v * v;
  }
  __shared__ double sh[512];
  sh[threadIdx.x] = s; sh[256 + threadIdx.x] = ss;
  __syncthreads();
  if (rs_ == 0) {
    s = sh[col] + sh[col + 64] + sh[col + 128] + sh[col + 192];
    ss = sh[256 + col] + sh[256 + col + 64] + sh[256 + col + 128] + sh[256 + col + 192];
    atomicAdd(&acc[col], s);
    atomicAdd(&acc[64 + col], ss);
  }
}

__global__ void k_stats_final(const double* __restrict__ acc, float* __restrict__ mean,
                              float* __restrict__ rstd) {
  int c = threadIdx.x;
  if (c < 64) {
    double s = acc[c], ss = acc[64 + c];
    double m = s / (double)Nn;
    double var = (ss - s * s / (double)Nn) / (double)(Nn - 1);
    double sd = sqrt(var > 0.0 ? var : 0.0);
    if (sd < 1e-8) sd = 1e-8;
    mean[c] = (float)m;
    rstd[c] = (float)(1.0 / sd);
  }
}

// ---------------- local Dirichlet energy: 4 edges/wave-iter, float4 lanes ----------------
__global__ __launch_bounds__(256) void k_energy(const float* __restrict__ Xs,
                                                const int* __restrict__ cnt,
                                                const int* __restrict__ offs,
                                                const int* __restrict__ csr,
                                                float* __restrict__ R) {
  int wid = threadIdx.x >> 6, lane = threadIdx.x & 63;
  int node = blockIdx.x * 4 + wid;
  if (node >= Nn) return;
  int q4 = lane >> 4;          // edge offset 0..3
  int cg = (lane & 15) * 4;    // 4 cols per lane
  float4 xi = *(const float4*)(Xs + (size_t)node * 64 + cg);
  float num[4] = {0.f, 0.f, 0.f, 0.f}, den[4] = {0.f, 0.f, 0.f, 0.f};
  int j0 = offs[node], j1 = offs[node + 1];
  for (int j = j0; j < j1; j += 4) {
    int e = j + q4;
    if (e < j1) {
      float4 xs = *(const float4*)(Xs + (size_t)csr[e] * 64 + cg);
      float d0 = xi.x - xs.x, d1 = xi.y - xs.y, d2 = xi.z - xs.z, d3 = xi.w - xs.w;
      num[0] += d0 * d0; num[1] += d1 * d1; num[2] += d2 * d2; num[3] += d3 * d3;
      den[0] += xs.x * xs.x; den[1] += xs.y * xs.y; den[2] += xs.z * xs.z; den[3] += xs.w * xs.w;
    }
  }
  #pragma unroll
  for (int c = 0; c < 4; c++) {
    num[c] += __shfl_xor(num[c], 32); num[c] += __shfl_xor(num[c], 16);
    den[c] += __shfl_xor(den[c], 32); den[c] += __shfl_xor(den[c], 16);
  }
  if (q4 == 0) {
    float degf = (float)cnt[node];
    float4 o;
    o.x = num[0] / (den[0] + degf * xi.x * xi.x + 1e-8f);
    o.y = num[1] / (den[1] + degf * xi.y * xi.y + 1e-8f);
    o.z = num[2] / (den[2] + degf * xi.z * xi.z + 1e-8f);
    o.w = num[3] / (den[3] + degf * xi.w * xi.w + 1e-8f);
    *(float4*)(R + (size_t)node * 64 + cg) = o;
  }
}

// ---------------- gate MLP + Z (in-place R -> Z, fp32) ----------------
__global__ __launch_bounds__(256) void k_gate(const float* __restrict__ feat,
                                              const float* __restrict__ fm, const float* __restrict__ fr,
                                              const float* __restrict__ rm, const float* __restrict__ rr,
                                              const float* __restrict__ w1, const float* __restrict__ b1,
                                              const float* __restrict__ w2, const float* __restrict__ b2,
                                              float* __restrict__ RZ) {
  __shared__ float sw1[1024], sw2[1024], sb1[16], sb2[64], sfm[64], sfr[64], srm[64], srr[64];
  for (int i = threadIdx.x; i < 1024; i += 256) { sw1[i] = w1[i]; sw2[i] = w2[i]; }
  if (threadIdx.x < 16) sb1[threadIdx.x] = b1[threadIdx.x];
  if (threadIdx.x < 64) {
    sb2[threadIdx.x] = b2[threadIdx.x];
    sfm[threadIdx.x] = fm[threadIdx.x]; sfr[threadIdx.x] = fr[threadIdx.x];
    srm[threadIdx.x] = rm[threadIdx.x]; srr[threadIdx.x] = rr[threadIdx.x];
  }
  __syncthreads();
  int node = blockIdx.x * 256 + threadIdx.x;
  if (node >= Nn) return;
  float xn[64];
  const float4* fx = (const float4*)(feat + (size_t)node * 64);
  for (int q = 0; q < 16; q++) {
    float4 v = fx[q];
    xn[q * 4 + 0] = (v.x - sfm[q * 4 + 0]) * sfr[q * 4 + 0];
    xn[q * 4 + 1] = (v.y - sfm[q * 4 + 1]) * sfr[q * 4 + 1];
    xn[q * 4 + 2] = (v.z - sfm[q * 4 + 2]) * sfr[q * 4 + 2];
    xn[q * 4 + 3] = (v.w - sfm[q * 4 + 3]) * sfr[q * 4 + 3];
  }
  float hid[16];
  #pragma unroll
  for (int h = 0; h < 16; h++) {
    float a = sb1[h];
    #pragma unroll
    for (int k = 0; k < 64; k++) a += xn[k] * sw1[k * 16 + h];
    hid[h] = fmaxf(a, 0.f);
  }
  float4* row = (float4*)(RZ + (size_t)node * 64);
  for (int q = 0; q < 16; q++) {
    float4 rv = row[q];
    float Rv[4] = {rv.x, rv.y, rv.z, rv.w};
    float zo[4];
    #pragma unroll
    for (int j = 0; j < 4; j++) {
      int o = q * 4 + j;
      float a = sb2[o];
      #pragma unroll
      for (int h = 0; h < 16; h++) a += hid[h] * sw2[h * 64 + o];
      float g = 1.f / (1.f + expf(-a));
      float Rn = (Rv[j] - srm[o]) * srr[o];
      float Rf = (2.f - Rv[j] - srm[o]) * srr[o];
      zo[j] = g * Rn + (1.f - g) * Rf;
    }
    row[q] = make_float4(zo[0], zo[1], zo[2], zo[3]);
  }
}

// ---------------- attn MLP + h0 = en*attn (Z fp32 -> H0 bf16) ----------------
__global__ __launch_bounds__(256) void k_attn(const float* __restrict__ zm, const float* __restrict__ zr,
                                              const float* __restrict__ w1, const float* __restrict__ b1,
                                              const float* __restrict__ w2, const float* __restrict__ b2,
                                              const float* __restrict__ Zf,
                                              unsigned short* __restrict__ Hh) {
  __shared__ float sw1[1024], sw2[1024], sb1[16], sb2[64], szm[64], szr[64];
  for (int i = threadIdx.x; i < 1024; i += 256) { sw1[i] = w1[i]; sw2[i] = w2[i]; }
  if (threadIdx.x < 16) sb1[threadIdx.x] = b1[threadIdx.x];
  if (threadIdx.x < 64) {
    sb2[threadIdx.x] = b2[threadIdx.x];
    szm[threadIdx.x] = zm[threadIdx.x]; szr[threadIdx.x] = zr[threadIdx.x];
  }
  __syncthreads();
  int node = blockIdx.x * 256 + threadIdx.x;
  if (node >= Nn) return;
  float en[64];
  const float4* row = (const float4*)(Zf + (size_t)node * 64);
  for (int q = 0; q < 16; q++) {
    float4 v = row[q];
    en[q * 4 + 0] = (v.x - szm[q * 4 + 0]) * szr[q * 4 + 0];
    en[q * 4 + 1] = (v.y - szm[q * 4 + 1]) * szr[q * 4 + 1];
    en[q * 4 + 2] = (v.z - szm[q * 4 + 2]) * szr[q * 4 + 2];
    en[q * 4 + 3] = (v.w - szm[q * 4 + 3]) * szr[q * 4 + 3];
  }
  float hid[16];
  #pragma unroll
  for (int h = 0; h < 16; h++) {
    float a = sb1[h];
    #pragma unroll
    for (int k = 0; k < 64; k++) a += en[k] * sw1[k * 16 + h];
    hid[h] = fmaxf(a, 0.f);
  }
  for (int q = 0; q < 16; q++) {
    ushort4 oh;
    unsigned short hq[4];
    #pragma unroll
    for (int j = 0; j < 4; j++) {
      int o = q * 4 + j;
      float a = sb2[o];
      #pragma unroll
      for (int h = 0; h < 16; h++) a += hid[h] * sw2[h * 64 + o];
      float att = 1.f / (1.f + expf(-a));
      hq[j] = f2bf_rtn(en[o] * att);
    }
    oh.x = hq[0]; oh.y = hq[1]; oh.z = hq[2]; oh.w = hq[3];
    *(ushort4*)(Hh + (size_t)node * 64 + q * 4) = oh;
  }
}

// ---------------- neighbor-mean pulls: wide lanes + multi-edge ILP ----------------
// 64-wide bf16: 8 lanes/row (ushort8), 8 edges per wave-iteration.
__global__ __launch_bounds__(256) void k_pull64b(const unsigned short* __restrict__ Xh,
                                                 const int* __restrict__ cnt,
                                                 const int* __restrict__ offs,
                                                 const int* __restrict__ csr,
                                                 unsigned short* __restrict__ Oh) {
  int wid = threadIdx.x >> 6, lane = threadIdx.x & 63;
  int node = blockIdx.x * 4 + wid;
  if (node >= Nn) return;
  int o8 = lane >> 3;         // edge offset 0..7
  int cg = (lane & 7) * 8;    // col group
  float s[8] = {0.f, 0.f, 0.f, 0.f, 0.f, 0.f, 0.f, 0.f};
  int j0 = offs[node], j1 = offs[node + 1];
  for (int j = j0; j < j1; j += 8) {
    int e = j + o8;
    if (e < j1) {
      short8 v = *(const short8*)(Xh + (size_t)csr[e] * 64 + cg);
      #pragma unroll
      for (int q = 0; q < 8; q++) s[q] += bf2f((unsigned short)v[q]);
    }
  }
  #pragma unroll
  for (int q = 0; q < 8; q++) {
    s[q] += __shfl_xor(s[q], 32);
    s[q] += __shfl_xor(s[q], 16);
    s[q] += __shfl_xor(s[q], 8);
  }
  if (o8 == 0) {
    float inv = 1.f / fmaxf((float)cnt[node], 1.f);
    short8 o;
    #pragma unroll
    for (int q = 0; q < 8; q++) o[q] = (short)f2bf_rtn(s[q] * inv);
    *(short8*)(Oh + (size_t)node * 64 + cg) = o;
  }
}

// 256-wide bf16: 32 lanes/row (ushort8), 2 edges per wave-iteration.
__global__ __launch_bounds__(256) void k_pull256b(const unsigned short* __restrict__ Xh,
                                                  const int* __restrict__ cnt,
                                                  const int* __restrict__ offs,
                                                  const int* __restrict__ csr,
                                                  unsigned short* __restrict__ Oh) {
  int wid = threadIdx.x >> 6, lane = threadIdx.x & 63;
  int node = blockIdx.x * 4 + wid;
  if (node >= Nn) return;
  int half = lane >> 5;        // edge offset 0..1
  int cg = (lane & 31) * 8;    // col group
  float s[8] = {0.f, 0.f, 0.f, 0.f, 0.f, 0.f, 0.f, 0.f};
  int j0 = offs[node], j1 = offs[node + 1];
  for (int j = j0; j < j1; j += 2) {
    int e = j + half;
    if (e < j1) {
      short8 v = *(const short8*)(Xh + (size_t)csr[e] * 256 + cg);
      #pragma unroll
      for (int q = 0; q < 8; q++) s[q] += bf2f((unsigned short)v[q]);
    }
  }
  #pragma unroll
  for (int q = 0; q < 8; q++) s[q] += __shfl_xor(s[q], 32);
  if (half == 0) {
    float inv = 1.f / fmaxf((float)cnt[node], 1.f);
    short8 o;
    #pragma unroll
    for (int q = 0; q < 8; q++) o[q] = (short)f2bf_rtn(s[q] * inv);
    *(short8*)(Oh + (size_t)node * 256 + cg) = o;
  }
}

// 128-wide bf16 in, fp32 out: 16 lanes/row (ushort8), 4 edges per wave-iteration.
__global__ __launch_bounds__(256) void k_pullh(const unsigned short* __restrict__ P,
                                               const int* __restrict__ cnt,
                                               const int* __restrict__ offs,
                                               const int* __restrict__ csr,
                                               float* __restrict__ AG) {
  int wid = threadIdx.x >> 6, lane = threadIdx.x & 63;
  int node = blockIdx.x * 4 + wid;
  if (node >= Nn) return;
  int q4 = lane >> 4;          // edge offset 0..3
  int cg = (lane & 15) * 8;    // col group
  float s[8] = {0.f, 0.f, 0.f, 0.f, 0.f, 0.f, 0.f, 0.f};
  int j0 = offs[node], j1 = offs[node + 1];
  for (int j = j0; j < j1; j += 4) {
    int e = j + q4;
    if (e < j1) {
      short8 v = *(const short8*)(P + (size_t)csr[e] * 128 + cg);
      #pragma unroll
      for (int q = 0; q < 8; q++) s[q] += bf2f((unsigned short)v[q]);
    }
  }
  #pragma unroll
  for (int q = 0; q < 8; q++) {
    s[q] += __shfl_xor(s[q], 32);
    s[q] += __shfl_xor(s[q], 16);
  }
  if (q4 == 0) {
    float inv = 1.f / fmaxf((float)cnt[node], 1.f);
    float* dst = AG + (size_t)node * 128 + cg;
    *(float4*)dst = make_float4(s[0] * inv, s[1] * inv, s[2] * inv, s[3] * inv);
    *(float4*)(dst + 4) = make_float4(s[4] * inv, s[5] * inv, s[6] * inv, s[7] * inv);
  }
}

// ---------------- weight prep: W[K][N] fp32 -> Wt hi/lo [N][K] bf16 ----------------
__global__ void k_prep(const float* __restrict__ W, int K, int N,
                       unsigned short* __restrict__ Hi, unsigned short* __restrict__ Lo) {
  int idx = blockIdx.x * 256 + threadIdx.x;
  if (idx >= K * N) return;
  int k = idx / N, n = idx - k * N;
  float x = W[idx];
  unsigned short h = f2bf_rtn(x);
  Hi[(size_t)n * K + k] = h;
  Lo[(size_t)n * K + k] = f2bf_rtn(x - bf2f(h));
}

__global__ void k_bias_pad(const float* __restrict__ b, float* __restrict__ out) {
  int i = threadIdx.x;
  out[i] = (i < 128) ? b[i] : 0.f;
}

// ---------------- bf16-A x split-bf16-B MFMA GEMM, BM=64 BN=256 BK=32 ----------------
template <int PASSES, bool RELU, bool SPLITOUT>
__global__ __launch_bounds__(256) void k_gemm(
    const unsigned short* __restrict__ A1,
    const unsigned short* __restrict__ B1h, const unsigned short* __restrict__ B1l,
    const unsigned short* __restrict__ A2,
    const unsigned short* __restrict__ B2h, const unsigned short* __restrict__ B2l,
    const float* __restrict__ bias,
    unsigned short* __restrict__ Cb, float* __restrict__ S3, unsigned short* __restrict__ P3,
    int K) {
  __shared__ __align__(16) unsigned short Ash[64 * 32];
  __shared__ __align__(16) unsigned short Bsh[256 * 32];
  __shared__ __align__(16) unsigned short Bsl[256 * 32];
  const int tid = threadIdx.x;
  const int lane = tid & 63;
  const int wid = tid >> 6;
  const int l15 = lane & 15, l4 = lane >> 4;
  const int wm = (wid >> 1) * 32;
  const int wn2 = (wid & 1) * 128;
  const int row0 = blockIdx.x * 64;
  const int srow = lane >> 2;
  const int sg = ((lane & 3) ^ ((lane >> 3) & 3)) * 8;
  const int gsw = (l4 ^ ((l15 >> 1) & 3)) * 8;

  f32x4 acc[2][8];
  #pragma unroll
  for (int s = 0; s < 2; ++s)
    #pragma unroll
    for (int t = 0; t < 8; ++t) acc[s][t] = (f32x4)0.0f;

  for (int pass = 0; pass < PASSES; ++pass) {
    const unsigned short* gA = pass ? A2 : A1;
    const unsigned short* gBh = pass ? B2h : B1h;
    const unsigned short* gBl = pass ? B2l : B1l;
    for (int k0 = 0; k0 < K; k0 += 32) {
      __syncthreads();
      #pragma unroll
      for (int cc = 0; cc < 9; ++cc) {
        int c = wid * 9 + cc;
        unsigned short* lb;
        const unsigned short* gb;
        int grow;
        if (c < 4)       { lb = Ash + c * 512;        gb = gA;  grow = row0 + c * 16 + srow; }
        else if (c < 20) { int q = c - 4;  lb = Bsh + q * 512; gb = gBh; grow = q * 16 + srow; }
        else             { int q = c - 20; lb = Bsl + q * 512; gb = gBl; grow = q * 16 + srow; }
        __builtin_amdgcn_global_load_lds(
            (const __attribute__((address_space(1))) void*)(gb + (size_t)grow * K + k0 + sg),
            (__attribute__((address_space(3))) void*)lb, 16, 0, 0);
      }
      __syncthreads();
      short8 af[2];
      #pragma unroll
      for (int s = 0; s < 2; ++s)
        af[s] = *(const short8*)&Ash[(wm + s * 16 + l15) * 32 + gsw];
      #pragma unroll
      for (int t = 0; t < 8; ++t) {
        short8 b = *(const short8*)&Bsh[(wn2 + t * 16 + l15) * 32 + gsw];
        acc[0][t] = __builtin_amdgcn_mfma_f32_16x16x32_bf16(af[0], b, acc[0][t], 0, 0, 0);
        acc[1][t] = __builtin_amdgcn_mfma_f32_16x16x32_bf16(af[1], b, acc[1][t], 0, 0, 0);
      }
      #pragma unroll
      for (int t = 0; t < 8; ++t) {
        short8 b = *(const short8*)&Bsl[(wn2 + t * 16 + l15) * 32 + gsw];
        acc[0][t] = __builtin_amdgcn_mfma_f32_16x16x32_bf16(af[0], b, acc[0][t], 0, 0, 0);
        acc[1][t] = __builtin_amdgcn_mfma_f32_16x16x32_bf16(af[1], b, acc[1][t], 0, 0, 0);
      }
    }
  }
  #pragma unroll
  for (int t = 0; t < 8; ++t) {
    int col = wn2 + t * 16 + l15;
    float bv = bias[col];
    #pragma unroll
    for (int s = 0; s < 2; ++s) {
      #pragma unroll
      for (int j = 0; j < 4; ++j) {
        int row = row0 + wm + s * 16 + l4 * 4 + j;
        if (row < Nn) {
          float v = acc[s][t][j] + bv;
          if (RELU) v = fmaxf(v, 0.f);
          if (SPLITOUT) {
            if (col < 128) S3[(size_t)row * 128 + col] = v;
            else P3[(size_t)row * 128 + col - 128] = f2bf_rtn(v);
          } else {
            Cb[(size_t)row * 256 + col] = f2bf_rtn(v);
          }
        }
      }
    }
  }
}

// ---------------- fused final: h3 = relu(S3 + AG3); out = h3 @ clw + clb ----------------
__global__ __launch_bounds__(256) void k_cls2(const float* __restrict__ S3,
                                              const float* __restrict__ AG3,
                                              const float* __restrict__ W,
                                              const float* __restrict__ B,
                                              float* __restrict__ out) {
  __shared__ float sw[1024];
  __shared__ float sb[8];
  for (int i = threadIdx.x; i < 1024; i += 256) sw[i] = W[i];
  if (threadIdx.x < 8) sb[threadIdx.x] = B[threadIdx.x];
  __syncthreads();
  int node = blockIdx.x * 256 + threadIdx.x;
  if (node >= Nn) return;
  float acc[8];
  #pragma unroll
  for (int o = 0; o < 8; o++) acc[o] = sb[o];
  const float4* s4 = (const float4*)(S3 + (size_t)node * 128);
  const float4* a4 = (const float4*)(AG3 + (size_t)node * 128);
  for (int k4 = 0; k4 < 32; k4++) {
    float4 sv = s4[k4];
    float4 av = a4[k4];
    float vv[4] = {fmaxf(sv.x + av.x, 0.f), fmaxf(sv.y + av.y, 0.f),
                   fmaxf(sv.z + av.z, 0.f), fmaxf(sv.w + av.w, 0.f)};
    #pragma unroll
    for (int j = 0; j < 4; j++) {
      int k = k4 * 4 + j;
      #pragma unroll
      for (int o = 0; o < 8; o++) acc[o] += vv[j] * sw[k * 8 + o];
    }
  }
  float4* orow = (float4*)(out + (size_t)node * 8);
  orow[0] = make_float4(acc[0], acc[1], acc[2], acc[3]);
  orow[1] = make_float4(acc[4], acc[5], acc[6], acc[7]);
}

extern "C" void kernel_launch(void* const* d_in, const int* in_sizes, int n_in,
                              void* d_out, int out_size, void* d_ws, size_t ws_size,
                              hipStream_t stream) {
  (void)in_sizes; (void)n_in; (void)out_size; (void)ws_size;
  const float* feat = (const float*)d_in[0];
  const int* eidx = (const int*)d_in[1];
  const int* esrc = eidx;
  const int* edst = eidx + Ee;
  const float* gw1 = (const float*)d_in[2];  const float* gb1 = (const float*)d_in[3];
  const float* gw2 = (const float*)d_in[4];  const float* gb2 = (const float*)d_in[5];
  const float* aw1 = (const float*)d_in[6];  const float* ab1 = (const float*)d_in[7];
  const float* aw2 = (const float*)d_in[8];  const float* ab2 = (const float*)d_in[9];
  const float* c1ws = (const float*)d_in[10]; const float* c1wn = (const float*)d_in[11]; const float* c1b = (const float*)d_in[12];
  const float* c2ws = (const float*)d_in[13]; const float* c2wn = (const float*)d_in[14]; const float* c2b = (const float*)d_in[15];
  const float* c3ws = (const float*)d_in[16]; const float* c3wn = (const float*)d_in[17]; const float* c3b = (const float*)d_in[18];
  const float* clw = (const float*)d_in[19];  const float* clb = (const float*)d_in[20];
  float* out = (float*)d_out;

  char* ws = (char*)d_ws;
  size_t off = 0;
  auto alloc = [&](size_t b) -> char* {
    char* p = ws + off;
    off = (off + b + 255) & ~(size_t)255;
    return p;
  };
  int* cnt = (int*)alloc(Nn * 4);
  int* cur = (int*)alloc(Nn * 4);
  double* accF = (double*)alloc(128 * 8);
  double* accR = (double*)alloc(128 * 8);
  double* accZ = (double*)alloc(128 * 8);
  size_t zbytes = off;  // region above must be zeroed
  int* offs = (int*)alloc((size_t)(Nn + 1) * 4);
  int* csr = (int*)alloc((size_t)Ee * 4);
  float* dinv = (float*)alloc(Nn * 4);
  float* fm = (float*)alloc(64 * 4); float* fr = (float*)alloc(64 * 4);
  float* rm = (float*)alloc(64 * 4); float* rr = (float*)alloc(64 * 4);
  float* zm = (float*)alloc(64 * 4); float* zr = (float*)alloc(64 * 4);
  // weight splits (transposed [256][K])
  unsigned short* B1sh = (unsigned short*)alloc(256 * 64 * 2);
  unsigned short* B1sl = (unsigned short*)alloc(256 * 64 * 2);
  unsigned short* B1nh = (unsigned short*)alloc(256 * 64 * 2);
  unsigned short* B1nl = (unsigned short*)alloc(256 * 64 * 2);
  unsigned short* B2sh = (unsigned short*)alloc(256 * 256 * 2);
  unsigned short* B2sl = (unsigned short*)alloc(256 * 256 * 2);
  unsigned short* B2nh = (unsigned short*)alloc(256 * 256 * 2);
  unsigned short* B2nl = (unsigned short*)alloc(256 * 256 * 2);
  unsigned short* B3h = (unsigned short*)alloc(256 * 256 * 2);
  unsigned short* B3l = (unsigned short*)alloc(256 * 256 * 2);
  float* b3p = (float*)alloc(256 * 4);
  // activations
  float* Xs = (float*)alloc((size_t)Nn * 64 * 4);            // 12.8 MB (scaled feat)
  float* Zf = (float*)alloc((size_t)Nn * 64 * 4);            // 12.8 MB
  unsigned short* H0h = (unsigned short*)alloc((size_t)Nn * 64 * 2);   // 6.4
  unsigned short* AG0 = (unsigned short*)alloc((size_t)Nn * 64 * 2);   // 6.4
  unsigned short* H1h = (unsigned short*)alloc((size_t)Nn * 256 * 2);  // 25.6
  unsigned short* AG1 = (unsigned short*)alloc((size_t)Nn * 256 * 2);  // 25.6
  unsigned short* H2h = (unsigned short*)alloc((size_t)Nn * 256 * 2);  // 25.6
  alloc(65536);  // guard for OOB A-row staging (rows 50000..50047)
  float* S3f = (float*)Zf;            // 25.6 MB alias over {Zf,H0h,AG0} (dead after GEMM1)
  float* AG3 = (float*)H1h;           // 25.6 MB alias (H1 dead after GEMM2)
  unsigned short* P3h = AG1;          // 12.8 MB alias (AG1 dead after GEMM2)

  hipMemsetAsync(d_ws, 0, zbytes, stream);

  // weight prep
  hipLaunchKernelGGL(k_prep, dim3(64), dim3(256), 0, stream, c1ws, 64, 256, B1sh, B1sl);
  hipLaunchKernelGGL(k_prep, dim3(64), dim3(256), 0, stream, c1wn, 64, 256, B1nh, B1nl);
  hipLaunchKernelGGL(k_prep, dim3(256), dim3(256), 0, stream, c2ws, 256, 256, B2sh, B2sl);
  hipLaunchKernelGGL(k_prep, dim3(256), dim3(256), 0, stream, c2wn, 256, 256, B2nh, B2nl);
  hipLaunchKernelGGL(k_prep, dim3(128), dim3(256), 0, stream, c3ws, 256, 128, B3h, B3l);
  hipLaunchKernelGGL(k_prep, dim3(128), dim3(256), 0, stream, c3wn, 256, 128,
                     B3h + 128 * 256, B3l + 128 * 256);
  hipLaunchKernelGGL(k_bias_pad, dim3(1), dim3(256), 0, stream, c3b, b3p);

  int eb = (Ee + 255) / 256;
  hipLaunchKernelGGL(k_count, dim3(eb), dim3(256), 0, stream, edst, cnt);
  hipLaunchKernelGGL(k_scan, dim3(1), dim3(1024), 0, stream, cnt, offs, dinv);
  hipLaunchKernelGGL(k_scatter, dim3(eb), dim3(256), 0, stream, esrc, edst, offs, cur, csr);
  hipLaunchKernelGGL(k_xs, dim3((Nn * 16 + 255) / 256), dim3(256), 0, stream, feat, dinv, Xs);

  hipLaunchKernelGGL(k_stats, dim3(196), dim3(256), 0, stream, feat, accF);
  hipLaunchKernelGGL(k_stats_final, dim3(1), dim3(64), 0, stream, accF, fm, fr);

  hipLaunchKernelGGL(k_energy, dim3((Nn + 3) / 4), dim3(256), 0, stream,
                     Xs, cnt, offs, csr, Zf);
  hipLaunchKernelGGL(k_stats, dim3(196), dim3(256), 0, stream, Zf, accR);
  hipLaunchKernelGGL(k_stats_final, dim3(1), dim3(64), 0, stream, accR, rm, rr);

  hipLaunchKernelGGL(k_gate, dim3((Nn + 255) / 256), dim3(256), 0, stream,
                     feat, fm, fr, rm, rr, gw1, gb1, gw2, gb2, Zf);
  hipLaunchKernelGGL(k_stats, dim3(196), dim3(256), 0, stream, Zf, accZ);
  hipLaunchKernelGGL(k_stats_final, dim3(1), dim3(64), 0, stream, accZ, zm, zr);

  hipLaunchKernelGGL(k_attn, dim3((Nn + 255) / 256), dim3(256), 0, stream,
                     zm, zr, aw1, ab1, aw2, ab2, Zf, H0h);

  hipLaunchKernelGGL(k_pull64b, dim3((Nn + 3) / 4), dim3(256), 0, stream,
                     H0h, cnt, offs, csr, AG0);
  hipLaunchKernelGGL((k_gemm<2, true, false>), dim3(782), dim3(256), 0, stream,
                     H0h, B1sh, B1sl, AG0, B1nh, B1nl, c1b,
                     H1h, (float*)nullptr, (unsigned short*)nullptr, 64);
  hipLaunchKernelGGL(k_pull256b, dim3((Nn + 3) / 4), dim3(256), 0, stream,
                     H1h, cnt, offs, csr, AG1);
  hipLaunchKernelGGL((k_gemm<2, true, false>), dim3(782), dim3(256), 0, stream,
                     H1h, B2sh, B2sl, AG1, B2nh, B2nl, c2b,
                     H2h, (float*)nullptr, (unsigned short*)nullptr, 256);
  hipLaunchKernelGGL((k_gemm<1, false, true>), dim3(782), dim3(256), 0, stream,
                     H2h, B3h, B3l,
                     (unsigned short*)nullptr, (unsigned short*)nullptr, (unsigned short*)nullptr,
                     b3p, (unsigned short*)nullptr, S3f, P3h, 256);
  hipLaunchKernelGGL(k_pullh, dim3((Nn + 3) / 4), dim3(256), 0, stream,
                     P3h, cnt, offs, csr, AG3);
  hipLaunchKernelGGL(k_cls2, dim3((Nn + 255) / 256), dim3(256), 0, stream,
                     S3f, AG3, clw, clb, out);
}

// Round 6
// 655.533 us; speedup vs baseline: 2.3276x; 1.1459x over previous
//
#include <hip/hip_runtime.h>
#include <math.h>

constexpr int Nn = 50000;
constexpr int Ee = 800000;
constexpr int NBLK = (Nn + 255) / 256;  // 196

typedef __attribute__((ext_vector_type(8))) short short8;
typedef __attribute__((ext_vector_type(4))) float f32x4;

__device__ inline unsigned short f2bf_rtn(float f) {
  union { float f; unsigned u; } v; v.f = f;
  unsigned r = v.u + 0x7FFFu + ((v.u >> 16) & 1u);
  return (unsigned short)(r >> 16);
}
__device__ inline float bf2f(unsigned short h) {
  union { unsigned u; float f; } v; v.u = ((unsigned)h) << 16;
  return v.f;
}

// ---------------- CSR build ----------------
__global__ void k_count(const int* __restrict__ dst, int* __restrict__ cnt) {
  int e = blockIdx.x * 256 + threadIdx.x;
  if (e < Ee) atomicAdd(&cnt[dst[e]], 1);
}

// per-block sums of cnt
__global__ __launch_bounds__(256) void k_bsum(const int* __restrict__ cnt, int* __restrict__ bsum) {
  __shared__ int sh[256];
  int i = blockIdx.x * 256 + threadIdx.x;
  int v = (i < Nn) ? cnt[i] : 0;
  sh[threadIdx.x] = v;
  __syncthreads();
  #pragma unroll
  for (int off = 128; off > 0; off >>= 1) {
    if (threadIdx.x < off) sh[threadIdx.x] += sh[threadIdx.x + off];
    __syncthreads();
  }
  if (threadIdx.x == 0) bsum[blockIdx.x] = sh[0];
}

// scan the 196 block sums (one tiny block)
__global__ __launch_bounds__(256) void k_bscan(const int* __restrict__ bsum,
                                               int* __restrict__ bbase, int* __restrict__ offs) {
  __shared__ int sh[256];
  int t = threadIdx.x;
  int v = (t < NBLK) ? bsum[t] : 0;
  sh[t] = v;
  __syncthreads();
  #pragma unroll
  for (int off = 1; off < 256; off <<= 1) {
    int u = (t >= off) ? sh[t - off] : 0;
    __syncthreads();
    sh[t] += u;
    __syncthreads();
  }
  if (t < NBLK) bbase[t] = sh[t] - v;
  if (t == 0) offs[Nn] = Ee;
}

// per-element exclusive scan + dinv
__global__ __launch_bounds__(256) void k_offsets(const int* __restrict__ cnt,
                                                 const int* __restrict__ bbase,
                                                 int* __restrict__ offs, float* __restrict__ dinv) {
  __shared__ int sh[256];
  int i = blockIdx.x * 256 + threadIdx.x;
  int t = threadIdx.x;
  int v = (i < Nn) ? cnt[i] : 0;
  sh[t] = v;
  __syncthreads();
  #pragma unroll
  for (int off = 1; off < 256; off <<= 1) {
    int u = (t >= off) ? sh[t - off] : 0;
    __syncthreads();
    sh[t] += u;
    __syncthreads();
  }
  if (i < Nn) {
    offs[i] = bbase[blockIdx.x] + sh[t] - v;
    dinv[i] = rsqrtf(fmaxf((float)v, 1e-12f));
  }
}

__global__ void k_scatter(const int* __restrict__ src, const int* __restrict__ dst,
                          const int* __restrict__ offs, int* __restrict__ cur,
                          int* __restrict__ csr) {
  int e = blockIdx.x * 256 + threadIdx.x;
  if (e < Ee) {
    int d = dst[e];
    int p = offs[d] + atomicAdd(&cur[d], 1);
    csr[p] = src[e];
  }
}

// Xs = feat * dinv[node] (row-scaled features for energy)
__global__ void k_xs(const float* __restrict__ feat, const float* __restrict__ dinv,
                     float* __restrict__ Xs) {
  int i = blockIdx.x * 256 + threadIdx.x;
  if (i < Nn * 16) {
    float d = dinv[i >> 4];
    float4 v = ((const float4*)feat)[i];
    ((float4*)Xs)[i] = make_float4(v.x * d, v.y * d, v.z * d, v.w * d);
  }
}

// ---------------- column stats (64-wide, ddof=1) ----------------
__global__ __launch_bounds__(256) void k_stats(const float* __restrict__ X, double* __restrict__ acc) {
  int col = threadIdx.x & 63, rs_ = threadIdx.x >> 6;
  int row0 = blockIdx.x * 256;
  int rend = min(row0 + 256, Nn);
  double s = 0.0, ss = 0.0;
  for (int r = row0 + rs_; r < rend; r += 4) {
    float v = X[(size_t)r * 64 + col];
    s += v; ss += (double)v * v;
  }
  __shared__ double sh[512];
  sh[threadIdx.x] = s; sh[256 + threadIdx.x] = ss;
  __syncthreads();
  if (rs_ == 0) {
    s = sh[col] + sh[col + 64] + sh[col + 128] + sh[col + 192];
    ss = sh[256 + col] + sh[256 + col + 64] + sh[256 + col + 128] + sh[256 + col + 192];
    atomicAdd(&acc[col], s);
    atomicAdd(&acc[64 + col], ss);
  }
}

__global__ void k_stats_final(const double* __restrict__ acc, float* __restrict__ mean,
                              float* __restrict__ rstd) {
  int c = threadIdx.x;
  if (c < 64) {
    double s = acc[c], ss = acc[64 + c];
    double m = s / (double)Nn;
    double var = (ss - s * s / (double)Nn) / (double)(Nn - 1);
    double sd = sqrt(var > 0.0 ? var : 0.0);
    if (sd < 1e-8) sd = 1e-8;
    mean[c] = (float)m;
    rstd[c] = (float)(1.0 / sd);
  }
}

// ---------------- local Dirichlet energy: 4 edges/wave-iter, float4 lanes ----------------
__global__ __launch_bounds__(256) void k_energy(const float* __restrict__ Xs,
                                                const int* __restrict__ cnt,
                                                const int* __restrict__ offs,
                                                const int* __restrict__ csr,
                                                float* __restrict__ R) {
  int wid = threadIdx.x >> 6, lane = threadIdx.x & 63;
  int node = blockIdx.x * 4 + wid;
  if (node >= Nn) return;
  int q4 = lane >> 4;          // edge offset 0..3
  int cg = (lane & 15) * 4;    // 4 cols per lane
  float4 xi = *(const float4*)(Xs + (size_t)node * 64 + cg);
  float num[4] = {0.f, 0.f, 0.f, 0.f}, den[4] = {0.f, 0.f, 0.f, 0.f};
  int j0 = offs[node], j1 = offs[node + 1];
  for (int j = j0; j < j1; j += 4) {
    int e = j + q4;
    if (e < j1) {
      float4 xs = *(const float4*)(Xs + (size_t)csr[e] * 64 + cg);
      float d0 = xi.x - xs.x, d1 = xi.y - xs.y, d2 = xi.z - xs.z, d3 = xi.w - xs.w;
      num[0] += d0 * d0; num[1] += d1 * d1; num[2] += d2 * d2; num[3] += d3 * d3;
      den[0] += xs.x * xs.x; den[1] += xs.y * xs.y; den[2] += xs.z * xs.z; den[3] += xs.w * xs.w;
    }
  }
  #pragma unroll
  for (int c = 0; c < 4; c++) {
    num[c] += __shfl_xor(num[c], 32); num[c] += __shfl_xor(num[c], 16);
    den[c] += __shfl_xor(den[c], 32); den[c] += __shfl_xor(den[c], 16);
  }
  if (q4 == 0) {
    float degf = (float)cnt[node];
    float4 o;
    o.x = num[0] / (den[0] + degf * xi.x * xi.x + 1e-8f);
    o.y = num[1] / (den[1] + degf * xi.y * xi.y + 1e-8f);
    o.z = num[2] / (den[2] + degf * xi.z * xi.z + 1e-8f);
    o.w = num[3] / (den[3] + degf * xi.w * xi.w + 1e-8f);
    *(float4*)(R + (size_t)node * 64 + cg) = o;
  }
}

// ---------------- gate MLP + Z (in-place R -> Z, fp32) ----------------
__global__ __launch_bounds__(256) void k_gate(const float* __restrict__ feat,
                                              const float* __restrict__ fm, const float* __restrict__ fr,
                                              const float* __restrict__ rm, const float* __restrict__ rr,
                                              const float* __restrict__ w1, const float* __restrict__ b1,
                                              const float* __restrict__ w2, const float* __restrict__ b2,
                                              float* __restrict__ RZ) {
  __shared__ float sw1[1024], sw2[1024], sb1[16], sb2[64], sfm[64], sfr[64], srm[64], srr[64];
  for (int i = threadIdx.x; i < 1024; i += 256) { sw1[i] = w1[i]; sw2[i] = w2[i]; }
  if (threadIdx.x < 16) sb1[threadIdx.x] = b1[threadIdx.x];
  if (threadIdx.x < 64) {
    sb2[threadIdx.x] = b2[threadIdx.x];
    sfm[threadIdx.x] = fm[threadIdx.x]; sfr[threadIdx.x] = fr[threadIdx.x];
    srm[threadIdx.x] = rm[threadIdx.x]; srr[threadIdx.x] = rr[threadIdx.x];
  }
  __syncthreads();
  int node = blockIdx.x * 256 + threadIdx.x;
  if (node >= Nn) return;
  float xn[64];
  const float4* fx = (const float4*)(feat + (size_t)node * 64);
  for (int q = 0; q < 16; q++) {
    float4 v = fx[q];
    xn[q * 4 + 0] = (v.x - sfm[q * 4 + 0]) * sfr[q * 4 + 0];
    xn[q * 4 + 1] = (v.y - sfm[q * 4 + 1]) * sfr[q * 4 + 1];
    xn[q * 4 + 2] = (v.z - sfm[q * 4 + 2]) * sfr[q * 4 + 2];
    xn[q * 4 + 3] = (v.w - sfm[q * 4 + 3]) * sfr[q * 4 + 3];
  }
  float hid[16];
  #pragma unroll
  for (int h = 0; h < 16; h++) {
    float a = sb1[h];
    #pragma unroll
    for (int k = 0; k < 64; k++) a += xn[k] * sw1[k * 16 + h];
    hid[h] = fmaxf(a, 0.f);
  }
  float4* row = (float4*)(RZ + (size_t)node * 64);
  for (int q = 0; q < 16; q++) {
    float4 rv = row[q];
    float Rv[4] = {rv.x, rv.y, rv.z, rv.w};
    float zo[4];
    #pragma unroll
    for (int j = 0; j < 4; j++) {
      int o = q * 4 + j;
      float a = sb2[o];
      #pragma unroll
      for (int h = 0; h < 16; h++) a += hid[h] * sw2[h * 64 + o];
      float g = 1.f / (1.f + expf(-a));
      float Rn = (Rv[j] - srm[o]) * srr[o];
      float Rf = (2.f - Rv[j] - srm[o]) * srr[o];
      zo[j] = g * Rn + (1.f - g) * Rf;
    }
    row[q] = make_float4(zo[0], zo[1], zo[2], zo[3]);
  }
}

// ---------------- attn MLP + h0 = en*attn (Z fp32 -> H0 bf16) ----------------
__global__ __launch_bounds__(256) void k_attn(const float* __restrict__ zm, const float* __restrict__ zr,
                                              const float* __restrict__ w1, const float* __restrict__ b1,
                                              const float* __restrict__ w2, const float* __restrict__ b2,
                                              const float* __restrict__ Zf,
                                              unsigned short* __restrict__ Hh) {
  __shared__ float sw1[1024], sw2[1024], sb1[16], sb2[64], szm[64], szr[64];
  for (int i = threadIdx.x; i < 1024; i += 256) { sw1[i] = w1[i]; sw2[i] = w2[i]; }
  if (threadIdx.x < 16) sb1[threadIdx.x] = b1[threadIdx.x];
  if (threadIdx.x < 64) {
    sb2[threadIdx.x] = b2[threadIdx.x];
    szm[threadIdx.x] = zm[threadIdx.x]; szr[threadIdx.x] = zr[threadIdx.x];
  }
  __syncthreads();
  int node = blockIdx.x * 256 + threadIdx.x;
  if (node >= Nn) return;
  float en[64];
  const float4* row = (const float4*)(Zf + (size_t)node * 64);
  for (int q = 0; q < 16; q++) {
    float4 v = row[q];
    en[q * 4 + 0] = (v.x - szm[q * 4 + 0]) * szr[q * 4 + 0];
    en[q * 4 + 1] = (v.y - szm[q * 4 + 1]) * szr[q * 4 + 1];
    en[q * 4 + 2] = (v.z - szm[q * 4 + 2]) * szr[q * 4 + 2];
    en[q * 4 + 3] = (v.w - szm[q * 4 + 3]) * szr[q * 4 + 3];
  }
  float hid[16];
  #pragma unroll
  for (int h = 0; h < 16; h++) {
    float a = sb1[h];
    #pragma unroll
    for (int k = 0; k < 64; k++) a += en[k] * sw1[k * 16 + h];
    hid[h] = fmaxf(a, 0.f);
  }
  for (int q = 0; q < 16; q++) {
    ushort4 oh;
    unsigned short hq[4];
    #pragma unroll
    for (int j = 0; j < 4; j++) {
      int o = q * 4 + j;
      float a = sb2[o];
      #pragma unroll
      for (int h = 0; h < 16; h++) a += hid[h] * sw2[h * 64 + o];
      float att = 1.f / (1.f + expf(-a));
      hq[j] = f2bf_rtn(en[o] * att);
    }
    oh.x = hq[0]; oh.y = hq[1]; oh.z = hq[2]; oh.w = hq[3];
    *(ushort4*)(Hh + (size_t)node * 64 + q * 4) = oh;
  }
}

// ---------------- neighbor-mean pulls: wide lanes + multi-edge ILP ----------------
__global__ __launch_bounds__(256) void k_pull64b(const unsigned short* __restrict__ Xh,
                                                 const int* __restrict__ cnt,
                                                 const int* __restrict__ offs,
                                                 const int* __restrict__ csr,
                                                 unsigned short* __restrict__ Oh) {
  int wid = threadIdx.x >> 6, lane = threadIdx.x & 63;
  int node = blockIdx.x * 4 + wid;
  if (node >= Nn) return;
  int o8 = lane >> 3;         // edge offset 0..7
  int cg = (lane & 7) * 8;    // col group
  float s[8] = {0.f, 0.f, 0.f, 0.f, 0.f, 0.f, 0.f, 0.f};
  int j0 = offs[node], j1 = offs[node + 1];
  for (int j = j0; j < j1; j += 8) {
    int e = j + o8;
    if (e < j1) {
      short8 v = *(const short8*)(Xh + (size_t)csr[e] * 64 + cg);
      #pragma unroll
      for (int q = 0; q < 8; q++) s[q] += bf2f((unsigned short)v[q]);
    }
  }
  #pragma unroll
  for (int q = 0; q < 8; q++) {
    s[q] += __shfl_xor(s[q], 32);
    s[q] += __shfl_xor(s[q], 16);
    s[q] += __shfl_xor(s[q], 8);
  }
  if (o8 == 0) {
    float inv = 1.f / fmaxf((float)cnt[node], 1.f);
    short8 o;
    #pragma unroll
    for (int q = 0; q < 8; q++) o[q] = (short)f2bf_rtn(s[q] * inv);
    *(short8*)(Oh + (size_t)node * 64 + cg) = o;
  }
}

__global__ __launch_bounds__(256) void k_pull256b(const unsigned short* __restrict__ Xh,
                                                  const int* __restrict__ cnt,
                                                  const int* __restrict__ offs,
                                                  const int* __restrict__ csr,
                                                  unsigned short* __restrict__ Oh) {
  int wid = threadIdx.x >> 6, lane = threadIdx.x & 63;
  int node = blockIdx.x * 4 + wid;
  if (node >= Nn) return;
  int half = lane >> 5;        // edge offset 0..1
  int cg = (lane & 31) * 8;    // col group
  float s[8] = {0.f, 0.f, 0.f, 0.f, 0.f, 0.f, 0.f, 0.f};
  int j0 = offs[node], j1 = offs[node + 1];
  for (int j = j0; j < j1; j += 2) {
    int e = j + half;
    if (e < j1) {
      short8 v = *(const short8*)(Xh + (size_t)csr[e] * 256 + cg);
      #pragma unroll
      for (int q = 0; q < 8; q++) s[q] += bf2f((unsigned short)v[q]);
    }
  }
  #pragma unroll
  for (int q = 0; q < 8; q++) s[q] += __shfl_xor(s[q], 32);
  if (half == 0) {
    float inv = 1.f / fmaxf((float)cnt[node], 1.f);
    short8 o;
    #pragma unroll
    for (int q = 0; q < 8; q++) o[q] = (short)f2bf_rtn(s[q] * inv);
    *(short8*)(Oh + (size_t)node * 256 + cg) = o;
  }
}

__global__ __launch_bounds__(256) void k_pullh(const unsigned short* __restrict__ P,
                                               const int* __restrict__ cnt,
                                               const int* __restrict__ offs,
                                               const int* __restrict__ csr,
                                               float* __restrict__ AG) {
  int wid = threadIdx.x >> 6, lane = threadIdx.x & 63;
  int node = blockIdx.x * 4 + wid;
  if (node >= Nn) return;
  int q4 = lane >> 4;          // edge offset 0..3
  int cg = (lane & 15) * 8;    // col group
  float s[8] = {0.f, 0.f, 0.f, 0.f, 0.f, 0.f, 0.f, 0.f};
  int j0 = offs[node], j1 = offs[node + 1];
  for (int j = j0; j < j1; j += 4) {
    int e = j + q4;
    if (e < j1) {
      short8 v = *(const short8*)(P + (size_t)csr[e] * 128 + cg);
      #pragma unroll
      for (int q = 0; q < 8; q++) s[q] += bf2f((unsigned short)v[q]);
    }
  }
  #pragma unroll
  for (int q = 0; q < 8; q++) {
    s[q] += __shfl_xor(s[q], 32);
    s[q] += __shfl_xor(s[q], 16);
  }
  if (q4 == 0) {
    float inv = 1.f / fmaxf((float)cnt[node], 1.f);
    float* dst = AG + (size_t)node * 128 + cg;
    *(float4*)dst = make_float4(s[0] * inv, s[1] * inv, s[2] * inv, s[3] * inv);
    *(float4*)(dst + 4) = make_float4(s[4] * inv, s[5] * inv, s[6] * inv, s[7] * inv);
  }
}

// ---------------- weight prep: W[K][N] fp32 -> Wt hi/lo [N][K] bf16 ----------------
__global__ void k_prep(const float* __restrict__ W, int K, int N,
                       unsigned short* __restrict__ Hi, unsigned short* __restrict__ Lo) {
  int idx = blockIdx.x * 256 + threadIdx.x;
  if (idx >= K * N) return;
  int k = idx / N, n = idx - k * N;
  float x = W[idx];
  unsigned short h = f2bf_rtn(x);
  Hi[(size_t)n * K + k] = h;
  Lo[(size_t)n * K + k] = f2bf_rtn(x - bf2f(h));
}

__global__ void k_bias_pad(const float* __restrict__ b, float* __restrict__ out) {
  int i = threadIdx.x;
  out[i] = (i < 128) ? b[i] : 0.f;
}

// ---------------- bf16-A x split-bf16-B MFMA GEMM, BM=64 BN=256 BK=32 ----------------
template <int PASSES, bool RELU, bool SPLITOUT>
__global__ __launch_bounds__(256) void k_gemm(
    const unsigned short* __restrict__ A1,
    const unsigned short* __restrict__ B1h, const unsigned short* __restrict__ B1l,
    const unsigned short* __restrict__ A2,
    const unsigned short* __restrict__ B2h, const unsigned short* __restrict__ B2l,
    const float* __restrict__ bias,
    unsigned short* __restrict__ Cb, float* __restrict__ S3, unsigned short* __restrict__ P3,
    int K) {
  __shared__ __align__(16) unsigned short Ash[64 * 32];
  __shared__ __align__(16) unsigned short Bsh[256 * 32];
  __shared__ __align__(16) unsigned short Bsl[256 * 32];
  const int tid = threadIdx.x;
  const int lane = tid & 63;
  const int wid = tid >> 6;
  const int l15 = lane & 15, l4 = lane >> 4;
  const int wm = (wid >> 1) * 32;
  const int wn2 = (wid & 1) * 128;
  const int row0 = blockIdx.x * 64;
  const int srow = lane >> 2;
  const int sg = ((lane & 3) ^ ((lane >> 3) & 3)) * 8;
  const int gsw = (l4 ^ ((l15 >> 1) & 3)) * 8;

  f32x4 acc[2][8];
  #pragma unroll
  for (int s = 0; s < 2; ++s)
    #pragma unroll
    for (int t = 0; t < 8; ++t) acc[s][t] = (f32x4)0.0f;

  for (int pass = 0; pass < PASSES; ++pass) {
    const unsigned short* gA = pass ? A2 : A1;
    const unsigned short* gBh = pass ? B2h : B1h;
    const unsigned short* gBl = pass ? B2l : B1l;
    for (int k0 = 0; k0 < K; k0 += 32) {
      __syncthreads();
      #pragma unroll
      for (int cc = 0; cc < 9; ++cc) {
        int c = wid * 9 + cc;
        unsigned short* lb;
        const unsigned short* gb;
        int grow;
        if (c < 4)       { lb = Ash + c * 512;        gb = gA;  grow = row0 + c * 16 + srow; }
        else if (c < 20) { int q = c - 4;  lb = Bsh + q * 512; gb = gBh; grow = q * 16 + srow; }
        else             { int q = c - 20; lb = Bsl + q * 512; gb = gBl; grow = q * 16 + srow; }
        __builtin_amdgcn_global_load_lds(
            (const __attribute__((address_space(1))) void*)(gb + (size_t)grow * K + k0 + sg),
            (__attribute__((address_space(3))) void*)lb, 16, 0, 0);
      }
      __syncthreads();
      short8 af[2];
      #pragma unroll
      for (int s = 0; s < 2; ++s)
        af[s] = *(const short8*)&Ash[(wm + s * 16 + l15) * 32 + gsw];
      #pragma unroll
      for (int t = 0; t < 8; ++t) {
        short8 b = *(const short8*)&Bsh[(wn2 + t * 16 + l15) * 32 + gsw];
        acc[0][t] = __builtin_amdgcn_mfma_f32_16x16x32_bf16(af[0], b, acc[0][t], 0, 0, 0);
        acc[1][t] = __builtin_amdgcn_mfma_f32_16x16x32_bf16(af[1], b, acc[1][t], 0, 0, 0);
      }
      #pragma unroll
      for (int t = 0; t < 8; ++t) {
        short8 b = *(const short8*)&Bsl[(wn2 + t * 16 + l15) * 32 + gsw];
        acc[0][t] = __builtin_amdgcn_mfma_f32_16x16x32_bf16(af[0], b, acc[0][t], 0, 0, 0);
        acc[1][t] = __builtin_amdgcn_mfma_f32_16x16x32_bf16(af[1], b, acc[1][t], 0, 0, 0);
      }
    }
  }
  #pragma unroll
  for (int t = 0; t < 8; ++t) {
    int col = wn2 + t * 16 + l15;
    float bv = bias[col];
    #pragma unroll
    for (int s = 0; s < 2; ++s) {
      #pragma unroll
      for (int j = 0; j < 4; ++j) {
        int row = row0 + wm + s * 16 + l4 * 4 + j;
        if (row < Nn) {
          float v = acc[s][t][j] + bv;
          if (RELU) v = fmaxf(v, 0.f);
          if (SPLITOUT) {
            if (col < 128) S3[(size_t)row * 128 + col] = v;
            else P3[(size_t)row * 128 + col - 128] = f2bf_rtn(v);
          } else {
            Cb[(size_t)row * 256 + col] = f2bf_rtn(v);
          }
        }
      }
    }
  }
}

// ---------------- fused final: h3 = relu(S3 + AG3); out = h3 @ clw + clb ----------------
__global__ __launch_bounds__(256) void k_cls2(const float* __restrict__ S3,
                                              const float* __restrict__ AG3,
                                              const float* __restrict__ W,
                                              const float* __restrict__ B,
                                              float* __restrict__ out) {
  __shared__ float sw[1024];
  __shared__ float sb[8];
  for (int i = threadIdx.x; i < 1024; i += 256) sw[i] = W[i];
  if (threadIdx.x < 8) sb[threadIdx.x] = B[threadIdx.x];
  __syncthreads();
  int node = blockIdx.x * 256 + threadIdx.x;
  if (node >= Nn) return;
  float acc[8];
  #pragma unroll
  for (int o = 0; o < 8; o++) acc[o] = sb[o];
  const float4* s4 = (const float4*)(S3 + (size_t)node * 128);
  const float4* a4 = (const float4*)(AG3 + (size_t)node * 128);
  for (int k4 = 0; k4 < 32; k4++) {
    float4 sv = s4[k4];
    float4 av = a4[k4];
    float vv[4] = {fmaxf(sv.x + av.x, 0.f), fmaxf(sv.y + av.y, 0.f),
                   fmaxf(sv.z + av.z, 0.f), fmaxf(sv.w + av.w, 0.f)};
    #pragma unroll
    for (int j = 0; j < 4; j++) {
      int k = k4 * 4 + j;
      #pragma unroll
      for (int o = 0; o < 8; o++) acc[o] += vv[j] * sw[k * 8 + o];
    }
  }
  float4* orow = (float4*)(out + (size_t)node * 8);
  orow[0] = make_float4(acc[0], acc[1], acc[2], acc[3]);
  orow[1] = make_float4(acc[4], acc[5], acc[6], acc[7]);
}

extern "C" void kernel_launch(void* const* d_in, const int* in_sizes, int n_in,
                              void* d_out, int out_size, void* d_ws, size_t ws_size,
                              hipStream_t stream) {
  (void)in_sizes; (void)n_in; (void)out_size; (void)ws_size;
  const float* feat = (const float*)d_in[0];
  const int* eidx = (const int*)d_in[1];
  const int* esrc = eidx;
  const int* edst = eidx + Ee;
  const float* gw1 = (const float*)d_in[2];  const float* gb1 = (const float*)d_in[3];
  const float* gw2 = (const float*)d_in[4];  const float* gb2 = (const float*)d_in[5];
  const float* aw1 = (const float*)d_in[6];  const float* ab1 = (const float*)d_in[7];
  const float* aw2 = (const float*)d_in[8];  const float* ab2 = (const float*)d_in[9];
  const float* c1ws = (const float*)d_in[10]; const float* c1wn = (const float*)d_in[11]; const float* c1b = (const float*)d_in[12];
  const float* c2ws = (const float*)d_in[13]; const float* c2wn = (const float*)d_in[14]; const float* c2b = (const float*)d_in[15];
  const float* c3ws = (const float*)d_in[16]; const float* c3wn = (const float*)d_in[17]; const float* c3b = (const float*)d_in[18];
  const float* clw = (const float*)d_in[19];  const float* clb = (const float*)d_in[20];
  float* out = (float*)d_out;

  char* ws = (char*)d_ws;
  size_t off = 0;
  auto alloc = [&](size_t b) -> char* {
    char* p = ws + off;
    off = (off + b + 255) & ~(size_t)255;
    return p;
  };
  int* cnt = (int*)alloc(Nn * 4);
  int* cur = (int*)alloc(Nn * 4);
  double* accF = (double*)alloc(128 * 8);
  double* accR = (double*)alloc(128 * 8);
  double* accZ = (double*)alloc(128 * 8);
  size_t zbytes = off;  // region above must be zeroed
  int* offs = (int*)alloc((size_t)(Nn + 1) * 4);
  int* csr = (int*)alloc((size_t)Ee * 4);
  int* bsum = (int*)alloc(NBLK * 4);
  int* bbase = (int*)alloc(NBLK * 4);
  float* dinv = (float*)alloc(Nn * 4);
  float* fm = (float*)alloc(64 * 4); float* fr = (float*)alloc(64 * 4);
  float* rm = (float*)alloc(64 * 4); float* rr = (float*)alloc(64 * 4);
  float* zm = (float*)alloc(64 * 4); float* zr = (float*)alloc(64 * 4);
  // weight splits (transposed [256][K])
  unsigned short* B1sh = (unsigned short*)alloc(256 * 64 * 2);
  unsigned short* B1sl = (unsigned short*)alloc(256 * 64 * 2);
  unsigned short* B1nh = (unsigned short*)alloc(256 * 64 * 2);
  unsigned short* B1nl = (unsigned short*)alloc(256 * 64 * 2);
  unsigned short* B2sh = (unsigned short*)alloc(256 * 256 * 2);
  unsigned short* B2sl = (unsigned short*)alloc(256 * 256 * 2);
  unsigned short* B2nh = (unsigned short*)alloc(256 * 256 * 2);
  unsigned short* B2nl = (unsigned short*)alloc(256 * 256 * 2);
  unsigned short* B3h = (unsigned short*)alloc(256 * 256 * 2);
  unsigned short* B3l = (unsigned short*)alloc(256 * 256 * 2);
  float* b3p = (float*)alloc(256 * 4);
  // activations
  float* Xs = (float*)alloc((size_t)Nn * 64 * 4);            // 12.8 MB (scaled feat)
  float* Zf = (float*)alloc((size_t)Nn * 64 * 4);            // 12.8 MB
  unsigned short* H0h = (unsigned short*)alloc((size_t)Nn * 64 * 2);   // 6.4
  unsigned short* AG0 = (unsigned short*)alloc((size_t)Nn * 64 * 2);   // 6.4
  unsigned short* H1h = (unsigned short*)alloc((size_t)Nn * 256 * 2);  // 25.6
  unsigned short* AG1 = (unsigned short*)alloc((size_t)Nn * 256 * 2);  // 25.6
  unsigned short* H2h = (unsigned short*)alloc((size_t)Nn * 256 * 2);  // 25.6
  alloc(65536);  // guard for OOB A-row staging (rows 50000..50047)
  float* S3f = (float*)Zf;            // 25.6 MB alias over {Zf,H0h,AG0} (dead after GEMM1)
  float* AG3 = (float*)H1h;           // 25.6 MB alias (H1 dead after GEMM2)
  unsigned short* P3h = AG1;          // 12.8 MB alias (AG1 dead after GEMM2)

  hipMemsetAsync(d_ws, 0, zbytes, stream);

  // weight prep
  hipLaunchKernelGGL(k_prep, dim3(64), dim3(256), 0, stream, c1ws, 64, 256, B1sh, B1sl);
  hipLaunchKernelGGL(k_prep, dim3(64), dim3(256), 0, stream, c1wn, 64, 256, B1nh, B1nl);
  hipLaunchKernelGGL(k_prep, dim3(256), dim3(256), 0, stream, c2ws, 256, 256, B2sh, B2sl);
  hipLaunchKernelGGL(k_prep, dim3(256), dim3(256), 0, stream, c2wn, 256, 256, B2nh, B2nl);
  hipLaunchKernelGGL(k_prep, dim3(128), dim3(256), 0, stream, c3ws, 256, 128, B3h, B3l);
  hipLaunchKernelGGL(k_prep, dim3(128), dim3(256), 0, stream, c3wn, 256, 128,
                     B3h + 128 * 256, B3l + 128 * 256);
  hipLaunchKernelGGL(k_bias_pad, dim3(1), dim3(256), 0, stream, c3b, b3p);

  int eb = (Ee + 255) / 256;
  hipLaunchKernelGGL(k_count, dim3(eb), dim3(256), 0, stream, edst, cnt);
  hipLaunchKernelGGL(k_bsum, dim3(NBLK), dim3(256), 0, stream, cnt, bsum);
  hipLaunchKernelGGL(k_bscan, dim3(1), dim3(256), 0, stream, bsum, bbase, offs);
  hipLaunchKernelGGL(k_offsets, dim3(NBLK), dim3(256), 0, stream, cnt, bbase, offs, dinv);
  hipLaunchKernelGGL(k_scatter, dim3(eb), dim3(256), 0, stream, esrc, edst, offs, cur, csr);
  hipLaunchKernelGGL(k_xs, dim3((Nn * 16 + 255) / 256), dim3(256), 0, stream, feat, dinv, Xs);

  hipLaunchKernelGGL(k_stats, dim3(196), dim3(256), 0, stream, feat, accF);
  hipLaunchKernelGGL(k_stats_final, dim3(1), dim3(64), 0, stream, accF, fm, fr);

  hipLaunchKernelGGL(k_energy, dim3((Nn + 3) / 4), dim3(256), 0, stream,
                     Xs, cnt, offs, csr, Zf);
  hipLaunchKernelGGL(k_stats, dim3(196), dim3(256), 0, stream, Zf, accR);
  hipLaunchKernelGGL(k_stats_final, dim3(1), dim3(64), 0, stream, accR, rm, rr);

  hipLaunchKernelGGL(k_gate, dim3((Nn + 255) / 256), dim3(256), 0, stream,
                     feat, fm, fr, rm, rr, gw1, gb1, gw2, gb2, Zf);
  hipLaunchKernelGGL(k_stats, dim3(196), dim3(256), 0, stream, Zf, accZ);
  hipLaunchKernelGGL(k_stats_final, dim3(1), dim3(64), 0, stream, accZ, zm, zr);

  hipLaunchKernelGGL(k_attn, dim3((Nn + 255) / 256), dim3(256), 0, stream,
                     zm, zr, aw1, ab1, aw2, ab2, Zf, H0h);

  hipLaunchKernelGGL(k_pull64b, dim3((Nn + 3) / 4), dim3(256), 0, stream,
                     H0h, cnt, offs, csr, AG0);
  hipLaunchKernelGGL((k_gemm<2, true, false>), dim3(782), dim3(256), 0, stream,
                     H0h, B1sh, B1sl, AG0, B1nh, B1nl, c1b,
                     H1h, (float*)nullptr, (unsigned short*)nullptr, 64);
  hipLaunchKernelGGL(k_pull256b, dim3((Nn + 3) / 4), dim3(256), 0, stream,
                     H1h, cnt, offs, csr, AG1);
  hipLaunchKernelGGL((k_gemm<2, true, false>), dim3(782), dim3(256), 0, stream,
                     H1h, B2sh, B2sl, AG1, B2nh, B2nl, c2b,
                     H2h, (float*)nullptr, (unsigned short*)nullptr, 256);
  hipLaunchKernelGGL((k_gemm<1, false, true>), dim3(782), dim3(256), 0, stream,
                     H2h, B3h, B3l,
                     (unsigned short*)nullptr, (unsigned short*)nullptr, (unsigned short*)nullptr,
                     b3p, (unsigned short*)nullptr, S3f, P3h, 256);
  hipLaunchKernelGGL(k_pullh, dim3((Nn + 3) / 4), dim3(256), 0, stream,
                     P3h, cnt, offs, csr, AG3);
  hipLaunchKernelGGL(k_cls2, dim3((Nn + 255) / 256), dim3(256), 0, stream,
                     S3f, AG3, clw, clb, out);
}

// Round 7
// 646.676 us; speedup vs baseline: 2.3595x; 1.0137x over previous
//
#include <hip/hip_runtime.h>
#include <math.h>

constexpr int Nn = 50000;
constexpr int Ee = 800000;
constexpr int NBLK = (Nn + 255) / 256;  // 196

typedef __attribute__((ext_vector_type(8))) short short8;
typedef __attribute__((ext_vector_type(4))) float f32x4;

__device__ inline unsigned short f2bf_rtn(float f) {
  union { float f; unsigned u; } v; v.f = f;
  unsigned r = v.u + 0x7FFFu + ((v.u >> 16) & 1u);
  return (unsigned short)(r >> 16);
}
__device__ inline float bf2f(unsigned short h) {
  union { unsigned u; float f; } v; v.u = ((unsigned)h) << 16;
  return v.f;
}

// ---------------- CSR build ----------------
__global__ void k_count(const int* __restrict__ dst, int* __restrict__ cnt) {
  int e = blockIdx.x * 256 + threadIdx.x;
  if (e < Ee) atomicAdd(&cnt[dst[e]], 1);
}

__global__ __launch_bounds__(256) void k_bsum(const int* __restrict__ cnt, int* __restrict__ bsum) {
  __shared__ int sh[256];
  int i = blockIdx.x * 256 + threadIdx.x;
  int v = (i < Nn) ? cnt[i] : 0;
  sh[threadIdx.x] = v;
  __syncthreads();
  #pragma unroll
  for (int off = 128; off > 0; off >>= 1) {
    if (threadIdx.x < off) sh[threadIdx.x] += sh[threadIdx.x + off];
    __syncthreads();
  }
  if (threadIdx.x == 0) bsum[blockIdx.x] = sh[0];
}

__global__ __launch_bounds__(256) void k_bscan(const int* __restrict__ bsum,
                                               int* __restrict__ bbase, int* __restrict__ offs) {
  __shared__ int sh[256];
  int t = threadIdx.x;
  int v = (t < NBLK) ? bsum[t] : 0;
  sh[t] = v;
  __syncthreads();
  #pragma unroll
  for (int off = 1; off < 256; off <<= 1) {
    int u = (t >= off) ? sh[t - off] : 0;
    __syncthreads();
    sh[t] += u;
    __syncthreads();
  }
  if (t < NBLK) bbase[t] = sh[t] - v;
  if (t == 0) offs[Nn] = Ee;
}

__global__ __launch_bounds__(256) void k_offsets(const int* __restrict__ cnt,
                                                 const int* __restrict__ bbase,
                                                 int* __restrict__ offs, float* __restrict__ dinv) {
  __shared__ int sh[256];
  int i = blockIdx.x * 256 + threadIdx.x;
  int t = threadIdx.x;
  int v = (i < Nn) ? cnt[i] : 0;
  sh[t] = v;
  __syncthreads();
  #pragma unroll
  for (int off = 1; off < 256; off <<= 1) {
    int u = (t >= off) ? sh[t - off] : 0;
    __syncthreads();
    sh[t] += u;
    __syncthreads();
  }
  if (i < Nn) {
    offs[i] = bbase[blockIdx.x] + sh[t] - v;
    dinv[i] = rsqrtf(fmaxf((float)v, 1e-12f));
  }
}

__global__ void k_scatter(const int* __restrict__ src, const int* __restrict__ dst,
                          const int* __restrict__ offs, int* __restrict__ cur,
                          int* __restrict__ csr) {
  int e = blockIdx.x * 256 + threadIdx.x;
  if (e < Ee) {
    int d = dst[e];
    int p = offs[d] + atomicAdd(&cur[d], 1);
    csr[p] = src[e];
  }
}

// Xs = feat * dinv[node]
__global__ void k_xs(const float* __restrict__ feat, const float* __restrict__ dinv,
                     float* __restrict__ Xs) {
  int i = blockIdx.x * 256 + threadIdx.x;
  if (i < Nn * 16) {
    float d = dinv[i >> 4];
    float4 v = ((const float4*)feat)[i];
    ((float4*)Xs)[i] = make_float4(v.x * d, v.y * d, v.z * d, v.w * d);
  }
}

// ---------------- column stats (64-wide, ddof=1) ----------------
__global__ __launch_bounds__(256) void k_stats(const float* __restrict__ X, double* __restrict__ acc) {
  int col = threadIdx.x & 63, rs_ = threadIdx.x >> 6;
  int row0 = blockIdx.x * 256;
  int rend = min(row0 + 256, Nn);
  double s = 0.0, ss = 0.0;
  for (int r = row0 + rs_; r < rend; r += 4) {
    float v = X[(size_t)r * 64 + col];
    s += v; ss += (double)v * v;
  }
  __shared__ double sh[512];
  sh[threadIdx.x] = s; sh[256 + threadIdx.x] = ss;
  __syncthreads();
  if (rs_ == 0) {
    s = sh[col] + sh[col + 64] + sh[col + 128] + sh[col + 192];
    ss = sh[256 + col] + sh[256 + col + 64] + sh[256 + col + 128] + sh[256 + col + 192];
    atomicAdd(&acc[col], s);
    atomicAdd(&acc[64 + col], ss);
  }
}

__global__ void k_stats_final(const double* __restrict__ acc, float* __restrict__ mean,
                              float* __restrict__ rstd) {
  int c = threadIdx.x;
  if (c < 64) {
    double s = acc[c], ss = acc[64 + c];
    double m = s / (double)Nn;
    double var = (ss - s * s / (double)Nn) / (double)(Nn - 1);
    double sd = sqrt(var > 0.0 ? var : 0.0);
    if (sd < 1e-8) sd = 1e-8;
    mean[c] = (float)m;
    rstd[c] = (float)(1.0 / sd);
  }
}

// ---------------- local Dirichlet energy ----------------
__global__ __launch_bounds__(256) void k_energy(const float* __restrict__ Xs,
                                                const int* __restrict__ cnt,
                                                const int* __restrict__ offs,
                                                const int* __restrict__ csr,
                                                float* __restrict__ R) {
  int wid = threadIdx.x >> 6, lane = threadIdx.x & 63;
  int node = blockIdx.x * 4 + wid;
  if (node >= Nn) return;
  int q4 = lane >> 4;
  int cg = (lane & 15) * 4;
  float4 xi = *(const float4*)(Xs + (size_t)node * 64 + cg);
  float num[4] = {0.f, 0.f, 0.f, 0.f}, den[4] = {0.f, 0.f, 0.f, 0.f};
  int j0 = offs[node], j1 = offs[node + 1];
  for (int j = j0; j < j1; j += 4) {
    int e = j + q4;
    if (e < j1) {
      float4 xs = *(const float4*)(Xs + (size_t)csr[e] * 64 + cg);
      float d0 = xi.x - xs.x, d1 = xi.y - xs.y, d2 = xi.z - xs.z, d3 = xi.w - xs.w;
      num[0] += d0 * d0; num[1] += d1 * d1; num[2] += d2 * d2; num[3] += d3 * d3;
      den[0] += xs.x * xs.x; den[1] += xs.y * xs.y; den[2] += xs.z * xs.z; den[3] += xs.w * xs.w;
    }
  }
  #pragma unroll
  for (int c = 0; c < 4; c++) {
    num[c] += __shfl_xor(num[c], 32); num[c] += __shfl_xor(num[c], 16);
    den[c] += __shfl_xor(den[c], 32); den[c] += __shfl_xor(den[c], 16);
  }
  if (q4 == 0) {
    float degf = (float)cnt[node];
    float4 o;
    o.x = num[0] / (den[0] + degf * xi.x * xi.x + 1e-8f);
    o.y = num[1] / (den[1] + degf * xi.y * xi.y + 1e-8f);
    o.z = num[2] / (den[2] + degf * xi.z * xi.z + 1e-8f);
    o.w = num[3] / (den[3] + degf * xi.w * xi.w + 1e-8f);
    *(float4*)(R + (size_t)node * 64 + cg) = o;
  }
}

// ---------------- gate MLP + Z (in-place R -> Z, fp32) ----------------
__global__ __launch_bounds__(256) void k_gate(const float* __restrict__ feat,
                                              const float* __restrict__ fm, const float* __restrict__ fr,
                                              const float* __restrict__ rm, const float* __restrict__ rr,
                                              const float* __restrict__ w1, const float* __restrict__ b1,
                                              const float* __restrict__ w2, const float* __restrict__ b2,
                                              float* __restrict__ RZ) {
  __shared__ float sw1[1024], sw2[1024], sb1[16], sb2[64], sfm[64], sfr[64], srm[64], srr[64];
  for (int i = threadIdx.x; i < 1024; i += 256) { sw1[i] = w1[i]; sw2[i] = w2[i]; }
  if (threadIdx.x < 16) sb1[threadIdx.x] = b1[threadIdx.x];
  if (threadIdx.x < 64) {
    sb2[threadIdx.x] = b2[threadIdx.x];
    sfm[threadIdx.x] = fm[threadIdx.x]; sfr[threadIdx.x] = fr[threadIdx.x];
    srm[threadIdx.x] = rm[threadIdx.x]; srr[threadIdx.x] = rr[threadIdx.x];
  }
  __syncthreads();
  int node = blockIdx.x * 256 + threadIdx.x;
  if (node >= Nn) return;
  float xn[64];
  const float4* fx = (const float4*)(feat + (size_t)node * 64);
  for (int q = 0; q < 16; q++) {
    float4 v = fx[q];
    xn[q * 4 + 0] = (v.x - sfm[q * 4 + 0]) * sfr[q * 4 + 0];
    xn[q * 4 + 1] = (v.y - sfm[q * 4 + 1]) * sfr[q * 4 + 1];
    xn[q * 4 + 2] = (v.z - sfm[q * 4 + 2]) * sfr[q * 4 + 2];
    xn[q * 4 + 3] = (v.w - sfm[q * 4 + 3]) * sfr[q * 4 + 3];
  }
  float hid[16];
  #pragma unroll
  for (int h = 0; h < 16; h++) {
    float a = sb1[h];
    #pragma unroll
    for (int k = 0; k < 64; k++) a += xn[k] * sw1[k * 16 + h];
    hid[h] = fmaxf(a, 0.f);
  }
  float4* row = (float4*)(RZ + (size_t)node * 64);
  for (int q = 0; q < 16; q++) {
    float4 rv = row[q];
    float Rv[4] = {rv.x, rv.y, rv.z, rv.w};
    float zo[4];
    #pragma unroll
    for (int j = 0; j < 4; j++) {
      int o = q * 4 + j;
      float a = sb2[o];
      #pragma unroll
      for (int h = 0; h < 16; h++) a += hid[h] * sw2[h * 64 + o];
      float g = 1.f / (1.f + expf(-a));
      float Rn = (Rv[j] - srm[o]) * srr[o];
      float Rf = (2.f - Rv[j] - srm[o]) * srr[o];
      zo[j] = g * Rn + (1.f - g) * Rf;
    }
    row[q] = make_float4(zo[0], zo[1], zo[2], zo[3]);
  }
}

// ---------------- attn MLP + h0 = en*attn (Z fp32 -> H0 bf16, coalesced store) ----------------
__global__ __launch_bounds__(256) void k_attn(const float* __restrict__ zm, const float* __restrict__ zr,
                                              const float* __restrict__ w1, const float* __restrict__ b1,
                                              const float* __restrict__ w2, const float* __restrict__ b2,
                                              const float* __restrict__ Zf,
                                              unsigned short* __restrict__ Hh) {
  __shared__ float sw1[1024], sw2[1024], sb1[16], sb2[64], szm[64], szr[64];
  __shared__ unsigned short sout[256][72];   // pad 72: 16B-aligned rows, spreads banks
  for (int i = threadIdx.x; i < 1024; i += 256) { sw1[i] = w1[i]; sw2[i] = w2[i]; }
  if (threadIdx.x < 16) sb1[threadIdx.x] = b1[threadIdx.x];
  if (threadIdx.x < 64) {
    sb2[threadIdx.x] = b2[threadIdx.x];
    szm[threadIdx.x] = zm[threadIdx.x]; szr[threadIdx.x] = zr[threadIdx.x];
  }
  __syncthreads();
  int node0 = blockIdx.x * 256;
  int node = node0 + threadIdx.x;
  if (node < Nn) {
    float en[64];
    const float4* row = (const float4*)(Zf + (size_t)node * 64);
    for (int q = 0; q < 16; q++) {
      float4 v = row[q];
      en[q * 4 + 0] = (v.x - szm[q * 4 + 0]) * szr[q * 4 + 0];
      en[q * 4 + 1] = (v.y - szm[q * 4 + 1]) * szr[q * 4 + 1];
      en[q * 4 + 2] = (v.z - szm[q * 4 + 2]) * szr[q * 4 + 2];
      en[q * 4 + 3] = (v.w - szm[q * 4 + 3]) * szr[q * 4 + 3];
    }
    float hid[16];
    #pragma unroll
    for (int h = 0; h < 16; h++) {
      float a = sb1[h];
      #pragma unroll
      for (int k = 0; k < 64; k++) a += en[k] * sw1[k * 16 + h];
      hid[h] = fmaxf(a, 0.f);
    }
    for (int q = 0; q < 16; q++) {
      #pragma unroll
      for (int j = 0; j < 4; j++) {
        int o = q * 4 + j;
        float a = sb2[o];
        #pragma unroll
        for (int h = 0; h < 16; h++) a += hid[h] * sw2[h * 64 + o];
        float att = 1.f / (1.f + expf(-a));
        sout[threadIdx.x][o] = f2bf_rtn(en[o] * att);
      }
    }
  }
  __syncthreads();
  // coalesced copy: 16384 bf16 elements, 8 per thread per pass
  int nval = (min(Nn - node0, 256)) * 64;
  for (int base = 0; base < 16384; base += 2048) {
    int i = base + threadIdx.x * 8;
    if (i < nval) {
      int r = i >> 6, c = i & 63;
      *(short8*)(Hh + (size_t)node0 * 64 + i) = *(const short8*)&sout[r][c];
    }
  }
}

// ---------------- neighbor-mean pulls ----------------
__global__ __launch_bounds__(256) void k_pull64b(const unsigned short* __restrict__ Xh,
                                                 const int* __restrict__ cnt,
                                                 const int* __restrict__ offs,
                                                 const int* __restrict__ csr,
                                                 unsigned short* __restrict__ Oh) {
  int wid = threadIdx.x >> 6, lane = threadIdx.x & 63;
  int node = blockIdx.x * 4 + wid;
  if (node >= Nn) return;
  int o8 = lane >> 3;
  int cg = (lane & 7) * 8;
  float s[8] = {0.f, 0.f, 0.f, 0.f, 0.f, 0.f, 0.f, 0.f};
  int j0 = offs[node], j1 = offs[node + 1];
  for (int j = j0; j < j1; j += 8) {
    int e = j + o8;
    if (e < j1) {
      short8 v = *(const short8*)(Xh + (size_t)csr[e] * 64 + cg);
      #pragma unroll
      for (int q = 0; q < 8; q++) s[q] += bf2f((unsigned short)v[q]);
    }
  }
  #pragma unroll
  for (int q = 0; q < 8; q++) {
    s[q] += __shfl_xor(s[q], 32);
    s[q] += __shfl_xor(s[q], 16);
    s[q] += __shfl_xor(s[q], 8);
  }
  if (o8 == 0) {
    float inv = 1.f / fmaxf((float)cnt[node], 1.f);
    short8 o;
    #pragma unroll
    for (int q = 0; q < 8; q++) o[q] = (short)f2bf_rtn(s[q] * inv);
    *(short8*)(Oh + (size_t)node * 64 + cg) = o;
  }
}

__global__ __launch_bounds__(256) void k_pull256b(const unsigned short* __restrict__ Xh,
                                                  const int* __restrict__ cnt,
                                                  const int* __restrict__ offs,
                                                  const int* __restrict__ csr,
                                                  unsigned short* __restrict__ Oh) {
  int wid = threadIdx.x >> 6, lane = threadIdx.x & 63;
  int node = blockIdx.x * 4 + wid;
  if (node >= Nn) return;
  int half = lane >> 5;
  int cg = (lane & 31) * 8;
  float s[8] = {0.f, 0.f, 0.f, 0.f, 0.f, 0.f, 0.f, 0.f};
  int j0 = offs[node], j1 = offs[node + 1];
  for (int j = j0; j < j1; j += 2) {
    int e = j + half;
    if (e < j1) {
      short8 v = *(const short8*)(Xh + (size_t)csr[e] * 256 + cg);
      #pragma unroll
      for (int q = 0; q < 8; q++) s[q] += bf2f((unsigned short)v[q]);
    }
  }
  #pragma unroll
  for (int q = 0; q < 8; q++) s[q] += __shfl_xor(s[q], 32);
  if (half == 0) {
    float inv = 1.f / fmaxf((float)cnt[node], 1.f);
    short8 o;
    #pragma unroll
    for (int q = 0; q < 8; q++) o[q] = (short)f2bf_rtn(s[q] * inv);
    *(short8*)(Oh + (size_t)node * 256 + cg) = o;
  }
}

__global__ __launch_bounds__(256) void k_pullh(const unsigned short* __restrict__ P,
                                               const int* __restrict__ cnt,
                                               const int* __restrict__ offs,
                                               const int* __restrict__ csr,
                                               float* __restrict__ AG) {
  int wid = threadIdx.x >> 6, lane = threadIdx.x & 63;
  int node = blockIdx.x * 4 + wid;
  if (node >= Nn) return;
  int q4 = lane >> 4;
  int cg = (lane & 15) * 8;
  float s[8] = {0.f, 0.f, 0.f, 0.f, 0.f, 0.f, 0.f, 0.f};
  int j0 = offs[node], j1 = offs[node + 1];
  for (int j = j0; j < j1; j += 4) {
    int e = j + q4;
    if (e < j1) {
      short8 v = *(const short8*)(P + (size_t)csr[e] * 128 + cg);
      #pragma unroll
      for (int q = 0; q < 8; q++) s[q] += bf2f((unsigned short)v[q]);
    }
  }
  #pragma unroll
  for (int q = 0; q < 8; q++) {
    s[q] += __shfl_xor(s[q], 32);
    s[q] += __shfl_xor(s[q], 16);
  }
  if (q4 == 0) {
    float inv = 1.f / fmaxf((float)cnt[node], 1.f);
    float* dst = AG + (size_t)node * 128 + cg;
    *(float4*)dst = make_float4(s[0] * inv, s[1] * inv, s[2] * inv, s[3] * inv);
    *(float4*)(dst + 4) = make_float4(s[4] * inv, s[5] * inv, s[6] * inv, s[7] * inv);
  }
}

// ---------------- weight prep ----------------
__global__ void k_prep(const float* __restrict__ W, int K, int N,
                       unsigned short* __restrict__ Hi, unsigned short* __restrict__ Lo) {
  int idx = blockIdx.x * 256 + threadIdx.x;
  if (idx >= K * N) return;
  int k = idx / N, n = idx - k * N;
  float x = W[idx];
  unsigned short h = f2bf_rtn(x);
  Hi[(size_t)n * K + k] = h;
  Lo[(size_t)n * K + k] = f2bf_rtn(x - bf2f(h));
}

__global__ void k_bias_pad(const float* __restrict__ b, float* __restrict__ out) {
  int i = threadIdx.x;
  out[i] = (i < 128) ? b[i] : 0.f;
}

// ---------------- bf16-A x split-bf16-B MFMA GEMM, BM=128 BN=256 BK=32, dbuf pipeline ----------------
template <int PASSES, bool RELU, bool SPLITOUT>
__global__ __launch_bounds__(256, 2) void k_gemm(
    const unsigned short* __restrict__ A1,
    const unsigned short* __restrict__ B1h, const unsigned short* __restrict__ B1l,
    const unsigned short* __restrict__ A2,
    const unsigned short* __restrict__ B2h, const unsigned short* __restrict__ B2l,
    const float* __restrict__ bias,
    unsigned short* __restrict__ Cb, float* __restrict__ S3, unsigned short* __restrict__ P3,
    int K) {
  __shared__ __align__(16) unsigned short Ash[2][128 * 32];   // 2 x 8KB
  __shared__ __align__(16) unsigned short Bsh[2][256 * 32];   // 2 x 16KB
  __shared__ __align__(16) unsigned short Bsl[2][256 * 32];   // 2 x 16KB
  const int tid = threadIdx.x;
  const int lane = tid & 63;
  const int wid = tid >> 6;
  const int l15 = lane & 15, l4 = lane >> 4;
  const int wm = (wid >> 1) * 64;        // wave row offset (0/64)
  const int wn2 = (wid & 1) * 128;       // wave col offset (0/128)
  const int row0 = blockIdx.x * 128;
  const int srow = lane >> 2;
  const int sg = ((lane & 3) ^ ((lane >> 3) & 3)) * 8;   // pre-swizzled stage k-group
  const int gsw = (l4 ^ ((l15 >> 1) & 3)) * 8;           // swizzled read k-group

  const int ktiles = K >> 5;
  const int nt = PASSES * ktiles;

  // stage one 128x32 A tile + 256x32 Bh/Bl tiles into buffer b (40 chunks / 4 waves)
  auto stage = [&](int t, int b) {
    int pass = (PASSES == 2 && t >= ktiles) ? 1 : 0;
    int k0 = (t - pass * ktiles) << 5;
    const unsigned short* gA = pass ? A2 : A1;
    const unsigned short* gBh = pass ? B2h : B1h;
    const unsigned short* gBl = pass ? B2l : B1l;
    #pragma unroll
    for (int cc = 0; cc < 10; ++cc) {
      int c = wid * 10 + cc;
      unsigned short* lb;
      const unsigned short* gb;
      int grow;
      if (c < 8)       { lb = &Ash[b][c * 512];              gb = gA;  grow = row0 + c * 16 + srow; }
      else if (c < 24) { int q = c - 8;  lb = &Bsh[b][q * 512]; gb = gBh; grow = q * 16 + srow; }
      else             { int q = c - 24; lb = &Bsl[b][q * 512]; gb = gBl; grow = q * 16 + srow; }
      __builtin_amdgcn_global_load_lds(
          (const __attribute__((address_space(1))) void*)(gb + (size_t)grow * K + k0 + sg),
          (__attribute__((address_space(3))) void*)lb, 16, 0, 0);
    }
  };

  f32x4 acc[4][8];
  #pragma unroll
  for (int s = 0; s < 4; ++s)
    #pragma unroll
    for (int t = 0; t < 8; ++t) acc[s][t] = (f32x4)0.0f;

  stage(0, 0);
  __syncthreads();
  for (int t = 0; t < nt; ++t) {
    int buf = t & 1;
    if (t + 1 < nt) stage(t + 1, buf ^ 1);   // prefetch next tile while computing this one
    short8 af[4];
    #pragma unroll
    for (int s = 0; s < 4; ++s)
      af[s] = *(const short8*)&Ash[buf][(wm + s * 16 + l15) * 32 + gsw];
    #pragma unroll
    for (int tt = 0; tt < 8; ++tt) {
      short8 b = *(const short8*)&Bsh[buf][(wn2 + tt * 16 + l15) * 32 + gsw];
      #pragma unroll
      for (int s = 0; s < 4; ++s)
        acc[s][tt] = __builtin_amdgcn_mfma_f32_16x16x32_bf16(af[s], b, acc[s][tt], 0, 0, 0);
    }
    #pragma unroll
    for (int tt = 0; tt < 8; ++tt) {
      short8 b = *(const short8*)&Bsl[buf][(wn2 + tt * 16 + l15) * 32 + gsw];
      #pragma unroll
      for (int s = 0; s < 4; ++s)
        acc[s][tt] = __builtin_amdgcn_mfma_f32_16x16x32_bf16(af[s], b, acc[s][tt], 0, 0, 0);
    }
    __syncthreads();   // vmcnt(0) drain: next tile landed; this buffer free for t+2
  }

  #pragma unroll
  for (int tt = 0; tt < 8; ++tt) {
    int col = wn2 + tt * 16 + l15;
    float bv = bias[col];
    #pragma unroll
    for (int s = 0; s < 4; ++s) {
      #pragma unroll
      for (int j = 0; j < 4; ++j) {
        int row = row0 + wm + s * 16 + l4 * 4 + j;
        if (row < Nn) {
          float v = acc[s][tt][j] + bv;
          if (RELU) v = fmaxf(v, 0.f);
          if (SPLITOUT) {
            if (col < 128) S3[(size_t)row * 128 + col] = v;
            else P3[(size_t)row * 128 + col - 128] = f2bf_rtn(v);
          } else {
            Cb[(size_t)row * 256 + col] = f2bf_rtn(v);
          }
        }
      }
    }
  }
}

// ---------------- fused final: h3 = relu(S3 + AG3); out = h3 @ clw + clb ----------------
__global__ __launch_bounds__(256) void k_cls2(const float* __restrict__ S3,
                                              const float* __restrict__ AG3,
                                              const float* __restrict__ W,
                                              const float* __restrict__ B,
                                              float* __restrict__ out) {
  __shared__ float sw[1024];
  __shared__ float sb[8];
  for (int i = threadIdx.x; i < 1024; i += 256) sw[i] = W[i];
  if (threadIdx.x < 8) sb[threadIdx.x] = B[threadIdx.x];
  __syncthreads();
  int node = blockIdx.x * 256 + threadIdx.x;
  if (node >= Nn) return;
  float acc[8];
  #pragma unroll
  for (int o = 0; o < 8; o++) acc[o] = sb[o];
  const float4* s4 = (const float4*)(S3 + (size_t)node * 128);
  const float4* a4 = (const float4*)(AG3 + (size_t)node * 128);
  for (int k4 = 0; k4 < 32; k4++) {
    float4 sv = s4[k4];
    float4 av = a4[k4];
    float vv[4] = {fmaxf(sv.x + av.x, 0.f), fmaxf(sv.y + av.y, 0.f),
                   fmaxf(sv.z + av.z, 0.f), fmaxf(sv.w + av.w, 0.f)};
    #pragma unroll
    for (int j = 0; j < 4; j++) {
      int k = k4 * 4 + j;
      #pragma unroll
      for (int o = 0; o < 8; o++) acc[o] += vv[j] * sw[k * 8 + o];
    }
  }
  float4* orow = (float4*)(out + (size_t)node * 8);
  orow[0] = make_float4(acc[0], acc[1], acc[2], acc[3]);
  orow[1] = make_float4(acc[4], acc[5], acc[6], acc[7]);
}

extern "C" void kernel_launch(void* const* d_in, const int* in_sizes, int n_in,
                              void* d_out, int out_size, void* d_ws, size_t ws_size,
                              hipStream_t stream) {
  (void)in_sizes; (void)n_in; (void)out_size; (void)ws_size;
  const float* feat = (const float*)d_in[0];
  const int* eidx = (const int*)d_in[1];
  const int* esrc = eidx;
  const int* edst = eidx + Ee;
  const float* gw1 = (const float*)d_in[2];  const float* gb1 = (const float*)d_in[3];
  const float* gw2 = (const float*)d_in[4];  const float* gb2 = (const float*)d_in[5];
  const float* aw1 = (const float*)d_in[6];  const float* ab1 = (const float*)d_in[7];
  const float* aw2 = (const float*)d_in[8];  const float* ab2 = (const float*)d_in[9];
  const float* c1ws = (const float*)d_in[10]; const float* c1wn = (const float*)d_in[11]; const float* c1b = (const float*)d_in[12];
  const float* c2ws = (const float*)d_in[13]; const float* c2wn = (const float*)d_in[14]; const float* c2b = (const float*)d_in[15];
  const float* c3ws = (const float*)d_in[16]; const float* c3wn = (const float*)d_in[17]; const float* c3b = (const float*)d_in[18];
  const float* clw = (const float*)d_in[19];  const float* clb = (const float*)d_in[20];
  float* out = (float*)d_out;

  char* ws = (char*)d_ws;
  size_t off = 0;
  auto alloc = [&](size_t b) -> char* {
    char* p = ws + off;
    off = (off + b + 255) & ~(size_t)255;
    return p;
  };
  int* cnt = (int*)alloc(Nn * 4);
  int* cur = (int*)alloc(Nn * 4);
  double* accF = (double*)alloc(128 * 8);
  double* accR = (double*)alloc(128 * 8);
  double* accZ = (double*)alloc(128 * 8);
  size_t zbytes = off;  // region above must be zeroed
  int* offs = (int*)alloc((size_t)(Nn + 1) * 4);
  int* csr = (int*)alloc((size_t)Ee * 4);
  int* bsum = (int*)alloc(NBLK * 4);
  int* bbase = (int*)alloc(NBLK * 4);
  float* dinv = (float*)alloc(Nn * 4);
  float* fm = (float*)alloc(64 * 4); float* fr = (float*)alloc(64 * 4);
  float* rm = (float*)alloc(64 * 4); float* rr = (float*)alloc(64 * 4);
  float* zm = (float*)alloc(64 * 4); float* zr = (float*)alloc(64 * 4);
  unsigned short* B1sh = (unsigned short*)alloc(256 * 64 * 2);
  unsigned short* B1sl = (unsigned short*)alloc(256 * 64 * 2);
  unsigned short* B1nh = (unsigned short*)alloc(256 * 64 * 2);
  unsigned short* B1nl = (unsigned short*)alloc(256 * 64 * 2);
  unsigned short* B2sh = (unsigned short*)alloc(256 * 256 * 2);
  unsigned short* B2sl = (unsigned short*)alloc(256 * 256 * 2);
  unsigned short* B2nh = (unsigned short*)alloc(256 * 256 * 2);
  unsigned short* B2nl = (unsigned short*)alloc(256 * 256 * 2);
  unsigned short* B3h = (unsigned short*)alloc(256 * 256 * 2);
  unsigned short* B3l = (unsigned short*)alloc(256 * 256 * 2);
  float* b3p = (float*)alloc(256 * 4);
  float* Xs = (float*)alloc((size_t)Nn * 64 * 4);
  float* Zf = (float*)alloc((size_t)Nn * 64 * 4);
  unsigned short* H0h = (unsigned short*)alloc((size_t)Nn * 64 * 2);
  unsigned short* AG0 = (unsigned short*)alloc((size_t)Nn * 64 * 2);
  unsigned short* H1h = (unsigned short*)alloc((size_t)Nn * 256 * 2);
  unsigned short* AG1 = (unsigned short*)alloc((size_t)Nn * 256 * 2);
  unsigned short* H2h = (unsigned short*)alloc((size_t)Nn * 256 * 2);
  alloc(65536);  // guard for OOB A-row staging (rows 50000..50047)
  float* S3f = (float*)Zf;            // alias (Zf dead after GEMM1)
  float* AG3 = (float*)H1h;           // alias (H1 dead after GEMM2)
  unsigned short* P3h = AG1;          // alias (AG1 dead after GEMM2)

  hipMemsetAsync(d_ws, 0, zbytes, stream);

  hipLaunchKernelGGL(k_prep, dim3(64), dim3(256), 0, stream, c1ws, 64, 256, B1sh, B1sl);
  hipLaunchKernelGGL(k_prep, dim3(64), dim3(256), 0, stream, c1wn, 64, 256, B1nh, B1nl);
  hipLaunchKernelGGL(k_prep, dim3(256), dim3(256), 0, stream, c2ws, 256, 256, B2sh, B2sl);
  hipLaunchKernelGGL(k_prep, dim3(256), dim3(256), 0, stream, c2wn, 256, 256, B2nh, B2nl);
  hipLaunchKernelGGL(k_prep, dim3(128), dim3(256), 0, stream, c3ws, 256, 128, B3h, B3l);
  hipLaunchKernelGGL(k_prep, dim3(128), dim3(256), 0, stream, c3wn, 256, 128,
                     B3h + 128 * 256, B3l + 128 * 256);
  hipLaunchKernelGGL(k_bias_pad, dim3(1), dim3(256), 0, stream, c3b, b3p);

  int eb = (Ee + 255) / 256;
  hipLaunchKernelGGL(k_count, dim3(eb), dim3(256), 0, stream, edst, cnt);
  hipLaunchKernelGGL(k_bsum, dim3(NBLK), dim3(256), 0, stream, cnt, bsum);
  hipLaunchKernelGGL(k_bscan, dim3(1), dim3(256), 0, stream, bsum, bbase, offs);
  hipLaunchKernelGGL(k_offsets, dim3(NBLK), dim3(256), 0, stream, cnt, bbase, offs, dinv);
  hipLaunchKernelGGL(k_scatter, dim3(eb), dim3(256), 0, stream, esrc, edst, offs, cur, csr);
  hipLaunchKernelGGL(k_xs, dim3((Nn * 16 + 255) / 256), dim3(256), 0, stream, feat, dinv, Xs);

  hipLaunchKernelGGL(k_stats, dim3(196), dim3(256), 0, stream, feat, accF);
  hipLaunchKernelGGL(k_stats_final, dim3(1), dim3(64), 0, stream, accF, fm, fr);

  hipLaunchKernelGGL(k_energy, dim3((Nn + 3) / 4), dim3(256), 0, stream,
                     Xs, cnt, offs, csr, Zf);
  hipLaunchKernelGGL(k_stats, dim3(196), dim3(256), 0, stream, Zf, accR);
  hipLaunchKernelGGL(k_stats_final, dim3(1), dim3(64), 0, stream, accR, rm, rr);

  hipLaunchKernelGGL(k_gate, dim3((Nn + 255) / 256), dim3(256), 0, stream,
                     feat, fm, fr, rm, rr, gw1, gb1, gw2, gb2, Zf);
  hipLaunchKernelGGL(k_stats, dim3(196), dim3(256), 0, stream, Zf, accZ);
  hipLaunchKernelGGL(k_stats_final, dim3(1), dim3(64), 0, stream, accZ, zm, zr);

  hipLaunchKernelGGL(k_attn, dim3(196), dim3(256), 0, stream,
                     zm, zr, aw1, ab1, aw2, ab2, Zf, H0h);

  hipLaunchKernelGGL(k_pull64b, dim3((Nn + 3) / 4), dim3(256), 0, stream,
                     H0h, cnt, offs, csr, AG0);
  hipLaunchKernelGGL((k_gemm<2, true, false>), dim3(391), dim3(256), 0, stream,
                     H0h, B1sh, B1sl, AG0, B1nh, B1nl, c1b,
                     H1h, (float*)nullptr, (unsigned short*)nullptr, 64);
  hipLaunchKernelGGL(k_pull256b, dim3((Nn + 3) / 4), dim3(256), 0, stream,
                     H1h, cnt, offs, csr, AG1);
  hipLaunchKernelGGL((k_gemm<2, true, false>), dim3(391), dim3(256), 0, stream,
                     H1h, B2sh, B2sl, AG1, B2nh, B2nl, c2b,
                     H2h, (float*)nullptr, (unsigned short*)nullptr, 256);
  hipLaunchKernelGGL((k_gemm<1, false, true>), dim3(391), dim3(256), 0, stream,
                     H2h, B3h, B3l,
                     (unsigned short*)nullptr, (unsigned short*)nullptr, (unsigned short*)nullptr,
                     b3p, (unsigned short*)nullptr, S3f, P3h, 256);
  hipLaunchKernelGGL(k_pullh, dim3((Nn + 3) / 4), dim3(256), 0, stream,
                     P3h, cnt, offs, csr, AG3);
  hipLaunchKernelGGL(k_cls2, dim3((Nn + 255) / 256), dim3(256), 0, stream,
                     S3f, AG3, clw, clb, out);
}